// Round 1
// baseline (1349.674 us; speedup 1.0000x reference)
//
#include <hip/hip_runtime.h>
#include <math.h>

#define NXc 432
#define NYc 496
#define NVc 10000
#define NPc 16384
#define CELLS (NXc*NYc)          // 214272
#define SHRINKc 0.0025f

// ---------------- zero output + stats ----------------
__global__ void k_zero(float* __restrict__ out, int n, float* __restrict__ stats) {
    int gid = blockIdx.x * blockDim.x + threadIdx.x;
    int n4 = n >> 2;
    float4 z = make_float4(0.f, 0.f, 0.f, 0.f);
    float4* o4 = (float4*)out;
    for (int i = gid; i < n4; i += gridDim.x * blockDim.x) o4[i] = z;
    int tail = n & 3;
    if (gid < tail) out[n4 * 4 + gid] = 0.f;
    if (gid < 260) stats[gid] = 0.f;
}

// ---------------- memory_lookup for ALL 16384 points ----------------
// P_out[p][d] = (renorm(shrink(softmax(x_p @ mem_w^T)))) @ mem_w
// 8 points/block, 2048 blocks. LDS: X 2KB + att 32KB + W-tile 17.4KB = 52KB.
__global__ __launch_bounds__(256) void k_mem(const float* __restrict__ pfeat,
                                             const float* __restrict__ memw,
                                             float* __restrict__ Pout) {
    __shared__ float X[8][64];
    __shared__ float att[8][1024];
    __shared__ float Wt[64][68];   // pad 68: keeps 16B alignment for b128
    int t = threadIdx.x;
    int pbase = blockIdx.x * 8;
    if (t < 128) {
        int p = t >> 4, d = (t & 15) << 2;
        *(float4*)&X[p][d] = *(const float4*)(pfeat + (pbase + p) * 64 + d);
    }
    __syncthreads();
    int wv = t >> 6, l = t & 63;
    int p0 = wv * 2, p1 = wv * 2 + 1;
    // Phase A: logits. tile = 64 mem rows (full 64-d dots per tile).
    for (int mt = 0; mt < 16; ++mt) {
#pragma unroll
        for (int r = 0; r < 4; ++r) {
            int q = t + 256 * r;
            int m = q >> 4, d = (q & 15) << 2;
            *(float4*)&Wt[m][d] = *(const float4*)(memw + (mt * 64 + m) * 64 + d);
        }
        __syncthreads();
        float a0 = 0.f, a1 = 0.f;
#pragma unroll
        for (int i = 0; i < 16; ++i) {
            float4 x0 = *(const float4*)&X[p0][4 * i];
            float4 x1 = *(const float4*)&X[p1][4 * i];
            float4 w  = *(const float4*)&Wt[l][4 * i];
            a0 += x0.x * w.x + x0.y * w.y + x0.z * w.z + x0.w * w.w;
            a1 += x1.x * w.x + x1.y * w.y + x1.z * w.z + x1.w * w.w;
        }
        att[p0][mt * 64 + l] = a0;
        att[p1][mt * 64 + l] = a1;
        __syncthreads();
    }
    // softmax + hard-shrink + L1 renorm, half-wave per point
    {
        int ps = wv * 2 + (l >> 5);
        int il = l & 31;
        float* ar = att[ps];
        float mx = -INFINITY;
#pragma unroll
        for (int j = 0; j < 32; ++j) mx = fmaxf(mx, ar[il + 32 * j]);
#pragma unroll
        for (int off = 16; off >= 1; off >>= 1) mx = fmaxf(mx, __shfl_xor(mx, off));
        float s = 0.f;
#pragma unroll
        for (int j = 0; j < 32; ++j) {
            float e = __expf(ar[il + 32 * j] - mx);
            ar[il + 32 * j] = e; s += e;
        }
#pragma unroll
        for (int off = 16; off >= 1; off >>= 1) s += __shfl_xor(s, off);
        float inv_s = 1.f / s;
        float s2 = 0.f;
#pragma unroll
        for (int j = 0; j < 32; ++j) {
            float a = ar[il + 32 * j] * inv_s;
            float tt = a - SHRINKc;
            float r2 = fmaxf(tt, 0.f) * a / (fabsf(tt) + 1e-12f);
            ar[il + 32 * j] = r2; s2 += r2;
        }
#pragma unroll
        for (int off = 16; off >= 1; off >>= 1) s2 += __shfl_xor(s2, off);
        float inv2 = 1.f / fmaxf(s2, 1e-12f);
#pragma unroll
        for (int j = 0; j < 32; ++j) ar[il + 32 * j] *= inv2;
    }
    __syncthreads();
    // Phase B: out = att @ mem_w. lane = output column.
    float o0 = 0.f, o1 = 0.f;
    for (int mt = 0; mt < 16; ++mt) {
#pragma unroll
        for (int r = 0; r < 4; ++r) {
            int q = t + 256 * r;
            int m = q >> 4, d = (q & 15) << 2;
            *(float4*)&Wt[m][d] = *(const float4*)(memw + (mt * 64 + m) * 64 + d);
        }
        __syncthreads();
        const float* a0r = &att[p0][mt * 64];
        const float* a1r = &att[p1][mt * 64];
#pragma unroll
        for (int m = 0; m < 64; ++m) {
            float w = Wt[m][l];
            o0 += a0r[m] * w;
            o1 += a1r[m] * w;
        }
        __syncthreads();
    }
    Pout[(pbase + p0) * 64 + l] = o0;
    Pout[(pbase + p1) * 64 + l] = o1;
}

// ---------------- Q[p][k*64+j] = sum_d Pout[p][d] * adapt[j][k*64+d] ----------------
// 32 points/block, 512 blocks.
__global__ __launch_bounds__(256) void k_proj(const float* __restrict__ Pout,
                                              const float* __restrict__ adapt,
                                              float* __restrict__ Q) {
    __shared__ float Xs[32][65];
    __shared__ float As[64][197];
    int t = threadIdx.x;
    int pb = blockIdx.x * 32;
#pragma unroll
    for (int r = 0; r < 2; ++r) {
        int q = t + 256 * r;
        int p = q >> 4, d = (q & 15) << 2;
        float4 v = *(const float4*)(Pout + (pb + p) * 64 + d);
        Xs[p][d] = v.x; Xs[p][d + 1] = v.y; Xs[p][d + 2] = v.z; Xs[p][d + 3] = v.w;
    }
#pragma unroll
    for (int r = 0; r < 12; ++r) {
        int q = t + 256 * r;            // 3072 float4 = 64*192 floats
        int j = q / 48, i = (q % 48) << 2;
        float4 v = *(const float4*)(adapt + j * 192 + i);
        As[j][i] = v.x; As[j][i + 1] = v.y; As[j][i + 2] = v.z; As[j][i + 3] = v.w;
    }
    __syncthreads();
    int tr = t >> 4, tc = t & 15;
    float acc[2][12];
#pragma unroll
    for (int u = 0; u < 2; ++u)
#pragma unroll
        for (int cc = 0; cc < 12; ++cc) acc[u][cc] = 0.f;
    for (int d = 0; d < 64; ++d) {
        float xv0 = Xs[tr * 2 + 0][d];
        float xv1 = Xs[tr * 2 + 1][d];
#pragma unroll
        for (int cc = 0; cc < 12; ++cc) {
            int c = tc * 12 + cc;
            float a = As[c & 63][((c >> 6) << 6) + d];
            acc[0][cc] += xv0 * a;
            acc[1][cc] += xv1 * a;
        }
    }
#pragma unroll
    for (int u = 0; u < 2; ++u)
#pragma unroll
        for (int cc = 0; cc < 12; ++cc)
            Q[(pb + tr * 2 + u) * 192 + tc * 12 + cc] = acc[u][cc];
}

// ---------------- score + pdist candidate top-4 per 1024-point chunk ----------------
// thread = pillar (64 pillar regs), grid (40, 16). LDS 34.8KB.
__global__ __launch_bounds__(256) void k_score(const float* __restrict__ pillar,
                                               const int* __restrict__ coords,
                                               const float* __restrict__ pfeat,
                                               const float* __restrict__ pcoord,
                                               int* __restrict__ sIdx,
                                               int* __restrict__ dIdx) {
    __shared__ float PT[128][64];
    __shared__ float PC[128][4];
    int t = threadIdx.x;
    int v = blockIdx.x * 256 + t;
    bool valid = v < NVc;
    int vv = valid ? v : 0;
    float pf[64];
#pragma unroll
    for (int i = 0; i < 16; ++i) {
        float4 q = *(const float4*)(pillar + vv * 64 + 4 * i);
        pf[4 * i] = q.x; pf[4 * i + 1] = q.y; pf[4 * i + 2] = q.z; pf[4 * i + 3] = q.w;
    }
    float cb = (float)coords[vv * 4 + 0];
    float cx = (float)coords[vv * 4 + 1];
    float cy = (float)coords[vv * 4 + 2];
    float cz = (float)coords[vv * 4 + 3];
    float sv0 = -INFINITY, sv1 = -INFINITY, sv2 = -INFINITY, sv3 = -INFINITY;
    int   si0 = 0, si1 = 0, si2 = 0, si3 = 0;
    float dv0 = INFINITY, dv1 = INFINITY, dv2 = INFINITY, dv3 = INFINITY;
    int   di0 = 0, di1 = 0, di2 = 0, di3 = 0;
    int chunkBase = blockIdx.y * 1024;
    for (int tile = 0; tile < 8; ++tile) {
        int pb = chunkBase + tile * 128;
        __syncthreads();
#pragma unroll
        for (int r = 0; r < 8; ++r) {
            int q = t + 256 * r;
            int p = q >> 4, d = (q & 15) << 2;
            *(float4*)&PT[p][d] = *(const float4*)(pfeat + (pb + p) * 64 + d);
        }
        if (t < 128) *(float4*)&PC[t][0] = *(const float4*)(pcoord + (pb + t) * 4);
        __syncthreads();
        for (int pl = 0; pl < 128; ++pl) {
            const float4* prow = (const float4*)&PT[pl][0];
            float s = 0.f;
#pragma unroll
            for (int i = 0; i < 16; ++i) {
                float4 w = prow[i];
                s += pf[4 * i] * w.x + pf[4 * i + 1] * w.y
                   + pf[4 * i + 2] * w.z + pf[4 * i + 3] * w.w;
            }
            int gp = pb + pl;
            if (valid && (s > sv3)) {
                if (s > sv0)      { sv3=sv2; si3=si2; sv2=sv1; si2=si1; sv1=sv0; si1=si0; sv0=s; si0=gp; }
                else if (s > sv1) { sv3=sv2; si3=si2; sv2=sv1; si2=si1; sv1=s; si1=gp; }
                else if (s > sv2) { sv3=sv2; si3=si2; sv2=s; si2=gp; }
                else              { sv3=s; si3=gp; }
            }
            float4 qc = *(const float4*)&PC[pl][0];
            float db_ = cb - qc.x, dx_ = cx - qc.y, dy_ = cy - qc.z, dz_ = cz - qc.w;
            float d2 = db_ * db_ + dx_ * dx_ + dy_ * dy_ + dz_ * dz_;
            if (valid && (d2 < dv3)) {
                if (d2 < dv0)      { dv3=dv2; di3=di2; dv2=dv1; di2=di1; dv1=dv0; di1=di0; dv0=d2; di0=gp; }
                else if (d2 < dv1) { dv3=dv2; di3=di2; dv2=dv1; di2=di1; dv1=d2; di1=gp; }
                else if (d2 < dv2) { dv3=dv2; di3=di2; dv2=d2; di2=gp; }
                else               { dv3=d2; di3=gp; }
            }
        }
    }
    if (valid) {
        int base = (blockIdx.y * NVc + v) * 4;
        sIdx[base + 0] = si0; sIdx[base + 1] = si1; sIdx[base + 2] = si2; sIdx[base + 3] = si3;
        dIdx[base + 0] = di0; dIdx[base + 1] = di1; dIdx[base + 2] = di2; dIdx[base + 3] = di3;
    }
}

// ---------------- fp64 re-rank of 64 candidates -> exact top-3 ----------------
// wave per pillar, lane = candidate.
__global__ __launch_bounds__(256) void k_rerank(const float* __restrict__ pillar,
                                                const int* __restrict__ coords,
                                                const float* __restrict__ pfeat,
                                                const float* __restrict__ pcoord,
                                                const int* __restrict__ sIdx,
                                                const int* __restrict__ dIdx,
                                                int* __restrict__ idx_f,
                                                int* __restrict__ idx_c) {
    int t = threadIdx.x;
    int wv = t >> 6, l = t & 63;
    int v = blockIdx.x * 4 + wv;            // exactly 10000
    int chunk = l >> 2, slot = l & 3;
    int ps = sIdx[(chunk * NVc + v) * 4 + slot];
    int pd = dIdx[(chunk * NVc + v) * 4 + slot];
    double s = 0.0;
#pragma unroll
    for (int i = 0; i < 16; ++i) {
        float4 a = *(const float4*)(pillar + v * 64 + 4 * i);
        float4 b = *(const float4*)(pfeat + ps * 64 + 4 * i);
        s += (double)a.x * (double)b.x + (double)a.y * (double)b.y
           + (double)a.z * (double)b.z + (double)a.w * (double)b.w;
    }
    float4 qc = *(const float4*)(pcoord + pd * 4);
    double db_ = (double)coords[v * 4 + 0] - (double)qc.x;
    double dx_ = (double)coords[v * 4 + 1] - (double)qc.y;
    double dy_ = (double)coords[v * 4 + 2] - (double)qc.z;
    double dz_ = (double)coords[v * 4 + 3] - (double)qc.w;
    double d2 = db_ * db_ + dx_ * dx_ + dy_ * dy_ + dz_ * dz_;
    // top-3 max (ties -> lower point index)
    double sv = s; int sx = ps;
    for (int k = 0; k < 3; ++k) {
        double bv = sv; int bi = sx;
#pragma unroll
        for (int off = 32; off >= 1; off >>= 1) {
            double ov = __shfl_xor(bv, off);
            int    oi = __shfl_xor(bi, off);
            if (ov > bv || (ov == bv && oi < bi)) { bv = ov; bi = oi; }
        }
        if (l == 0) idx_f[v * 3 + k] = bi;
        if (sx == bi) { sv = -INFINITY; sx = 0x7fffffff; }
    }
    // top-3 min distance
    double dv = d2; int dx2 = pd;
    for (int k = 0; k < 3; ++k) {
        double bv = dv; int bi = dx2;
#pragma unroll
        for (int off = 32; off >= 1; off >>= 1) {
            double ov = __shfl_xor(bv, off);
            int    oi = __shfl_xor(bi, off);
            if (ov < bv || (ov == bv && oi < bi)) { bv = ov; bi = oi; }
        }
        if (l == 0) idx_c[v * 3 + k] = bi;
        if (dx2 == bi) { dv = INFINITY; dx2 = 0x7fffffff; }
    }
}

// ---------------- gather-add + w logits + BN partial sums ----------------
__global__ __launch_bounds__(256) void k_gather(const float* __restrict__ Q,
                                                const int* __restrict__ idx_f,
                                                const int* __restrict__ idx_c,
                                                const float* __restrict__ pillar,
                                                const float* __restrict__ ww,
                                                float* __restrict__ f_pre,
                                                float* __restrict__ c_pre,
                                                float* __restrict__ w_pre,
                                                float* __restrict__ stats) {
    __shared__ float red[4][4][64];
    __shared__ float redw[4][4];
    int t = threadIdx.x;
    int wv = t >> 6, l = t & 63;
    int base = blockIdx.x * 250;
    int vend = base + 250;
    float fs = 0, fq = 0, cs = 0, cq = 0, ws0 = 0, wq0 = 0, ws1 = 0, wq1 = 0;
    float w0l = ww[l], w1l = ww[64 + l];
    for (int v = base + wv; v < vend; v += 4) {
        int if0 = idx_f[v * 3], if1 = idx_f[v * 3 + 1], if2 = idx_f[v * 3 + 2];
        float f = Q[if0 * 192 + l] + Q[if1 * 192 + 64 + l] + Q[if2 * 192 + 128 + l];
        f_pre[v * 64 + l] = f; fs += f; fq += f * f;
        int ic0 = idx_c[v * 3], ic1 = idx_c[v * 3 + 1], ic2 = idx_c[v * 3 + 2];
        float c = Q[ic0 * 192 + l] + Q[ic1 * 192 + 64 + l] + Q[ic2 * 192 + 128 + l];
        c_pre[v * 64 + l] = c; cs += c; cq += c * c;
        float pv = pillar[v * 64 + l];
        float a0 = pv * w0l, a1 = pv * w1l;
#pragma unroll
        for (int off = 32; off >= 1; off >>= 1) {
            a0 += __shfl_xor(a0, off);
            a1 += __shfl_xor(a1, off);
        }
        if (l == 0) { w_pre[v * 2] = a0; w_pre[v * 2 + 1] = a1; }
        ws0 += a0; wq0 += a0 * a0; ws1 += a1; wq1 += a1 * a1;
    }
    red[0][wv][l] = fs; red[1][wv][l] = fq; red[2][wv][l] = cs; red[3][wv][l] = cq;
    if (l == 0) { redw[wv][0] = ws0; redw[wv][1] = wq0; redw[wv][2] = ws1; redw[wv][3] = wq1; }
    __syncthreads();
    if (wv == 0) {
#pragma unroll
        for (int q = 0; q < 4; ++q) {
            float sum = red[q][0][l] + red[q][1][l] + red[q][2][l] + red[q][3][l];
            atomicAdd(&stats[q * 64 + l], sum);
        }
        if (l < 4) {
            float sum = redw[0][l] + redw[1][l] + redw[2][l] + redw[3][l];
            atomicAdd(&stats[256 + l], sum);
        }
    }
}

// ---------------- BN finalize + softmax weights + scatter ----------------
__global__ __launch_bounds__(256) void k_final(const float* __restrict__ f_pre,
                                               const float* __restrict__ c_pre,
                                               const float* __restrict__ w_pre,
                                               const float* __restrict__ stats,
                                               const float* __restrict__ pillar,
                                               const int* __restrict__ coords,
                                               const float* __restrict__ g1,
                                               const float* __restrict__ b1,
                                               const float* __restrict__ g2,
                                               const float* __restrict__ b2,
                                               float* __restrict__ out) {
    int t = threadIdx.x;
    int wv = t >> 6, l = t & 63;
    int v = blockIdx.x * 4 + wv;            // exactly 10000
    const float invn = 1.0f / (float)NVc;
    float mf = stats[l] * invn;
    float vf = stats[64 + l] * invn - mf * mf;
    float rf = rsqrtf(vf + 1e-3f);
    float mc = stats[128 + l] * invn;
    float vc = stats[192 + l] * invn - mc * mc;
    float rc = rsqrtf(vc + 1e-3f);
    float mw0 = stats[256] * invn, vw0 = stats[257] * invn - mw0 * mw0;
    float mw1 = stats[258] * invn, vw1 = stats[259] * invn - mw1 * mw1;
    float rw0 = rsqrtf(vw0 + 1e-3f), rw1 = rsqrtf(vw1 + 1e-3f);
    float fb = (f_pre[v * 64 + l] - mf) * rf * g1[l] + b1[l];
    float f = fmaxf(fb, 0.f);
    float cb_ = (c_pre[v * 64 + l] - mc) * rc * g1[l] + b1[l];
    float c = fmaxf(cb_, 0.f);
    float z0 = (w_pre[v * 2] - mw0) * rw0 * g2[0] + b2[0];
    float z1 = (w_pre[v * 2 + 1] - mw1) * rw1 * g2[1] + b2[1];
    float mz = fmaxf(z0, z1);
    float e0 = __expf(z0 - mz), e1 = __expf(z1 - mz);
    float wd = 1.f / (e0 + e1);
    float aug = (e0 * wd) * f + (e1 * wd) * c;
    int cxi = coords[v * 4 + 1], cyi = coords[v * 4 + 2], czi = coords[v * 4 + 3];
    int cell = cxi + cyi * NXc + czi;
    out[l * CELLS + cell] = pillar[v * 64 + l];
    out[(64 + l) * CELLS + cell] = aug;
    if (l == 0) {
        float* o1 = out + 128 * CELLS;
        o1[cell] = (float)cyi;
        o1[CELLS + cell] = (float)czi;
        o1[2 * CELLS + cell] = (float)cxi;
    }
}

extern "C" void kernel_launch(void* const* d_in, const int* in_sizes, int n_in,
                              void* d_out, int out_size, void* d_ws, size_t ws_size,
                              hipStream_t stream) {
    const float* pillar = (const float*)d_in[0];
    const int*   coords = (const int*)d_in[1];
    const float* pfeat  = (const float*)d_in[2];
    const float* pcoord = (const float*)d_in[3];
    const float* adapt  = (const float*)d_in[4];
    const float* bn1g   = (const float*)d_in[5];
    const float* bn1b   = (const float*)d_in[6];
    const float* ww     = (const float*)d_in[7];
    const float* bn2g   = (const float*)d_in[8];
    const float* bn2b   = (const float*)d_in[9];
    const float* memw   = (const float*)d_in[10];
    float* out = (float*)d_out;
    float* ws  = (float*)d_ws;
    // workspace layout (float offsets)
    float* Pout  = ws + 0;           // 16384*64   = 1,048,576
    float* Q     = ws + 1048576;     // 16384*192  = 3,145,728
    int*   sIdx  = (int*)(ws + 4194304);   // 16*10000*4 = 640,000
    int*   dIdx  = (int*)(ws + 4834304);   // 640,000
    int*   idxf  = (int*)(ws + 5474304);   // 30,000
    int*   idxc  = (int*)(ws + 5504304);   // 30,000
    float* fpre  = ws + 5534304;     // 640,000
    float* cpre  = ws + 6174304;     // 640,000
    float* wpre  = ws + 6814304;     // 20,000
    float* stats = ws + 6834304;     // 260

    k_zero  <<<4096, 256, 0, stream>>>(out, out_size, stats);
    k_mem   <<<2048, 256, 0, stream>>>(pfeat, memw, Pout);
    k_proj  <<<512,  256, 0, stream>>>(Pout, adapt, Q);
    k_score <<<dim3(40, 16), 256, 0, stream>>>(pillar, coords, pfeat, pcoord, sIdx, dIdx);
    k_rerank<<<2500, 256, 0, stream>>>(pillar, coords, pfeat, pcoord, sIdx, dIdx, idxf, idxc);
    k_gather<<<40,   256, 0, stream>>>(Q, idxf, idxc, pillar, ww, fpre, cpre, wpre, stats);
    k_final <<<2500, 256, 0, stream>>>(fpre, cpre, wpre, stats, pillar, coords,
                                       bn1g, bn1b, bn2g, bn2b, out);
}

// Round 2
// 726.436 us; speedup vs baseline: 1.8579x; 1.8579x over previous
//
#include <hip/hip_runtime.h>
#include <math.h>

#define NXc 432
#define NYc 496
#define NVc 10000
#define NPc 16384
#define CELLS (NXc*NYc)          // 214272
#define SHRINKc 0.0025f
#define NVPAD 10048              // 157*64

typedef unsigned short u16;
typedef __attribute__((ext_vector_type(8))) short s16x8;   // 8 bf16
typedef __attribute__((ext_vector_type(4))) float f32x4;

// ---------------- zero output + stats ----------------
__global__ void k_zero(float* __restrict__ out, int n, float* __restrict__ stats) {
    int gid = blockIdx.x * blockDim.x + threadIdx.x;
    int n4 = n >> 2;
    float4 z = make_float4(0.f, 0.f, 0.f, 0.f);
    float4* o4 = (float4*)out;
    for (int i = gid; i < n4; i += gridDim.x * blockDim.x) o4[i] = z;
    int tail = n & 3;
    if (gid < tail) out[n4 * 4 + gid] = 0.f;
    if (gid < 260) stats[gid] = 0.f;
}

// ---------------- fp32 -> bf16 (RNE) cast of pillar + point features ----------------
__device__ __forceinline__ u16 f2b(float x) {
    unsigned u = __float_as_uint(x);
    unsigned r = (u + 0x7fffu + ((u >> 16) & 1u)) >> 16;
    return (u16)r;
}
__global__ __launch_bounds__(256) void k_cast(const float* __restrict__ pillar,
                                              const float* __restrict__ pfeat,
                                              u16* __restrict__ pillarH,
                                              u16* __restrict__ pfeatH) {
    int idx = blockIdx.x * 256 + threadIdx.x;      // 6608 blocks * 256 = 1691648 exactly
    const int N1 = NVPAD * 64;                     // 643072
    if (idx < N1) {
        int v = idx >> 6;
        float x = (v < NVc) ? pillar[idx] : 0.f;
        pillarH[idx] = f2b(x);
    } else {
        int j = idx - N1;
        pfeatH[j] = f2b(pfeat[j]);
    }
}

// ---------------- memory_lookup for ALL 16384 points ----------------
__global__ __launch_bounds__(256) void k_mem(const float* __restrict__ pfeat,
                                             const float* __restrict__ memw,
                                             float* __restrict__ Pout) {
    __shared__ float X[8][64];
    __shared__ float att[8][1024];
    __shared__ float Wt[64][68];
    int t = threadIdx.x;
    int pbase = blockIdx.x * 8;
    if (t < 128) {
        int p = t >> 4, d = (t & 15) << 2;
        *(float4*)&X[p][d] = *(const float4*)(pfeat + (pbase + p) * 64 + d);
    }
    __syncthreads();
    int wv = t >> 6, l = t & 63;
    int p0 = wv * 2, p1 = wv * 2 + 1;
    for (int mt = 0; mt < 16; ++mt) {
#pragma unroll
        for (int r = 0; r < 4; ++r) {
            int q = t + 256 * r;
            int m = q >> 4, d = (q & 15) << 2;
            *(float4*)&Wt[m][d] = *(const float4*)(memw + (mt * 64 + m) * 64 + d);
        }
        __syncthreads();
        float a0 = 0.f, a1 = 0.f;
#pragma unroll
        for (int i = 0; i < 16; ++i) {
            float4 x0 = *(const float4*)&X[p0][4 * i];
            float4 x1 = *(const float4*)&X[p1][4 * i];
            float4 w  = *(const float4*)&Wt[l][4 * i];
            a0 += x0.x * w.x + x0.y * w.y + x0.z * w.z + x0.w * w.w;
            a1 += x1.x * w.x + x1.y * w.y + x1.z * w.z + x1.w * w.w;
        }
        att[p0][mt * 64 + l] = a0;
        att[p1][mt * 64 + l] = a1;
        __syncthreads();
    }
    {
        int ps = wv * 2 + (l >> 5);
        int il = l & 31;
        float* ar = att[ps];
        float mx = -INFINITY;
#pragma unroll
        for (int j = 0; j < 32; ++j) mx = fmaxf(mx, ar[il + 32 * j]);
#pragma unroll
        for (int off = 16; off >= 1; off >>= 1) mx = fmaxf(mx, __shfl_xor(mx, off));
        float s = 0.f;
#pragma unroll
        for (int j = 0; j < 32; ++j) {
            float e = __expf(ar[il + 32 * j] - mx);
            ar[il + 32 * j] = e; s += e;
        }
#pragma unroll
        for (int off = 16; off >= 1; off >>= 1) s += __shfl_xor(s, off);
        float inv_s = 1.f / s;
        float s2 = 0.f;
#pragma unroll
        for (int j = 0; j < 32; ++j) {
            float a = ar[il + 32 * j] * inv_s;
            float tt = a - SHRINKc;
            float r2 = fmaxf(tt, 0.f) * a / (fabsf(tt) + 1e-12f);
            ar[il + 32 * j] = r2; s2 += r2;
        }
#pragma unroll
        for (int off = 16; off >= 1; off >>= 1) s2 += __shfl_xor(s2, off);
        float inv2 = 1.f / fmaxf(s2, 1e-12f);
#pragma unroll
        for (int j = 0; j < 32; ++j) ar[il + 32 * j] *= inv2;
    }
    __syncthreads();
    float o0 = 0.f, o1 = 0.f;
    for (int mt = 0; mt < 16; ++mt) {
#pragma unroll
        for (int r = 0; r < 4; ++r) {
            int q = t + 256 * r;
            int m = q >> 4, d = (q & 15) << 2;
            *(float4*)&Wt[m][d] = *(const float4*)(memw + (mt * 64 + m) * 64 + d);
        }
        __syncthreads();
        const float* a0r = &att[p0][mt * 64];
        const float* a1r = &att[p1][mt * 64];
#pragma unroll
        for (int m = 0; m < 64; ++m) {
            float w = Wt[m][l];
            o0 += a0r[m] * w;
            o1 += a1r[m] * w;
        }
        __syncthreads();
    }
    Pout[(pbase + p0) * 64 + l] = o0;
    Pout[(pbase + p1) * 64 + l] = o1;
}

// ---------------- Q[p][k*64+j] = sum_d Pout[p][d] * adapt[j][k*64+d] ----------------
__global__ __launch_bounds__(256) void k_proj(const float* __restrict__ Pout,
                                              const float* __restrict__ adapt,
                                              float* __restrict__ Q) {
    __shared__ float Xs[32][65];
    __shared__ float As[64][197];
    int t = threadIdx.x;
    int pb = blockIdx.x * 32;
#pragma unroll
    for (int r = 0; r < 2; ++r) {
        int q = t + 256 * r;
        int p = q >> 4, d = (q & 15) << 2;
        float4 v = *(const float4*)(Pout + (pb + p) * 64 + d);
        Xs[p][d] = v.x; Xs[p][d + 1] = v.y; Xs[p][d + 2] = v.z; Xs[p][d + 3] = v.w;
    }
#pragma unroll
    for (int r = 0; r < 12; ++r) {
        int q = t + 256 * r;
        int j = q / 48, i = (q % 48) << 2;
        float4 v = *(const float4*)(adapt + j * 192 + i);
        As[j][i] = v.x; As[j][i + 1] = v.y; As[j][i + 2] = v.z; As[j][i + 3] = v.w;
    }
    __syncthreads();
    int tr = t >> 4, tc = t & 15;
    float acc[2][12];
#pragma unroll
    for (int u = 0; u < 2; ++u)
#pragma unroll
        for (int cc = 0; cc < 12; ++cc) acc[u][cc] = 0.f;
    for (int d = 0; d < 64; ++d) {
        float xv0 = Xs[tr * 2 + 0][d];
        float xv1 = Xs[tr * 2 + 1][d];
#pragma unroll
        for (int cc = 0; cc < 12; ++cc) {
            int c = tc * 12 + cc;
            float a = As[c & 63][((c >> 6) << 6) + d];
            acc[0][cc] += xv0 * a;
            acc[1][cc] += xv1 * a;
        }
    }
#pragma unroll
    for (int u = 0; u < 2; ++u)
#pragma unroll
        for (int cc = 0; cc < 12; ++cc)
            Q[(pb + tr * 2 + u) * 192 + tc * 12 + cc] = acc[u][cc];
}

// ---------------- MFMA score + dist candidate top-4 per 1024-point chunk ----------------
// grid (157 pillar-tiles, 16 chunks), block 256 (4 waves).
// Block: 64 pillars x 1024 points, subtiles of 128 points.
__global__ __launch_bounds__(256) void k_score2(const u16* __restrict__ pillarH,
                                                const u16* __restrict__ pfeatH,
                                                const int* __restrict__ coords,
                                                const float* __restrict__ pcoord,
                                                int* __restrict__ sIdx,
                                                int* __restrict__ dIdx) {
    __shared__ u16   Bbf[128][72];       // 18 KB, pad 72 for bank spread
    __shared__ float S[64][133];         // 34 KB, pad 133
    __shared__ float4 PCs[128];          // 2 KB
    __shared__ float mrgV[4][64][4];     // 4 KB
    __shared__ int   mrgI[4][64][4];     // 4 KB

    int t = threadIdx.x;
    int w = t >> 6, l = t & 63;
    int qd = l >> 4, lm = l & 15;
    int pb = blockIdx.x * 64;
    int cb = blockIdx.y * 1024;

    // A fragments: pillar rows 16w+lm, k halves [0,32) and [32,64)
    const u16* arow = pillarH + (size_t)(pb + 16 * w + lm) * 64 + qd * 8;
    s16x8 a0 = *(const s16x8*)arow;
    s16x8 a1 = *(const s16x8*)(arow + 32);

    // pillar coords for selection (lane = pillar)
    int gp = pb + l;
    int gpc = gp < NVc ? gp : 0;
    float cbf = (float)coords[gpc * 4 + 0];
    float cxf = (float)coords[gpc * 4 + 1];
    float cyf = (float)coords[gpc * 4 + 2];
    float czf = (float)coords[gpc * 4 + 3];

    float sv0 = -INFINITY, sv1 = -INFINITY, sv2 = -INFINITY, sv3 = -INFINITY;
    int   si0 = 0, si1 = 0, si2 = 0, si3 = 0;
    float dv0 = INFINITY, dv1 = INFINITY, dv2 = INFINITY, dv3 = INFINITY;
    int   di0 = 0, di1 = 0, di2 = 0, di3 = 0;

    for (int s = 0; s < 8; ++s) {
        int ptb = cb + s * 128;
        // ---- stage B tile + point coords ----
#pragma unroll
        for (int r = 0; r < 4; ++r) {
            int q = t + 256 * r;
            int row = q >> 3, c8 = (q & 7) << 3;
            uint4 v = *(const uint4*)(pfeatH + (size_t)(ptb + row) * 64 + c8);
            *(uint4*)(&Bbf[row][c8]) = v;
        }
        if (t < 128) PCs[t] = *(const float4*)(pcoord + (size_t)(ptb + t) * 4);
        __syncthreads();
        // ---- MFMA: wave w owns pillar rows 16w..16w+15 ----
#pragma unroll
        for (int pt = 0; pt < 8; ++pt) {
            const u16* brow = &Bbf[pt * 16 + lm][0] + qd * 8;
            s16x8 b0 = *(const s16x8*)brow;
            s16x8 b1 = *(const s16x8*)(brow + 32);
            f32x4 acc = {0.f, 0.f, 0.f, 0.f};
            acc = __builtin_amdgcn_mfma_f32_16x16x32_bf16(a0, b0, acc, 0, 0, 0);
            acc = __builtin_amdgcn_mfma_f32_16x16x32_bf16(a1, b1, acc, 0, 0, 0);
            int col = pt * 16 + lm;
            int rowb = 16 * w + qd * 4;
            S[rowb + 0][col] = acc[0];
            S[rowb + 1][col] = acc[1];
            S[rowb + 2][col] = acc[2];
            S[rowb + 3][col] = acc[3];
        }
        __syncthreads();
        // ---- selection: lane = pillar, wave = point-quarter ----
#pragma unroll 4
        for (int i = 0; i < 32; ++i) {
            int jl = w * 32 + i;
            int jg = ptb + jl;
            float sc = S[l][jl];
            bool b0 = sc > sv0, b1 = sc > sv1, b2 = sc > sv2, b3 = sc > sv3;
            sv3 = b3 ? (b2 ? sv2 : sc) : sv3;  si3 = b3 ? (b2 ? si2 : jg) : si3;
            sv2 = b2 ? (b1 ? sv1 : sc) : sv2;  si2 = b2 ? (b1 ? si1 : jg) : si2;
            sv1 = b1 ? (b0 ? sv0 : sc) : sv1;  si1 = b1 ? (b0 ? si0 : jg) : si1;
            sv0 = b0 ? sc : sv0;               si0 = b0 ? jg : si0;
            float4 pc = PCs[jl];
            float e0 = cbf - pc.x, e1 = cxf - pc.y, e2 = cyf - pc.z, e3 = czf - pc.w;
            float d2 = e0 * e0 + e1 * e1 + e2 * e2 + e3 * e3;
            bool c0 = d2 < dv0, c1 = d2 < dv1, c2 = d2 < dv2, c3 = d2 < dv3;
            dv3 = c3 ? (c2 ? dv2 : d2) : dv3;  di3 = c3 ? (c2 ? di2 : jg) : di3;
            dv2 = c2 ? (c1 ? dv1 : d2) : dv2;  di2 = c2 ? (c1 ? di1 : jg) : di2;
            dv1 = c1 ? (c0 ? dv0 : d2) : dv1;  di1 = c1 ? (c0 ? di0 : jg) : di1;
            dv0 = c0 ? d2 : dv0;               di0 = c0 ? jg : di0;
        }
        __syncthreads();
    }
    // ---- merge 4 partial top-4s per pillar: scores ----
    mrgV[w][l][0] = sv0; mrgV[w][l][1] = sv1; mrgV[w][l][2] = sv2; mrgV[w][l][3] = sv3;
    mrgI[w][l][0] = si0; mrgI[w][l][1] = si1; mrgI[w][l][2] = si2; mrgI[w][l][3] = si3;
    __syncthreads();
    if (w == 0 && gp < NVc) {
        float m0 = -INFINITY, m1 = -INFINITY, m2 = -INFINITY, m3 = -INFINITY;
        int   i0 = 0, i1 = 0, i2 = 0, i3 = 0;
#pragma unroll
        for (int src = 0; src < 4; ++src)
#pragma unroll
            for (int k = 0; k < 4; ++k) {
                float v = mrgV[src][l][k]; int ix = mrgI[src][l][k];
                bool b0 = v > m0, b1 = v > m1, b2 = v > m2, b3 = v > m3;
                m3 = b3 ? (b2 ? m2 : v) : m3;  i3 = b3 ? (b2 ? i2 : ix) : i3;
                m2 = b2 ? (b1 ? m1 : v) : m2;  i2 = b2 ? (b1 ? i1 : ix) : i2;
                m1 = b1 ? (b0 ? m0 : v) : m1;  i1 = b1 ? (b0 ? i0 : ix) : i1;
                m0 = b0 ? v : m0;              i0 = b0 ? ix : i0;
            }
        int base = (blockIdx.y * NVc + gp) * 4;
        sIdx[base + 0] = i0; sIdx[base + 1] = i1; sIdx[base + 2] = i2; sIdx[base + 3] = i3;
    }
    __syncthreads();
    // ---- merge: distances ----
    mrgV[w][l][0] = dv0; mrgV[w][l][1] = dv1; mrgV[w][l][2] = dv2; mrgV[w][l][3] = dv3;
    mrgI[w][l][0] = di0; mrgI[w][l][1] = di1; mrgI[w][l][2] = di2; mrgI[w][l][3] = di3;
    __syncthreads();
    if (w == 0 && gp < NVc) {
        float m0 = INFINITY, m1 = INFINITY, m2 = INFINITY, m3 = INFINITY;
        int   i0 = 0, i1 = 0, i2 = 0, i3 = 0;
#pragma unroll
        for (int src = 0; src < 4; ++src)
#pragma unroll
            for (int k = 0; k < 4; ++k) {
                float v = mrgV[src][l][k]; int ix = mrgI[src][l][k];
                bool b0 = v < m0, b1 = v < m1, b2 = v < m2, b3 = v < m3;
                m3 = b3 ? (b2 ? m2 : v) : m3;  i3 = b3 ? (b2 ? i2 : ix) : i3;
                m2 = b2 ? (b1 ? m1 : v) : m2;  i2 = b2 ? (b1 ? i1 : ix) : i2;
                m1 = b1 ? (b0 ? m0 : v) : m1;  i1 = b1 ? (b0 ? i0 : ix) : i1;
                m0 = b0 ? v : m0;              i0 = b0 ? ix : i0;
            }
        int base = (blockIdx.y * NVc + gp) * 4;
        dIdx[base + 0] = i0; dIdx[base + 1] = i1; dIdx[base + 2] = i2; dIdx[base + 3] = i3;
    }
}

// ---------------- fp64 re-rank of 64 candidates -> exact top-3 ----------------
__global__ __launch_bounds__(256) void k_rerank(const float* __restrict__ pillar,
                                                const int* __restrict__ coords,
                                                const float* __restrict__ pfeat,
                                                const float* __restrict__ pcoord,
                                                const int* __restrict__ sIdx,
                                                const int* __restrict__ dIdx,
                                                int* __restrict__ idx_f,
                                                int* __restrict__ idx_c) {
    int t = threadIdx.x;
    int wv = t >> 6, l = t & 63;
    int v = blockIdx.x * 4 + wv;
    int chunk = l >> 2, slot = l & 3;
    int ps = sIdx[(chunk * NVc + v) * 4 + slot];
    int pd = dIdx[(chunk * NVc + v) * 4 + slot];
    double s = 0.0;
#pragma unroll
    for (int i = 0; i < 16; ++i) {
        float4 a = *(const float4*)(pillar + v * 64 + 4 * i);
        float4 b = *(const float4*)(pfeat + ps * 64 + 4 * i);
        s += (double)a.x * (double)b.x + (double)a.y * (double)b.y
           + (double)a.z * (double)b.z + (double)a.w * (double)b.w;
    }
    float4 qc = *(const float4*)(pcoord + pd * 4);
    double db_ = (double)coords[v * 4 + 0] - (double)qc.x;
    double dx_ = (double)coords[v * 4 + 1] - (double)qc.y;
    double dy_ = (double)coords[v * 4 + 2] - (double)qc.z;
    double dz_ = (double)coords[v * 4 + 3] - (double)qc.w;
    double d2 = db_ * db_ + dx_ * dx_ + dy_ * dy_ + dz_ * dz_;
    double sv = s; int sx = ps;
    for (int k = 0; k < 3; ++k) {
        double bv = sv; int bi = sx;
#pragma unroll
        for (int off = 32; off >= 1; off >>= 1) {
            double ov = __shfl_xor(bv, off);
            int    oi = __shfl_xor(bi, off);
            if (ov > bv || (ov == bv && oi < bi)) { bv = ov; bi = oi; }
        }
        if (l == 0) idx_f[v * 3 + k] = bi;
        if (sx == bi) { sv = -INFINITY; sx = 0x7fffffff; }
    }
    double dv = d2; int dx2 = pd;
    for (int k = 0; k < 3; ++k) {
        double bv = dv; int bi = dx2;
#pragma unroll
        for (int off = 32; off >= 1; off >>= 1) {
            double ov = __shfl_xor(bv, off);
            int    oi = __shfl_xor(bi, off);
            if (ov < bv || (ov == bv && oi < bi)) { bv = ov; bi = oi; }
        }
        if (l == 0) idx_c[v * 3 + k] = bi;
        if (dx2 == bi) { dv = INFINITY; dx2 = 0x7fffffff; }
    }
}

// ---------------- gather-add + w logits + BN partial sums ----------------
__global__ __launch_bounds__(256) void k_gather(const float* __restrict__ Q,
                                                const int* __restrict__ idx_f,
                                                const int* __restrict__ idx_c,
                                                const float* __restrict__ pillar,
                                                const float* __restrict__ ww,
                                                float* __restrict__ f_pre,
                                                float* __restrict__ c_pre,
                                                float* __restrict__ w_pre,
                                                float* __restrict__ stats) {
    __shared__ float red[4][4][64];
    __shared__ float redw[4][4];
    int t = threadIdx.x;
    int wv = t >> 6, l = t & 63;
    int base = blockIdx.x * 250;
    int vend = base + 250;
    float fs = 0, fq = 0, cs = 0, cq = 0, ws0 = 0, wq0 = 0, ws1 = 0, wq1 = 0;
    float w0l = ww[l], w1l = ww[64 + l];
    for (int v = base + wv; v < vend; v += 4) {
        int if0 = idx_f[v * 3], if1 = idx_f[v * 3 + 1], if2 = idx_f[v * 3 + 2];
        float f = Q[if0 * 192 + l] + Q[if1 * 192 + 64 + l] + Q[if2 * 192 + 128 + l];
        f_pre[v * 64 + l] = f; fs += f; fq += f * f;
        int ic0 = idx_c[v * 3], ic1 = idx_c[v * 3 + 1], ic2 = idx_c[v * 3 + 2];
        float c = Q[ic0 * 192 + l] + Q[ic1 * 192 + 64 + l] + Q[ic2 * 192 + 128 + l];
        c_pre[v * 64 + l] = c; cs += c; cq += c * c;
        float pv = pillar[v * 64 + l];
        float a0 = pv * w0l, a1 = pv * w1l;
#pragma unroll
        for (int off = 32; off >= 1; off >>= 1) {
            a0 += __shfl_xor(a0, off);
            a1 += __shfl_xor(a1, off);
        }
        if (l == 0) { w_pre[v * 2] = a0; w_pre[v * 2 + 1] = a1; }
        ws0 += a0; wq0 += a0 * a0; ws1 += a1; wq1 += a1 * a1;
    }
    red[0][wv][l] = fs; red[1][wv][l] = fq; red[2][wv][l] = cs; red[3][wv][l] = cq;
    if (l == 0) { redw[wv][0] = ws0; redw[wv][1] = wq0; redw[wv][2] = ws1; redw[wv][3] = wq1; }
    __syncthreads();
    if (wv == 0) {
#pragma unroll
        for (int q = 0; q < 4; ++q) {
            float sum = red[q][0][l] + red[q][1][l] + red[q][2][l] + red[q][3][l];
            atomicAdd(&stats[q * 64 + l], sum);
        }
        if (l < 4) {
            float sum = redw[0][l] + redw[1][l] + redw[2][l] + redw[3][l];
            atomicAdd(&stats[256 + l], sum);
        }
    }
}

// ---------------- BN finalize + softmax weights + scatter ----------------
__global__ __launch_bounds__(256) void k_final(const float* __restrict__ f_pre,
                                               const float* __restrict__ c_pre,
                                               const float* __restrict__ w_pre,
                                               const float* __restrict__ stats,
                                               const float* __restrict__ pillar,
                                               const int* __restrict__ coords,
                                               const float* __restrict__ g1,
                                               const float* __restrict__ b1,
                                               const float* __restrict__ g2,
                                               const float* __restrict__ b2,
                                               float* __restrict__ out) {
    int t = threadIdx.x;
    int wv = t >> 6, l = t & 63;
    int v = blockIdx.x * 4 + wv;
    const float invn = 1.0f / (float)NVc;
    float mf = stats[l] * invn;
    float vf = stats[64 + l] * invn - mf * mf;
    float rf = rsqrtf(vf + 1e-3f);
    float mc = stats[128 + l] * invn;
    float vc = stats[192 + l] * invn - mc * mc;
    float rc = rsqrtf(vc + 1e-3f);
    float mw0 = stats[256] * invn, vw0 = stats[257] * invn - mw0 * mw0;
    float mw1 = stats[258] * invn, vw1 = stats[259] * invn - mw1 * mw1;
    float rw0 = rsqrtf(vw0 + 1e-3f), rw1 = rsqrtf(vw1 + 1e-3f);
    float fb = (f_pre[v * 64 + l] - mf) * rf * g1[l] + b1[l];
    float f = fmaxf(fb, 0.f);
    float cb_ = (c_pre[v * 64 + l] - mc) * rc * g1[l] + b1[l];
    float c = fmaxf(cb_, 0.f);
    float z0 = (w_pre[v * 2] - mw0) * rw0 * g2[0] + b2[0];
    float z1 = (w_pre[v * 2 + 1] - mw1) * rw1 * g2[1] + b2[1];
    float mz = fmaxf(z0, z1);
    float e0 = __expf(z0 - mz), e1 = __expf(z1 - mz);
    float wd = 1.f / (e0 + e1);
    float aug = (e0 * wd) * f + (e1 * wd) * c;
    int cxi = coords[v * 4 + 1], cyi = coords[v * 4 + 2], czi = coords[v * 4 + 3];
    int cell = cxi + cyi * NXc + czi;
    out[l * CELLS + cell] = pillar[v * 64 + l];
    out[(64 + l) * CELLS + cell] = aug;
    if (l == 0) {
        float* o1 = out + 128 * CELLS;
        o1[cell] = (float)cyi;
        o1[CELLS + cell] = (float)czi;
        o1[2 * CELLS + cell] = (float)cxi;
    }
}

extern "C" void kernel_launch(void* const* d_in, const int* in_sizes, int n_in,
                              void* d_out, int out_size, void* d_ws, size_t ws_size,
                              hipStream_t stream) {
    const float* pillar = (const float*)d_in[0];
    const int*   coords = (const int*)d_in[1];
    const float* pfeat  = (const float*)d_in[2];
    const float* pcoord = (const float*)d_in[3];
    const float* adapt  = (const float*)d_in[4];
    const float* bn1g   = (const float*)d_in[5];
    const float* bn1b   = (const float*)d_in[6];
    const float* ww     = (const float*)d_in[7];
    const float* bn2g   = (const float*)d_in[8];
    const float* bn2b   = (const float*)d_in[9];
    const float* memw   = (const float*)d_in[10];
    float* out = (float*)d_out;
    float* ws  = (float*)d_ws;
    // workspace layout (float offsets)
    float* Pout  = ws + 0;                 // 1,048,576
    float* Q     = ws + 1048576;           // 3,145,728
    int*   sIdx  = (int*)(ws + 4194304);   // 640,000
    int*   dIdx  = (int*)(ws + 4834304);   // 640,000
    int*   idxf  = (int*)(ws + 5474304);   // 30,000
    int*   idxc  = (int*)(ws + 5504304);   // 30,000
    float* fpre  = ws + 5534304;           // 640,000 (bf16 bufs overlap here until k_gather)
    float* cpre  = ws + 6174304;           // 640,000
    float* wpre  = ws + 6814304;           // 20,000
    float* stats = ws + 6834304;           // 260
    // bf16 feature buffers overlap fpre/cpre region (dead before k_gather writes them)
    u16* pillarH = (u16*)(ws + 5534304);           // 643,072 u16
    u16* pfeatH  = pillarH + (size_t)NVPAD * 64;   // 1,048,576 u16

    k_zero  <<<4096, 256, 0, stream>>>(out, out_size, stats);
    k_cast  <<<6608, 256, 0, stream>>>(pillar, pfeat, pillarH, pfeatH);
    k_score2<<<dim3(157, 16), 256, 0, stream>>>(pillarH, pfeatH, coords, pcoord, sIdx, dIdx);
    k_rerank<<<2500, 256, 0, stream>>>(pillar, coords, pfeat, pcoord, sIdx, dIdx, idxf, idxc);
    k_mem   <<<2048, 256, 0, stream>>>(pfeat, memw, Pout);
    k_proj  <<<512,  256, 0, stream>>>(Pout, adapt, Q);
    k_gather<<<40,   256, 0, stream>>>(Q, idxf, idxc, pillar, ww, fpre, cpre, wpre, stats);
    k_final <<<2500, 256, 0, stream>>>(fpre, cpre, wpre, stats, pillar, coords,
                                       bn1g, bn1b, bn2g, bn2b, out);
}

// Round 3
// 608.334 us; speedup vs baseline: 2.2186x; 1.1941x over previous
//
#include <hip/hip_runtime.h>
#include <math.h>

#define NXc 432
#define NYc 496
#define NVc 10000
#define NPc 16384
#define CELLS (NXc*NYc)          // 214272
#define SHRINKc 0.0025f
#define NVPAD 10048              // 157*64

typedef unsigned short u16;
typedef __attribute__((ext_vector_type(8))) short s16x8;   // 8 bf16
typedef __attribute__((ext_vector_type(4))) float f32x4;

// ---------------- zero output + stats ----------------
__global__ void k_zero(float* __restrict__ out, int n, float* __restrict__ stats) {
    int gid = blockIdx.x * blockDim.x + threadIdx.x;
    int n4 = n >> 2;
    float4 z = make_float4(0.f, 0.f, 0.f, 0.f);
    float4* o4 = (float4*)out;
    for (int i = gid; i < n4; i += gridDim.x * blockDim.x) o4[i] = z;
    int tail = n & 3;
    if (gid < tail) out[n4 * 4 + gid] = 0.f;
    if (gid < 260) stats[gid] = 0.f;
}

// ---------------- fp32 -> bf16 (RNE) cast of pillar + point features ----------------
__device__ __forceinline__ u16 f2b(float x) {
    unsigned u = __float_as_uint(x);
    unsigned r = (u + 0x7fffu + ((u >> 16) & 1u)) >> 16;
    return (u16)r;
}
__global__ __launch_bounds__(256) void k_cast(const float* __restrict__ pillar,
                                              const float* __restrict__ pfeat,
                                              u16* __restrict__ pillarH,
                                              u16* __restrict__ pfeatH) {
    int idx = blockIdx.x * 256 + threadIdx.x;      // 6608 blocks * 256 = 1691648 exactly
    const int N1 = NVPAD * 64;                     // 643072
    if (idx < N1) {
        int v = idx >> 6;
        float x = (v < NVc) ? pillar[idx] : 0.f;
        pillarH[idx] = f2b(x);
    } else {
        int j = idx - N1;
        pfeatH[j] = f2b(pfeat[j]);
    }
}

// ---------------- memory_lookup for ALL 16384 points ----------------
__global__ __launch_bounds__(256) void k_mem(const float* __restrict__ pfeat,
                                             const float* __restrict__ memw,
                                             float* __restrict__ Pout) {
    __shared__ float X[8][64];
    __shared__ float att[8][1024];
    __shared__ float Wt[64][68];
    int t = threadIdx.x;
    int pbase = blockIdx.x * 8;
    if (t < 128) {
        int p = t >> 4, d = (t & 15) << 2;
        *(float4*)&X[p][d] = *(const float4*)(pfeat + (pbase + p) * 64 + d);
    }
    __syncthreads();
    int wv = t >> 6, l = t & 63;
    int p0 = wv * 2, p1 = wv * 2 + 1;
    for (int mt = 0; mt < 16; ++mt) {
#pragma unroll
        for (int r = 0; r < 4; ++r) {
            int q = t + 256 * r;
            int m = q >> 4, d = (q & 15) << 2;
            *(float4*)&Wt[m][d] = *(const float4*)(memw + (mt * 64 + m) * 64 + d);
        }
        __syncthreads();
        float a0 = 0.f, a1 = 0.f;
#pragma unroll
        for (int i = 0; i < 16; ++i) {
            float4 x0 = *(const float4*)&X[p0][4 * i];
            float4 x1 = *(const float4*)&X[p1][4 * i];
            float4 w  = *(const float4*)&Wt[l][4 * i];
            a0 += x0.x * w.x + x0.y * w.y + x0.z * w.z + x0.w * w.w;
            a1 += x1.x * w.x + x1.y * w.y + x1.z * w.z + x1.w * w.w;
        }
        att[p0][mt * 64 + l] = a0;
        att[p1][mt * 64 + l] = a1;
        __syncthreads();
    }
    {
        int ps = wv * 2 + (l >> 5);
        int il = l & 31;
        float* ar = att[ps];
        float mx = -INFINITY;
#pragma unroll
        for (int j = 0; j < 32; ++j) mx = fmaxf(mx, ar[il + 32 * j]);
#pragma unroll
        for (int off = 16; off >= 1; off >>= 1) mx = fmaxf(mx, __shfl_xor(mx, off));
        float s = 0.f;
#pragma unroll
        for (int j = 0; j < 32; ++j) {
            float e = __expf(ar[il + 32 * j] - mx);
            ar[il + 32 * j] = e; s += e;
        }
#pragma unroll
        for (int off = 16; off >= 1; off >>= 1) s += __shfl_xor(s, off);
        float inv_s = 1.f / s;
        float s2 = 0.f;
#pragma unroll
        for (int j = 0; j < 32; ++j) {
            float a = ar[il + 32 * j] * inv_s;
            float tt = a - SHRINKc;
            float r2 = fmaxf(tt, 0.f) * a / (fabsf(tt) + 1e-12f);
            ar[il + 32 * j] = r2; s2 += r2;
        }
#pragma unroll
        for (int off = 16; off >= 1; off >>= 1) s2 += __shfl_xor(s2, off);
        float inv2 = 1.f / fmaxf(s2, 1e-12f);
#pragma unroll
        for (int j = 0; j < 32; ++j) ar[il + 32 * j] *= inv2;
    }
    __syncthreads();
    float o0 = 0.f, o1 = 0.f;
    for (int mt = 0; mt < 16; ++mt) {
#pragma unroll
        for (int r = 0; r < 4; ++r) {
            int q = t + 256 * r;
            int m = q >> 4, d = (q & 15) << 2;
            *(float4*)&Wt[m][d] = *(const float4*)(memw + (mt * 64 + m) * 64 + d);
        }
        __syncthreads();
        const float* a0r = &att[p0][mt * 64];
        const float* a1r = &att[p1][mt * 64];
#pragma unroll
        for (int m = 0; m < 64; ++m) {
            float w = Wt[m][l];
            o0 += a0r[m] * w;
            o1 += a1r[m] * w;
        }
        __syncthreads();
    }
    Pout[(pbase + p0) * 64 + l] = o0;
    Pout[(pbase + p1) * 64 + l] = o1;
}

// ---------------- Q[p][k*64+j] = sum_d Pout[p][d] * adapt[j][k*64+d] ----------------
__global__ __launch_bounds__(256) void k_proj(const float* __restrict__ Pout,
                                              const float* __restrict__ adapt,
                                              float* __restrict__ Q) {
    __shared__ float Xs[32][65];
    __shared__ float As[64][197];
    int t = threadIdx.x;
    int pb = blockIdx.x * 32;
#pragma unroll
    for (int r = 0; r < 2; ++r) {
        int q = t + 256 * r;
        int p = q >> 4, d = (q & 15) << 2;
        float4 v = *(const float4*)(Pout + (pb + p) * 64 + d);
        Xs[p][d] = v.x; Xs[p][d + 1] = v.y; Xs[p][d + 2] = v.z; Xs[p][d + 3] = v.w;
    }
#pragma unroll
    for (int r = 0; r < 12; ++r) {
        int q = t + 256 * r;
        int j = q / 48, i = (q % 48) << 2;
        float4 v = *(const float4*)(adapt + j * 192 + i);
        As[j][i] = v.x; As[j][i + 1] = v.y; As[j][i + 2] = v.z; As[j][i + 3] = v.w;
    }
    __syncthreads();
    int tr = t >> 4, tc = t & 15;
    float acc[2][12];
#pragma unroll
    for (int u = 0; u < 2; ++u)
#pragma unroll
        for (int cc = 0; cc < 12; ++cc) acc[u][cc] = 0.f;
    for (int d = 0; d < 64; ++d) {
        float xv0 = Xs[tr * 2 + 0][d];
        float xv1 = Xs[tr * 2 + 1][d];
#pragma unroll
        for (int cc = 0; cc < 12; ++cc) {
            int c = tc * 12 + cc;
            float a = As[c & 63][((c >> 6) << 6) + d];
            acc[0][cc] += xv0 * a;
            acc[1][cc] += xv1 * a;
        }
    }
#pragma unroll
    for (int u = 0; u < 2; ++u)
#pragma unroll
        for (int cc = 0; cc < 12; ++cc)
            Q[(pb + tr * 2 + u) * 192 + tc * 12 + cc] = acc[u][cc];
}

// ---------------- packed-key insertion networks ----------------
__device__ __forceinline__ void ins_max4(unsigned &k0, unsigned &k1, unsigned &k2,
                                         unsigned &k3, unsigned t) {
    unsigned n;
    n = k0 > t ? k0 : t;  t = k0 > t ? t : k0;  k0 = n;
    n = k1 > t ? k1 : t;  t = k1 > t ? t : k1;  k1 = n;
    n = k2 > t ? k2 : t;  t = k2 > t ? t : k2;  k2 = n;
    k3 = k3 > t ? k3 : t;
}
__device__ __forceinline__ void ins_min4(unsigned &k0, unsigned &k1, unsigned &k2,
                                         unsigned &k3, unsigned t) {
    unsigned n;
    n = k0 < t ? k0 : t;  t = k0 < t ? t : k0;  k0 = n;
    n = k1 < t ? k1 : t;  t = k1 < t ? t : k1;  k1 = n;
    n = k2 < t ? k2 : t;  t = k2 < t ? t : k2;  k2 = n;
    k3 = k3 < t ? k3 : t;
}

// ---------------- MFMA score + dist candidate top-4, register-resident ----------------
// grid (157 pillar-tiles, 16 chunks), block 256 (4 waves). 64 pillars x 1024 points.
__global__ __launch_bounds__(256) void k_score3(const u16* __restrict__ pillarH,
                                                const u16* __restrict__ pfeatH,
                                                const int* __restrict__ coords,
                                                const float* __restrict__ pcoord,
                                                int* __restrict__ sIdx,
                                                int* __restrict__ dIdx) {
    __shared__ u16 BF[8192];            // 16 KB: [pt][g][lm^g][8] swizzled fragments
    __shared__ float4 PCs[128];         // 2 KB
    __shared__ unsigned mrg[4096];      // 16 KB merge scratch

    int t = threadIdx.x;
    int w = t >> 6, l = t & 63;
    int lm = l & 15, qd = l >> 4;
    int pb = blockIdx.x * 64;
    int cb = blockIdx.y * 1024;

    // A fragments: wave w owns pillar rows pb+16w .. pb+16w+15
    const u16* arow = pillarH + (size_t)(pb + 16 * w + lm) * 64 + qd * 8;
    s16x8 a0 = *(const s16x8*)arow;
    s16x8 a1 = *(const s16x8*)(arow + 32);

    // pillar coords (lane = pillar). b and z are structurally 0 for pillars;
    // point b is structurally 0 -> d2 = (x-qx)^2 + (y-qy)^2 + qz^2.
    int gp = pb + l;
    int gpc = gp < NVc ? gp : 0;
    float cxf = (float)coords[gpc * 4 + 1];
    float cyf = (float)coords[gpc * 4 + 2];

    unsigned sk[4][4];                   // per acc-row: desc-sorted score keys
#pragma unroll
    for (int r = 0; r < 4; ++r)
#pragma unroll
        for (int j = 0; j < 4; ++j) sk[r][j] = 0u;
    unsigned dk0 = 0xFFFFFFFFu, dk1 = 0xFFFFFFFFu, dk2 = 0xFFFFFFFFu, dk3 = 0xFFFFFFFFu;

    for (int s = 0; s < 8; ++s) {
        int ptb = cb + s * 128;
        // ---- stage B fragments (xor-swizzled) + point coords ----
#pragma unroll
        for (int r = 0; r < 4; ++r) {
            int q = t + 256 * r;            // 0..1023: 128 rows x 8 granules
            int row = q >> 3, g = q & 7;
            uint4 v = *(const uint4*)(pfeatH + (size_t)(ptb + row) * 64 + g * 8);
            int pt = row >> 4, lmr = row & 15;
            *(uint4*)&BF[(((pt * 8 + g) * 16) + (lmr ^ g)) * 8] = v;
        }
        if (t < 128) PCs[t] = *(const float4*)(pcoord + (size_t)(ptb + t) * 4);
        __syncthreads();
        // ---- MFMA + in-register score top-4 ----
#pragma unroll
        for (int pt = 0; pt < 8; ++pt) {
            s16x8 b0 = *(const s16x8*)&BF[(((pt * 8 + qd) * 16) + (lm ^ qd)) * 8];
            s16x8 b1 = *(const s16x8*)&BF[(((pt * 8 + qd + 4) * 16) + (lm ^ (qd + 4))) * 8];
            f32x4 acc = {0.f, 0.f, 0.f, 0.f};
            acc = __builtin_amdgcn_mfma_f32_16x16x32_bf16(a0, b0, acc, 0, 0, 0);
            acc = __builtin_amdgcn_mfma_f32_16x16x32_bf16(a1, b1, acc, 0, 0, 0);
            unsigned idf = (unsigned)(1023 - (s * 128 + pt * 16 + lm));
#pragma unroll
            for (int r = 0; r < 4; ++r) {
                int b = __float_as_int(acc[r]);
                unsigned mask = ((unsigned)(b >> 31)) | 0x80000000u;
                unsigned key = ((((unsigned)b) ^ mask) & 0xFFFFFC00u) | idf;
                ins_max4(sk[r][0], sk[r][1], sk[r][2], sk[r][3], key);
            }
        }
        // ---- dist top-4 (lane = pillar, wave w covers its 32-point quarter) ----
#pragma unroll 4
        for (int i = 0; i < 32; ++i) {
            int jl = w * 32 + i;
            float4 pc = PCs[jl];
            float e1 = cxf - pc.y, e2 = cyf - pc.z;
            float d2 = fmaf(e1, e1, fmaf(e2, e2, pc.w * pc.w));
            unsigned key = (__float_as_uint(d2) & 0xFFFFFC00u) | (unsigned)(s * 128 + jl);
            ins_min4(dk0, dk1, dk2, dk3, key);
        }
        __syncthreads();
    }
    // ---- merge score keys: dump 4 rows x 4 keys per lane ----
#pragma unroll
    for (int r = 0; r < 4; ++r) {
        int row = 16 * w + qd * 4 + r;
        *(uint4*)&mrg[(row * 16 + lm) * 4] = make_uint4(sk[r][0], sk[r][1], sk[r][2], sk[r][3]);
    }
    __syncthreads();
    if (t < 64) {
        int row = t, gpr = pb + row;
        unsigned m0 = 0u, m1 = 0u, m2 = 0u, m3 = 0u;
#pragma unroll 4
        for (int cc = 0; cc < 16; ++cc) {
            uint4 v = *(const uint4*)&mrg[(row * 16 + cc) * 4];
            ins_max4(m0, m1, m2, m3, v.x);
            ins_max4(m0, m1, m2, m3, v.y);
            ins_max4(m0, m1, m2, m3, v.z);
            ins_max4(m0, m1, m2, m3, v.w);
        }
        if (gpr < NVc) {
            int base = (blockIdx.y * NVc + gpr) * 4;
            sIdx[base + 0] = cb + 1023 - (int)(m0 & 1023u);
            sIdx[base + 1] = cb + 1023 - (int)(m1 & 1023u);
            sIdx[base + 2] = cb + 1023 - (int)(m2 & 1023u);
            sIdx[base + 3] = cb + 1023 - (int)(m3 & 1023u);
        }
    }
    __syncthreads();
    // ---- merge dist keys: 4 wave-partials per pillar ----
    *(uint4*)&mrg[(w * 64 + l) * 4] = make_uint4(dk0, dk1, dk2, dk3);
    __syncthreads();
    if (t < 64) {
        int gpr = pb + t;
        unsigned m0 = 0xFFFFFFFFu, m1 = 0xFFFFFFFFu, m2 = 0xFFFFFFFFu, m3 = 0xFFFFFFFFu;
#pragma unroll
        for (int ww = 0; ww < 4; ++ww) {
            uint4 v = *(const uint4*)&mrg[(ww * 64 + t) * 4];
            ins_min4(m0, m1, m2, m3, v.x);
            ins_min4(m0, m1, m2, m3, v.y);
            ins_min4(m0, m1, m2, m3, v.z);
            ins_min4(m0, m1, m2, m3, v.w);
        }
        if (gpr < NVc) {
            int base = (blockIdx.y * NVc + gpr) * 4;
            dIdx[base + 0] = cb + (int)(m0 & 1023u);
            dIdx[base + 1] = cb + (int)(m1 & 1023u);
            dIdx[base + 2] = cb + (int)(m2 & 1023u);
            dIdx[base + 3] = cb + (int)(m3 & 1023u);
        }
    }
}

// ---------------- fp64 re-rank of 64 candidates -> exact top-3 ----------------
__global__ __launch_bounds__(256) void k_rerank(const float* __restrict__ pillar,
                                                const int* __restrict__ coords,
                                                const float* __restrict__ pfeat,
                                                const float* __restrict__ pcoord,
                                                const int* __restrict__ sIdx,
                                                const int* __restrict__ dIdx,
                                                int* __restrict__ idx_f,
                                                int* __restrict__ idx_c) {
    int t = threadIdx.x;
    int wv = t >> 6, l = t & 63;
    int v = blockIdx.x * 4 + wv;
    int chunk = l >> 2, slot = l & 3;
    int ps = sIdx[(chunk * NVc + v) * 4 + slot];
    int pd = dIdx[(chunk * NVc + v) * 4 + slot];
    double s = 0.0;
#pragma unroll
    for (int i = 0; i < 16; ++i) {
        float4 a = *(const float4*)(pillar + v * 64 + 4 * i);
        float4 b = *(const float4*)(pfeat + ps * 64 + 4 * i);
        s += (double)a.x * (double)b.x + (double)a.y * (double)b.y
           + (double)a.z * (double)b.z + (double)a.w * (double)b.w;
    }
    float4 qc = *(const float4*)(pcoord + pd * 4);
    double db_ = (double)coords[v * 4 + 0] - (double)qc.x;
    double dx_ = (double)coords[v * 4 + 1] - (double)qc.y;
    double dy_ = (double)coords[v * 4 + 2] - (double)qc.z;
    double dz_ = (double)coords[v * 4 + 3] - (double)qc.w;
    double d2 = db_ * db_ + dx_ * dx_ + dy_ * dy_ + dz_ * dz_;
    double sv = s; int sx = ps;
    for (int k = 0; k < 3; ++k) {
        double bv = sv; int bi = sx;
#pragma unroll
        for (int off = 32; off >= 1; off >>= 1) {
            double ov = __shfl_xor(bv, off);
            int    oi = __shfl_xor(bi, off);
            if (ov > bv || (ov == bv && oi < bi)) { bv = ov; bi = oi; }
        }
        if (l == 0) idx_f[v * 3 + k] = bi;
        if (sx == bi) { sv = -INFINITY; sx = 0x7fffffff; }
    }
    double dv = d2; int dx2 = pd;
    for (int k = 0; k < 3; ++k) {
        double bv = dv; int bi = dx2;
#pragma unroll
        for (int off = 32; off >= 1; off >>= 1) {
            double ov = __shfl_xor(bv, off);
            int    oi = __shfl_xor(bi, off);
            if (ov < bv || (ov == bv && oi < bi)) { bv = ov; bi = oi; }
        }
        if (l == 0) idx_c[v * 3 + k] = bi;
        if (dx2 == bi) { dv = INFINITY; dx2 = 0x7fffffff; }
    }
}

// ---------------- gather-add + w logits + BN partial sums ----------------
__global__ __launch_bounds__(256) void k_gather(const float* __restrict__ Q,
                                                const int* __restrict__ idx_f,
                                                const int* __restrict__ idx_c,
                                                const float* __restrict__ pillar,
                                                const float* __restrict__ ww,
                                                float* __restrict__ f_pre,
                                                float* __restrict__ c_pre,
                                                float* __restrict__ w_pre,
                                                float* __restrict__ stats) {
    __shared__ float red[4][4][64];
    __shared__ float redw[4][4];
    int t = threadIdx.x;
    int wv = t >> 6, l = t & 63;
    int base = blockIdx.x * 250;
    int vend = base + 250;
    float fs = 0, fq = 0, cs = 0, cq = 0, ws0 = 0, wq0 = 0, ws1 = 0, wq1 = 0;
    float w0l = ww[l], w1l = ww[64 + l];
    for (int v = base + wv; v < vend; v += 4) {
        int if0 = idx_f[v * 3], if1 = idx_f[v * 3 + 1], if2 = idx_f[v * 3 + 2];
        float f = Q[if0 * 192 + l] + Q[if1 * 192 + 64 + l] + Q[if2 * 192 + 128 + l];
        f_pre[v * 64 + l] = f; fs += f; fq += f * f;
        int ic0 = idx_c[v * 3], ic1 = idx_c[v * 3 + 1], ic2 = idx_c[v * 3 + 2];
        float c = Q[ic0 * 192 + l] + Q[ic1 * 192 + 64 + l] + Q[ic2 * 192 + 128 + l];
        c_pre[v * 64 + l] = c; cs += c; cq += c * c;
        float pv = pillar[v * 64 + l];
        float a0 = pv * w0l, a1 = pv * w1l;
#pragma unroll
        for (int off = 32; off >= 1; off >>= 1) {
            a0 += __shfl_xor(a0, off);
            a1 += __shfl_xor(a1, off);
        }
        if (l == 0) { w_pre[v * 2] = a0; w_pre[v * 2 + 1] = a1; }
        ws0 += a0; wq0 += a0 * a0; ws1 += a1; wq1 += a1 * a1;
    }
    red[0][wv][l] = fs; red[1][wv][l] = fq; red[2][wv][l] = cs; red[3][wv][l] = cq;
    if (l == 0) { redw[wv][0] = ws0; redw[wv][1] = wq0; redw[wv][2] = ws1; redw[wv][3] = wq1; }
    __syncthreads();
    if (wv == 0) {
#pragma unroll
        for (int q = 0; q < 4; ++q) {
            float sum = red[q][0][l] + red[q][1][l] + red[q][2][l] + red[q][3][l];
            atomicAdd(&stats[q * 64 + l], sum);
        }
        if (l < 4) {
            float sum = redw[0][l] + redw[1][l] + redw[2][l] + redw[3][l];
            atomicAdd(&stats[256 + l], sum);
        }
    }
}

// ---------------- BN finalize + softmax weights + scatter ----------------
__global__ __launch_bounds__(256) void k_final(const float* __restrict__ f_pre,
                                               const float* __restrict__ c_pre,
                                               const float* __restrict__ w_pre,
                                               const float* __restrict__ stats,
                                               const float* __restrict__ pillar,
                                               const int* __restrict__ coords,
                                               const float* __restrict__ g1,
                                               const float* __restrict__ b1,
                                               const float* __restrict__ g2,
                                               const float* __restrict__ b2,
                                               float* __restrict__ out) {
    int t = threadIdx.x;
    int wv = t >> 6, l = t & 63;
    int v = blockIdx.x * 4 + wv;
    const float invn = 1.0f / (float)NVc;
    float mf = stats[l] * invn;
    float vf = stats[64 + l] * invn - mf * mf;
    float rf = rsqrtf(vf + 1e-3f);
    float mc = stats[128 + l] * invn;
    float vc = stats[192 + l] * invn - mc * mc;
    float rc = rsqrtf(vc + 1e-3f);
    float mw0 = stats[256] * invn, vw0 = stats[257] * invn - mw0 * mw0;
    float mw1 = stats[258] * invn, vw1 = stats[259] * invn - mw1 * mw1;
    float rw0 = rsqrtf(vw0 + 1e-3f), rw1 = rsqrtf(vw1 + 1e-3f);
    float fb = (f_pre[v * 64 + l] - mf) * rf * g1[l] + b1[l];
    float f = fmaxf(fb, 0.f);
    float cb_ = (c_pre[v * 64 + l] - mc) * rc * g1[l] + b1[l];
    float c = fmaxf(cb_, 0.f);
    float z0 = (w_pre[v * 2] - mw0) * rw0 * g2[0] + b2[0];
    float z1 = (w_pre[v * 2 + 1] - mw1) * rw1 * g2[1] + b2[1];
    float mz = fmaxf(z0, z1);
    float e0 = __expf(z0 - mz), e1 = __expf(z1 - mz);
    float wd = 1.f / (e0 + e1);
    float aug = (e0 * wd) * f + (e1 * wd) * c;
    int cxi = coords[v * 4 + 1], cyi = coords[v * 4 + 2], czi = coords[v * 4 + 3];
    int cell = cxi + cyi * NXc + czi;
    out[l * CELLS + cell] = pillar[v * 64 + l];
    out[(64 + l) * CELLS + cell] = aug;
    if (l == 0) {
        float* o1 = out + 128 * CELLS;
        o1[cell] = (float)cyi;
        o1[CELLS + cell] = (float)czi;
        o1[2 * CELLS + cell] = (float)cxi;
    }
}

extern "C" void kernel_launch(void* const* d_in, const int* in_sizes, int n_in,
                              void* d_out, int out_size, void* d_ws, size_t ws_size,
                              hipStream_t stream) {
    const float* pillar = (const float*)d_in[0];
    const int*   coords = (const int*)d_in[1];
    const float* pfeat  = (const float*)d_in[2];
    const float* pcoord = (const float*)d_in[3];
    const float* adapt  = (const float*)d_in[4];
    const float* bn1g   = (const float*)d_in[5];
    const float* bn1b   = (const float*)d_in[6];
    const float* ww     = (const float*)d_in[7];
    const float* bn2g   = (const float*)d_in[8];
    const float* bn2b   = (const float*)d_in[9];
    const float* memw   = (const float*)d_in[10];
    float* out = (float*)d_out;
    float* ws  = (float*)d_ws;
    // workspace layout (float offsets)
    float* Pout  = ws + 0;                 // 1,048,576
    float* Q     = ws + 1048576;           // 3,145,728
    int*   sIdx  = (int*)(ws + 4194304);   // 640,000
    int*   dIdx  = (int*)(ws + 4834304);   // 640,000
    int*   idxf  = (int*)(ws + 5474304);   // 30,000
    int*   idxc  = (int*)(ws + 5504304);   // 30,000
    float* fpre  = ws + 5534304;           // 640,000 (bf16 bufs overlap here until k_gather)
    float* cpre  = ws + 6174304;           // 640,000
    float* wpre  = ws + 6814304;           // 20,000
    float* stats = ws + 6834304;           // 260
    // bf16 feature buffers overlap fpre/cpre region (dead before k_gather writes them)
    u16* pillarH = (u16*)(ws + 5534304);           // 643,072 u16
    u16* pfeatH  = pillarH + (size_t)NVPAD * 64;   // 1,048,576 u16

    k_zero  <<<4096, 256, 0, stream>>>(out, out_size, stats);
    k_cast  <<<6608, 256, 0, stream>>>(pillar, pfeat, pillarH, pfeatH);
    k_score3<<<dim3(157, 16), 256, 0, stream>>>(pillarH, pfeatH, coords, pcoord, sIdx, dIdx);
    k_rerank<<<2500, 256, 0, stream>>>(pillar, coords, pfeat, pcoord, sIdx, dIdx, idxf, idxc);
    k_mem   <<<2048, 256, 0, stream>>>(pfeat, memw, Pout);
    k_proj  <<<512,  256, 0, stream>>>(Pout, adapt, Q);
    k_gather<<<40,   256, 0, stream>>>(Q, idxf, idxc, pillar, ww, fpre, cpre, wpre, stats);
    k_final <<<2500, 256, 0, stream>>>(fpre, cpre, wpre, stats, pillar, coords,
                                       bn1g, bn1b, bn2g, bn2b, out);
}

// Round 4
// 422.247 us; speedup vs baseline: 3.1964x; 1.4407x over previous
//
#include <hip/hip_runtime.h>
#include <math.h>

#define NXc 432
#define NYc 496
#define NVc 10000
#define NPc 16384
#define CELLS (NXc*NYc)          // 214272
#define SHRINKc 0.0025f
#define NVPAD 10048              // 157*64

typedef unsigned short u16;
typedef __attribute__((ext_vector_type(8))) short s16x8;   // 8 bf16
typedef __attribute__((ext_vector_type(4))) float f32x4;

// ---------------- zero output + stats ----------------
__global__ void k_zero(float* __restrict__ out, int n, float* __restrict__ stats) {
    int gid = blockIdx.x * blockDim.x + threadIdx.x;
    int n4 = n >> 2;
    float4 z = make_float4(0.f, 0.f, 0.f, 0.f);
    float4* o4 = (float4*)out;
    for (int i = gid; i < n4; i += gridDim.x * blockDim.x) o4[i] = z;
    int tail = n & 3;
    if (gid < tail) out[n4 * 4 + gid] = 0.f;
    if (gid < 260) stats[gid] = 0.f;
}

// ---------------- fp32 -> bf16 (RNE) casts ----------------
__device__ __forceinline__ u16 f2b(float x) {
    unsigned u = __float_as_uint(x);
    unsigned r = (u + 0x7fffu + ((u >> 16) & 1u)) >> 16;
    return (u16)r;
}
__global__ __launch_bounds__(256) void k_cast(const float* __restrict__ pillar,
                                              const float* __restrict__ pfeat,
                                              const float* __restrict__ memw,
                                              u16* __restrict__ pillarH,
                                              u16* __restrict__ pfeatH,
                                              u16* __restrict__ memwH,
                                              u16* __restrict__ memwTH) {
    int idx = blockIdx.x * 256 + threadIdx.x;      // 7120 * 256 = 1822720 exactly
    const int N1 = NVPAD * 64;                     // 643072
    const int N2 = N1 + NPc * 64;                  // 1691648
    const int N3 = N2 + 65536;                     // 1757184
    if (idx < N1) {
        int v = idx >> 6;
        pillarH[idx] = f2b(v < NVc ? pillar[idx] : 0.f);
    } else if (idx < N2) {
        int j = idx - N1;
        pfeatH[j] = f2b(pfeat[j]);
    } else if (idx < N3) {
        int j = idx - N2;
        memwH[j] = f2b(memw[j]);
    } else {
        int i = idx - N3;                          // 0..65535
        int d = i >> 10, j = i & 1023;
        memwTH[i] = f2b(memw[j * 64 + d]);         // memwT[d][j]
    }
}

// ---------------- MFMA streaming memory_lookup for all 16384 points ----------------
// Block = 64 points (wave w -> points 16w..16w+15). Grid 256.
// Pass 1: online softmax stats (m, Z) streaming memw in 8x128-row bf16 tiles.
// Pass 2: recompute logits, shrink, LDS transpose (C->A layout), out-MFMA, L1 renorm.
__global__ __launch_bounds__(256) void k_mem2(const u16* __restrict__ pfeatH,
                                              const u16* __restrict__ memwH,
                                              const u16* __restrict__ memwTH,
                                              float* __restrict__ Pout) {
    __shared__ u16 WH[8192];        // 16 KB: memw rows tile, xor-granule swizzled
    __shared__ u16 WT[8192];        // 16 KB: memwT rows tile, xor-granule swizzled
    __shared__ u16 ST[4][2048];     // 16 KB: per-wave s tile (16 pts x 128 mem)
    int t = threadIdx.x;
    int w = t >> 6, l = t & 63;
    int lm = l & 15, qd = l >> 4;
    int pb = blockIdx.x * 64;

    const u16* arow = pfeatH + (size_t)(pb + 16 * w + lm) * 64 + qd * 8;
    s16x8 a0 = *(const s16x8*)arow;
    s16x8 a1 = *(const s16x8*)(arow + 32);

    float mM[4] = {-INFINITY, -INFINITY, -INFINITY, -INFINITY};
    float Zs[4] = {0.f, 0.f, 0.f, 0.f};

    // ---- pass 1: logits -> online (max, sumexp) ----
    for (int tile = 0; tile < 8; ++tile) {
        __syncthreads();
#pragma unroll
        for (int r = 0; r < 4; ++r) {
            int q = t + 256 * r;
            int row = q >> 3, g = q & 7;
            uint4 v = *(const uint4*)(memwH + (size_t)(tile * 128 + row) * 64 + g * 8);
            *(uint4*)&WH[(((row >> 4) * 8 + g) * 16 + ((row & 15) ^ g)) * 8] = v;
        }
        __syncthreads();
        f32x4 acc[8];
#pragma unroll
        for (int st = 0; st < 8; ++st) {
            s16x8 b0 = *(const s16x8*)&WH[((st * 8 + qd) * 16 + (lm ^ qd)) * 8];
            s16x8 b1 = *(const s16x8*)&WH[((st * 8 + qd + 4) * 16 + (lm ^ (qd + 4))) * 8];
            f32x4 z = {0.f, 0.f, 0.f, 0.f};
            z = __builtin_amdgcn_mfma_f32_16x16x32_bf16(a0, b0, z, 0, 0, 0);
            z = __builtin_amdgcn_mfma_f32_16x16x32_bf16(a1, b1, z, 0, 0, 0);
            acc[st] = z;
        }
#pragma unroll
        for (int r = 0; r < 4; ++r) {
            float tmax = acc[0][r];
#pragma unroll
            for (int st = 1; st < 8; ++st) tmax = fmaxf(tmax, acc[st][r]);
            float mn = fmaxf(mM[r], tmax);
            float zacc = Zs[r] * __expf(mM[r] - mn);
#pragma unroll
            for (int st = 0; st < 8; ++st) zacc += __expf(acc[st][r] - mn);
            mM[r] = mn; Zs[r] = zacc;
        }
    }
    // reduce (m, Z) across the 16 lanes sharing each row group
#pragma unroll
    for (int r = 0; r < 4; ++r) {
#pragma unroll
        for (int off = 1; off < 16; off <<= 1) {
            float om = __shfl_xor(mM[r], off);
            float oz = __shfl_xor(Zs[r], off);
            float mn = fmaxf(mM[r], om);
            Zs[r] = Zs[r] * __expf(mM[r] - mn) + oz * __expf(om - mn);
            mM[r] = mn;
        }
    }
    float invZ[4], L1[4] = {0.f, 0.f, 0.f, 0.f};
#pragma unroll
    for (int r = 0; r < 4; ++r) invZ[r] = 1.f / Zs[r];

    f32x4 oacc[4];
#pragma unroll
    for (int n = 0; n < 4; ++n) oacc[n] = (f32x4){0.f, 0.f, 0.f, 0.f};

    // ---- pass 2: recompute, shrink, transpose via LDS, out-MFMA ----
    for (int tile = 0; tile < 8; ++tile) {
        __syncthreads();
#pragma unroll
        for (int r = 0; r < 4; ++r) {
            int q = t + 256 * r;
            int row = q >> 3, g = q & 7;
            uint4 v = *(const uint4*)(memwH + (size_t)(tile * 128 + row) * 64 + g * 8);
            *(uint4*)&WH[(((row >> 4) * 8 + g) * 16 + ((row & 15) ^ g)) * 8] = v;
        }
#pragma unroll
        for (int r = 0; r < 4; ++r) {
            int q = t + 256 * r;
            int row = q >> 4, g = q & 15;
            uint4 v = *(const uint4*)(memwTH + (size_t)row * 1024 + tile * 128 + g * 8);
            *(uint4*)&WT[(g * 64 + (row ^ g)) * 8] = v;
        }
        __syncthreads();
#pragma unroll
        for (int st = 0; st < 8; ++st) {
            s16x8 b0 = *(const s16x8*)&WH[((st * 8 + qd) * 16 + (lm ^ qd)) * 8];
            s16x8 b1 = *(const s16x8*)&WH[((st * 8 + qd + 4) * 16 + (lm ^ (qd + 4))) * 8];
            f32x4 z = {0.f, 0.f, 0.f, 0.f};
            z = __builtin_amdgcn_mfma_f32_16x16x32_bf16(a0, b0, z, 0, 0, 0);
            z = __builtin_amdgcn_mfma_f32_16x16x32_bf16(a1, b1, z, 0, 0, 0);
            int g2 = st * 2 + (lm >> 3);
#pragma unroll
            for (int r = 0; r < 4; ++r) {
                float e = __expf(z[r] - mM[r]);
                float a = e * invZ[r];
                float tt = a - SHRINKc;
                float sres = fmaxf(tt, 0.f) * a / (fabsf(tt) + 1e-12f);
                L1[r] += sres;
                int rr = qd * 4 + r;
                ST[w][(g2 * 16 + (rr ^ g2)) * 8 + (lm & 7)] = f2b(sres);
            }
        }
        // wave-private ST: program-order ds dependency, no block barrier needed
#pragma unroll
        for (int ks = 0; ks < 4; ++ks) {
            int g = ks * 4 + qd;
            s16x8 af = *(const s16x8*)&ST[w][(g * 16 + (lm ^ g)) * 8];
#pragma unroll
            for (int n = 0; n < 4; ++n) {
                s16x8 bf = *(const s16x8*)&WT[(g * 64 + ((n * 16 + lm) ^ g)) * 8];
                oacc[n] = __builtin_amdgcn_mfma_f32_16x16x32_bf16(af, bf, oacc[n], 0, 0, 0);
            }
        }
    }
    // L1 renorm + coalesced store
#pragma unroll
    for (int r = 0; r < 4; ++r) {
#pragma unroll
        for (int off = 1; off < 16; off <<= 1) L1[r] += __shfl_xor(L1[r], off);
        L1[r] = 1.f / fmaxf(L1[r], 1e-12f);
    }
#pragma unroll
    for (int n = 0; n < 4; ++n)
#pragma unroll
        for (int r = 0; r < 4; ++r)
            Pout[(size_t)(pb + 16 * w + qd * 4 + r) * 64 + n * 16 + lm] = oacc[n][r] * L1[r];
}

// ---------------- Q[p][k*64+j] = sum_d Pout[p][d] * adapt[j][k*64+d] ----------------
__global__ __launch_bounds__(256) void k_proj(const float* __restrict__ Pout,
                                              const float* __restrict__ adapt,
                                              float* __restrict__ Q) {
    __shared__ float Xs[32][65];
    __shared__ float As[64][197];
    int t = threadIdx.x;
    int pb = blockIdx.x * 32;
#pragma unroll
    for (int r = 0; r < 2; ++r) {
        int q = t + 256 * r;
        int p = q >> 4, d = (q & 15) << 2;
        float4 v = *(const float4*)(Pout + (pb + p) * 64 + d);
        Xs[p][d] = v.x; Xs[p][d + 1] = v.y; Xs[p][d + 2] = v.z; Xs[p][d + 3] = v.w;
    }
#pragma unroll
    for (int r = 0; r < 12; ++r) {
        int q = t + 256 * r;
        int j = q / 48, i = (q % 48) << 2;
        float4 v = *(const float4*)(adapt + j * 192 + i);
        As[j][i] = v.x; As[j][i + 1] = v.y; As[j][i + 2] = v.z; As[j][i + 3] = v.w;
    }
    __syncthreads();
    int tr = t >> 4, tc = t & 15;
    float acc[2][12];
#pragma unroll
    for (int u = 0; u < 2; ++u)
#pragma unroll
        for (int cc = 0; cc < 12; ++cc) acc[u][cc] = 0.f;
    for (int d = 0; d < 64; ++d) {
        float xv0 = Xs[tr * 2 + 0][d];
        float xv1 = Xs[tr * 2 + 1][d];
#pragma unroll
        for (int cc = 0; cc < 12; ++cc) {
            int c = tc * 12 + cc;
            float a = As[c & 63][((c >> 6) << 6) + d];
            acc[0][cc] += xv0 * a;
            acc[1][cc] += xv1 * a;
        }
    }
#pragma unroll
    for (int u = 0; u < 2; ++u)
#pragma unroll
        for (int cc = 0; cc < 12; ++cc)
            Q[(pb + tr * 2 + u) * 192 + tc * 12 + cc] = acc[u][cc];
}

// ---------------- packed-key insertion networks ----------------
__device__ __forceinline__ void ins_max4(unsigned &k0, unsigned &k1, unsigned &k2,
                                         unsigned &k3, unsigned t) {
    unsigned n;
    n = k0 > t ? k0 : t;  t = k0 > t ? t : k0;  k0 = n;
    n = k1 > t ? k1 : t;  t = k1 > t ? t : k1;  k1 = n;
    n = k2 > t ? k2 : t;  t = k2 > t ? t : k2;  k2 = n;
    k3 = k3 > t ? k3 : t;
}
__device__ __forceinline__ void ins_min4(unsigned &k0, unsigned &k1, unsigned &k2,
                                         unsigned &k3, unsigned t) {
    unsigned n;
    n = k0 < t ? k0 : t;  t = k0 < t ? t : k0;  k0 = n;
    n = k1 < t ? k1 : t;  t = k1 < t ? t : k1;  k1 = n;
    n = k2 < t ? k2 : t;  t = k2 < t ? t : k2;  k2 = n;
    k3 = k3 < t ? k3 : t;
}

// ---------------- MFMA score + dist candidate top-4, register-resident ----------------
__global__ __launch_bounds__(256) void k_score3(const u16* __restrict__ pillarH,
                                                const u16* __restrict__ pfeatH,
                                                const int* __restrict__ coords,
                                                const float* __restrict__ pcoord,
                                                int* __restrict__ sIdx,
                                                int* __restrict__ dIdx) {
    __shared__ u16 BF[8192];
    __shared__ float4 PCs[128];
    __shared__ unsigned mrg[4096];

    int t = threadIdx.x;
    int w = t >> 6, l = t & 63;
    int lm = l & 15, qd = l >> 4;
    int pb = blockIdx.x * 64;
    int cb = blockIdx.y * 1024;

    const u16* arow = pillarH + (size_t)(pb + 16 * w + lm) * 64 + qd * 8;
    s16x8 a0 = *(const s16x8*)arow;
    s16x8 a1 = *(const s16x8*)(arow + 32);

    int gp = pb + l;
    int gpc = gp < NVc ? gp : 0;
    float cxf = (float)coords[gpc * 4 + 1];
    float cyf = (float)coords[gpc * 4 + 2];

    unsigned sk[4][4];
#pragma unroll
    for (int r = 0; r < 4; ++r)
#pragma unroll
        for (int j = 0; j < 4; ++j) sk[r][j] = 0u;
    unsigned dk0 = 0xFFFFFFFFu, dk1 = 0xFFFFFFFFu, dk2 = 0xFFFFFFFFu, dk3 = 0xFFFFFFFFu;

    for (int s = 0; s < 8; ++s) {
        int ptb = cb + s * 128;
#pragma unroll
        for (int r = 0; r < 4; ++r) {
            int q = t + 256 * r;
            int row = q >> 3, g = q & 7;
            uint4 v = *(const uint4*)(pfeatH + (size_t)(ptb + row) * 64 + g * 8);
            int pt = row >> 4, lmr = row & 15;
            *(uint4*)&BF[(((pt * 8 + g) * 16) + (lmr ^ g)) * 8] = v;
        }
        if (t < 128) PCs[t] = *(const float4*)(pcoord + (size_t)(ptb + t) * 4);
        __syncthreads();
#pragma unroll
        for (int pt = 0; pt < 8; ++pt) {
            s16x8 b0 = *(const s16x8*)&BF[(((pt * 8 + qd) * 16) + (lm ^ qd)) * 8];
            s16x8 b1 = *(const s16x8*)&BF[(((pt * 8 + qd + 4) * 16) + (lm ^ (qd + 4))) * 8];
            f32x4 acc = {0.f, 0.f, 0.f, 0.f};
            acc = __builtin_amdgcn_mfma_f32_16x16x32_bf16(a0, b0, acc, 0, 0, 0);
            acc = __builtin_amdgcn_mfma_f32_16x16x32_bf16(a1, b1, acc, 0, 0, 0);
            unsigned idf = (unsigned)(1023 - (s * 128 + pt * 16 + lm));
#pragma unroll
            for (int r = 0; r < 4; ++r) {
                int b = __float_as_int(acc[r]);
                unsigned mask = ((unsigned)(b >> 31)) | 0x80000000u;
                unsigned key = ((((unsigned)b) ^ mask) & 0xFFFFFC00u) | idf;
                ins_max4(sk[r][0], sk[r][1], sk[r][2], sk[r][3], key);
            }
        }
#pragma unroll 4
        for (int i = 0; i < 32; ++i) {
            int jl = w * 32 + i;
            float4 pc = PCs[jl];
            float e1 = cxf - pc.y, e2 = cyf - pc.z;
            float d2 = fmaf(e1, e1, fmaf(e2, e2, pc.w * pc.w));
            unsigned key = (__float_as_uint(d2) & 0xFFFFFC00u) | (unsigned)(s * 128 + jl);
            ins_min4(dk0, dk1, dk2, dk3, key);
        }
        __syncthreads();
    }
#pragma unroll
    for (int r = 0; r < 4; ++r) {
        int row = 16 * w + qd * 4 + r;
        *(uint4*)&mrg[(row * 16 + lm) * 4] = make_uint4(sk[r][0], sk[r][1], sk[r][2], sk[r][3]);
    }
    __syncthreads();
    if (t < 64) {
        int row = t, gpr = pb + row;
        unsigned m0 = 0u, m1 = 0u, m2 = 0u, m3 = 0u;
#pragma unroll 4
        for (int cc = 0; cc < 16; ++cc) {
            uint4 v = *(const uint4*)&mrg[(row * 16 + cc) * 4];
            ins_max4(m0, m1, m2, m3, v.x);
            ins_max4(m0, m1, m2, m3, v.y);
            ins_max4(m0, m1, m2, m3, v.z);
            ins_max4(m0, m1, m2, m3, v.w);
        }
        if (gpr < NVc) {
            int base = (blockIdx.y * NVc + gpr) * 4;
            sIdx[base + 0] = cb + 1023 - (int)(m0 & 1023u);
            sIdx[base + 1] = cb + 1023 - (int)(m1 & 1023u);
            sIdx[base + 2] = cb + 1023 - (int)(m2 & 1023u);
            sIdx[base + 3] = cb + 1023 - (int)(m3 & 1023u);
        }
    }
    __syncthreads();
    *(uint4*)&mrg[(w * 64 + l) * 4] = make_uint4(dk0, dk1, dk2, dk3);
    __syncthreads();
    if (t < 64) {
        int gpr = pb + t;
        unsigned m0 = 0xFFFFFFFFu, m1 = 0xFFFFFFFFu, m2 = 0xFFFFFFFFu, m3 = 0xFFFFFFFFu;
#pragma unroll
        for (int ww = 0; ww < 4; ++ww) {
            uint4 v = *(const uint4*)&mrg[(ww * 64 + t) * 4];
            ins_min4(m0, m1, m2, m3, v.x);
            ins_min4(m0, m1, m2, m3, v.y);
            ins_min4(m0, m1, m2, m3, v.z);
            ins_min4(m0, m1, m2, m3, v.w);
        }
        if (gpr < NVc) {
            int base = (blockIdx.y * NVc + gpr) * 4;
            dIdx[base + 0] = cb + (int)(m0 & 1023u);
            dIdx[base + 1] = cb + (int)(m1 & 1023u);
            dIdx[base + 2] = cb + (int)(m2 & 1023u);
            dIdx[base + 3] = cb + (int)(m3 & 1023u);
        }
    }
}

// ---------------- fp64 re-rank of 64 candidates -> exact top-3 ----------------
__global__ __launch_bounds__(256) void k_rerank(const float* __restrict__ pillar,
                                                const int* __restrict__ coords,
                                                const float* __restrict__ pfeat,
                                                const float* __restrict__ pcoord,
                                                const int* __restrict__ sIdx,
                                                const int* __restrict__ dIdx,
                                                int* __restrict__ idx_f,
                                                int* __restrict__ idx_c) {
    int t = threadIdx.x;
    int wv = t >> 6, l = t & 63;
    int v = blockIdx.x * 4 + wv;
    int chunk = l >> 2, slot = l & 3;
    int ps = sIdx[(chunk * NVc + v) * 4 + slot];
    int pd = dIdx[(chunk * NVc + v) * 4 + slot];
    double s = 0.0;
#pragma unroll
    for (int i = 0; i < 16; ++i) {
        float4 a = *(const float4*)(pillar + v * 64 + 4 * i);
        float4 b = *(const float4*)(pfeat + ps * 64 + 4 * i);
        s += (double)a.x * (double)b.x + (double)a.y * (double)b.y
           + (double)a.z * (double)b.z + (double)a.w * (double)b.w;
    }
    float4 qc = *(const float4*)(pcoord + pd * 4);
    double db_ = (double)coords[v * 4 + 0] - (double)qc.x;
    double dx_ = (double)coords[v * 4 + 1] - (double)qc.y;
    double dy_ = (double)coords[v * 4 + 2] - (double)qc.z;
    double dz_ = (double)coords[v * 4 + 3] - (double)qc.w;
    double d2 = db_ * db_ + dx_ * dx_ + dy_ * dy_ + dz_ * dz_;
    double sv = s; int sx = ps;
    for (int k = 0; k < 3; ++k) {
        double bv = sv; int bi = sx;
#pragma unroll
        for (int off = 32; off >= 1; off >>= 1) {
            double ov = __shfl_xor(bv, off);
            int    oi = __shfl_xor(bi, off);
            if (ov > bv || (ov == bv && oi < bi)) { bv = ov; bi = oi; }
        }
        if (l == 0) idx_f[v * 3 + k] = bi;
        if (sx == bi) { sv = -INFINITY; sx = 0x7fffffff; }
    }
    double dv = d2; int dx2 = pd;
    for (int k = 0; k < 3; ++k) {
        double bv = dv; int bi = dx2;
#pragma unroll
        for (int off = 32; off >= 1; off >>= 1) {
            double ov = __shfl_xor(bv, off);
            int    oi = __shfl_xor(bi, off);
            if (ov < bv || (ov == bv && oi < bi)) { bv = ov; bi = oi; }
        }
        if (l == 0) idx_c[v * 3 + k] = bi;
        if (dx2 == bi) { dv = INFINITY; dx2 = 0x7fffffff; }
    }
}

// ---------------- gather-add + w logits + BN partial sums ----------------
__global__ __launch_bounds__(256) void k_gather(const float* __restrict__ Q,
                                                const int* __restrict__ idx_f,
                                                const int* __restrict__ idx_c,
                                                const float* __restrict__ pillar,
                                                const float* __restrict__ ww,
                                                float* __restrict__ f_pre,
                                                float* __restrict__ c_pre,
                                                float* __restrict__ w_pre,
                                                float* __restrict__ stats) {
    __shared__ float red[4][4][64];
    __shared__ float redw[4][4];
    int t = threadIdx.x;
    int wv = t >> 6, l = t & 63;
    int base = blockIdx.x * 250;
    int vend = base + 250;
    float fs = 0, fq = 0, cs = 0, cq = 0, ws0 = 0, wq0 = 0, ws1 = 0, wq1 = 0;
    float w0l = ww[l], w1l = ww[64 + l];
    for (int v = base + wv; v < vend; v += 4) {
        int if0 = idx_f[v * 3], if1 = idx_f[v * 3 + 1], if2 = idx_f[v * 3 + 2];
        float f = Q[if0 * 192 + l] + Q[if1 * 192 + 64 + l] + Q[if2 * 192 + 128 + l];
        f_pre[v * 64 + l] = f; fs += f; fq += f * f;
        int ic0 = idx_c[v * 3], ic1 = idx_c[v * 3 + 1], ic2 = idx_c[v * 3 + 2];
        float c = Q[ic0 * 192 + l] + Q[ic1 * 192 + 64 + l] + Q[ic2 * 192 + 128 + l];
        c_pre[v * 64 + l] = c; cs += c; cq += c * c;
        float pv = pillar[v * 64 + l];
        float a0 = pv * w0l, a1 = pv * w1l;
#pragma unroll
        for (int off = 32; off >= 1; off >>= 1) {
            a0 += __shfl_xor(a0, off);
            a1 += __shfl_xor(a1, off);
        }
        if (l == 0) { w_pre[v * 2] = a0; w_pre[v * 2 + 1] = a1; }
        ws0 += a0; wq0 += a0 * a0; ws1 += a1; wq1 += a1 * a1;
    }
    red[0][wv][l] = fs; red[1][wv][l] = fq; red[2][wv][l] = cs; red[3][wv][l] = cq;
    if (l == 0) { redw[wv][0] = ws0; redw[wv][1] = wq0; redw[wv][2] = ws1; redw[wv][3] = wq1; }
    __syncthreads();
    if (wv == 0) {
#pragma unroll
        for (int q = 0; q < 4; ++q) {
            float sum = red[q][0][l] + red[q][1][l] + red[q][2][l] + red[q][3][l];
            atomicAdd(&stats[q * 64 + l], sum);
        }
        if (l < 4) {
            float sum = redw[0][l] + redw[1][l] + redw[2][l] + redw[3][l];
            atomicAdd(&stats[256 + l], sum);
        }
    }
}

// ---------------- BN finalize + softmax weights + scatter ----------------
__global__ __launch_bounds__(256) void k_final(const float* __restrict__ f_pre,
                                               const float* __restrict__ c_pre,
                                               const float* __restrict__ w_pre,
                                               const float* __restrict__ stats,
                                               const float* __restrict__ pillar,
                                               const int* __restrict__ coords,
                                               const float* __restrict__ g1,
                                               const float* __restrict__ b1,
                                               const float* __restrict__ g2,
                                               const float* __restrict__ b2,
                                               float* __restrict__ out) {
    int t = threadIdx.x;
    int wv = t >> 6, l = t & 63;
    int v = blockIdx.x * 4 + wv;
    const float invn = 1.0f / (float)NVc;
    float mf = stats[l] * invn;
    float vf = stats[64 + l] * invn - mf * mf;
    float rf = rsqrtf(vf + 1e-3f);
    float mc = stats[128 + l] * invn;
    float vc = stats[192 + l] * invn - mc * mc;
    float rc = rsqrtf(vc + 1e-3f);
    float mw0 = stats[256] * invn, vw0 = stats[257] * invn - mw0 * mw0;
    float mw1 = stats[258] * invn, vw1 = stats[259] * invn - mw1 * mw1;
    float rw0 = rsqrtf(vw0 + 1e-3f), rw1 = rsqrtf(vw1 + 1e-3f);
    float fb = (f_pre[v * 64 + l] - mf) * rf * g1[l] + b1[l];
    float f = fmaxf(fb, 0.f);
    float cb_ = (c_pre[v * 64 + l] - mc) * rc * g1[l] + b1[l];
    float c = fmaxf(cb_, 0.f);
    float z0 = (w_pre[v * 2] - mw0) * rw0 * g2[0] + b2[0];
    float z1 = (w_pre[v * 2 + 1] - mw1) * rw1 * g2[1] + b2[1];
    float mz = fmaxf(z0, z1);
    float e0 = __expf(z0 - mz), e1 = __expf(z1 - mz);
    float wd = 1.f / (e0 + e1);
    float aug = (e0 * wd) * f + (e1 * wd) * c;
    int cxi = coords[v * 4 + 1], cyi = coords[v * 4 + 2], czi = coords[v * 4 + 3];
    int cell = cxi + cyi * NXc + czi;
    out[l * CELLS + cell] = pillar[v * 64 + l];
    out[(64 + l) * CELLS + cell] = aug;
    if (l == 0) {
        float* o1 = out + 128 * CELLS;
        o1[cell] = (float)cyi;
        o1[CELLS + cell] = (float)czi;
        o1[2 * CELLS + cell] = (float)cxi;
    }
}

extern "C" void kernel_launch(void* const* d_in, const int* in_sizes, int n_in,
                              void* d_out, int out_size, void* d_ws, size_t ws_size,
                              hipStream_t stream) {
    const float* pillar = (const float*)d_in[0];
    const int*   coords = (const int*)d_in[1];
    const float* pfeat  = (const float*)d_in[2];
    const float* pcoord = (const float*)d_in[3];
    const float* adapt  = (const float*)d_in[4];
    const float* bn1g   = (const float*)d_in[5];
    const float* bn1b   = (const float*)d_in[6];
    const float* ww     = (const float*)d_in[7];
    const float* bn2g   = (const float*)d_in[8];
    const float* bn2b   = (const float*)d_in[9];
    const float* memw   = (const float*)d_in[10];
    float* out = (float*)d_out;
    float* ws  = (float*)d_ws;
    // workspace layout (float offsets)
    float* Pout  = ws + 0;                 // 1,048,576
    float* Q     = ws + 1048576;           // 3,145,728
    int*   sIdx  = (int*)(ws + 4194304);   // 640,000
    int*   dIdx  = (int*)(ws + 4834304);   // 640,000
    int*   idxf  = (int*)(ws + 5474304);   // 30,000
    int*   idxc  = (int*)(ws + 5504304);   // 30,000
    float* fpre  = ws + 5534304;           // 640,000
    float* cpre  = ws + 6174304;           // 640,000
    float* wpre  = ws + 6814304;           // 20,000
    float* stats = ws + 6834304;           // 260
    // bf16 feature buffers overlap fpre/cpre (dead until k_gather writes them)
    u16* pillarH = (u16*)(ws + 5534304);           // 643,072 u16
    u16* pfeatH  = pillarH + (size_t)NVPAD * 64;   // 1,048,576 u16
    // bf16 memw copies overlap the head of Q (dead until k_proj writes Q)
    u16* memwH   = (u16*)(ws + 1048576);           // 65,536 u16 (32,768 floats)
    u16* memwTH  = memwH + 65536;                  // 65,536 u16

    k_zero  <<<4096, 256, 0, stream>>>(out, out_size, stats);
    k_cast  <<<7120, 256, 0, stream>>>(pillar, pfeat, memw, pillarH, pfeatH, memwH, memwTH);
    k_score3<<<dim3(157, 16), 256, 0, stream>>>(pillarH, pfeatH, coords, pcoord, sIdx, dIdx);
    k_rerank<<<2500, 256, 0, stream>>>(pillar, coords, pfeat, pcoord, sIdx, dIdx, idxf, idxc);
    k_mem2  <<<256,  256, 0, stream>>>(pfeatH, memwH, memwTH, Pout);
    k_proj  <<<512,  256, 0, stream>>>(Pout, adapt, Q);
    k_gather<<<40,   256, 0, stream>>>(Q, idxf, idxc, pillar, ww, fpre, cpre, wpre, stats);
    k_final <<<2500, 256, 0, stream>>>(fpre, cpre, wpre, stats, pillar, coords,
                                       bn1g, bn1b, bn2g, bn2b, out);
}

// Round 5
// 397.684 us; speedup vs baseline: 3.3938x; 1.0618x over previous
//
#include <hip/hip_runtime.h>
#include <math.h>

#define NXc 432
#define NYc 496
#define NVc 10000
#define NPc 16384
#define CELLS (NXc*NYc)          // 214272
#define SHRINKc 0.0025f
#define NVPAD 10048              // 157*64
#define NBX 27
#define NBY 31
#define NBIN (NBX*NBY)           // 837

typedef unsigned short u16;
typedef __attribute__((ext_vector_type(8))) short s16x8;   // 8 bf16
typedef __attribute__((ext_vector_type(4))) float f32x4;

// ---------------- zero output + stats + bin counters ----------------
__global__ void k_zero(float* __restrict__ out, int n, float* __restrict__ stats,
                       int* __restrict__ binCnt) {
    int gid = blockIdx.x * blockDim.x + threadIdx.x;
    int n4 = n >> 2;
    float4 z = make_float4(0.f, 0.f, 0.f, 0.f);
    float4* o4 = (float4*)out;
    for (int i = gid; i < n4; i += gridDim.x * blockDim.x) o4[i] = z;
    int tail = n & 3;
    if (gid < tail) out[n4 * 4 + gid] = 0.f;
    if (gid < 260) stats[gid] = 0.f;
    if (gid >= 512 && gid < 512 + NBIN) binCnt[gid - 512] = 0;
}

// ---------------- fp32 -> bf16 (RNE) casts + bin histogram ----------------
__device__ __forceinline__ u16 f2b(float x) {
    unsigned u = __float_as_uint(x);
    unsigned r = (u + 0x7fffu + ((u >> 16) & 1u)) >> 16;
    return (u16)r;
}
__global__ __launch_bounds__(256) void k_cast(const float* __restrict__ pillar,
                                              const float* __restrict__ pfeat,
                                              const float* __restrict__ memw,
                                              const float* __restrict__ pcoord,
                                              u16* __restrict__ pillarH,
                                              u16* __restrict__ pfeatH,
                                              u16* __restrict__ memwH,
                                              u16* __restrict__ memwTH,
                                              int* __restrict__ binCnt) {
    int idx = blockIdx.x * 256 + threadIdx.x;      // 7184*256 = 1839104 exactly
    const int N1 = NVPAD * 64;                     // 643072
    const int N2 = N1 + NPc * 64;                  // 1691648
    const int N3 = N2 + 65536;                     // 1757184
    const int N4 = N3 + 65536;                     // 1822720
    if (idx < N1) {
        int v = idx >> 6;
        pillarH[idx] = f2b(v < NVc ? pillar[idx] : 0.f);
    } else if (idx < N2) {
        int j = idx - N1;
        pfeatH[j] = f2b(pfeat[j]);
    } else if (idx < N3) {
        int j = idx - N2;
        memwH[j] = f2b(memw[j]);
    } else if (idx < N4) {
        int i = idx - N3;                          // 0..65535
        int d = i >> 10, j = i & 1023;
        memwTH[i] = f2b(memw[j * 64 + d]);         // memwT[d][j]
    } else {
        int j = idx - N4;                          // 0..16383 point histogram
        float qx = pcoord[j * 4 + 1], qy = pcoord[j * 4 + 2];
        int bx = (int)(qx * 0.0625f); if (bx > NBX - 1) bx = NBX - 1;
        int by = (int)(qy * 0.0625f); if (by > NBY - 1) by = NBY - 1;
        atomicAdd(&binCnt[by * NBX + bx], 1);
    }
}

// ---------------- exclusive scan of bin counts ----------------
__global__ __launch_bounds__(1024) void k_binscan(const int* __restrict__ binCnt,
                                                  int* __restrict__ binStart,
                                                  int* __restrict__ binCursor) {
    __shared__ int sc[1024];
    int t = threadIdx.x;
    int vcount = (t < NBIN) ? binCnt[t] : 0;
    sc[t] = vcount;
    __syncthreads();
    for (int off = 1; off < 1024; off <<= 1) {
        int add = (t >= off) ? sc[t - off] : 0;
        __syncthreads();
        sc[t] += add;
        __syncthreads();
    }
    int excl = sc[t] - vcount;
    if (t <= NBIN) { binStart[t] = excl; binCursor[t] = excl; }
}

// ---------------- fill bins: (qx, qy, qz^2, idx-bits) per slot ----------------
__global__ __launch_bounds__(256) void k_binfill(const float* __restrict__ pcoord,
                                                 int* __restrict__ binCursor,
                                                 float4* __restrict__ binPC) {
    int j = blockIdx.x * 256 + threadIdx.x;        // 64*256 = 16384 exactly
    float qx = pcoord[j * 4 + 1], qy = pcoord[j * 4 + 2], qz = pcoord[j * 4 + 3];
    int bx = (int)(qx * 0.0625f); if (bx > NBX - 1) bx = NBX - 1;
    int by = (int)(qy * 0.0625f); if (by > NBY - 1) by = NBY - 1;
    int slot = atomicAdd(&binCursor[by * NBX + bx], 1);
    binPC[slot] = make_float4(qx, qy, qz * qz, __uint_as_float((unsigned)j));
}

// ---------------- packed-key insertion networks ----------------
__device__ __forceinline__ void ins_max4(unsigned &k0, unsigned &k1, unsigned &k2,
                                         unsigned &k3, unsigned t) {
    unsigned n;
    n = k0 > t ? k0 : t;  t = k0 > t ? t : k0;  k0 = n;
    n = k1 > t ? k1 : t;  t = k1 > t ? t : k1;  k1 = n;
    n = k2 > t ? k2 : t;  t = k2 > t ? t : k2;  k2 = n;
    k3 = k3 > t ? k3 : t;
}
__device__ __forceinline__ void ins_min4(unsigned &k0, unsigned &k1, unsigned &k2,
                                         unsigned &k3, unsigned t) {
    unsigned n;
    n = k0 < t ? k0 : t;  t = k0 < t ? t : k0;  k0 = n;
    n = k1 < t ? k1 : t;  t = k1 < t ? t : k1;  k1 = n;
    n = k2 < t ? k2 : t;  t = k2 < t ? t : k2;  k2 = n;
    k3 = k3 < t ? k3 : t;
}
__device__ __forceinline__ void ins_min6(unsigned kk[6], unsigned t) {
    unsigned n;
#pragma unroll
    for (int i = 0; i < 5; ++i) {
        n = kk[i] < t ? kk[i] : t;  t = kk[i] < t ? t : kk[i];  kk[i] = n;
    }
    kk[5] = kk[5] < t ? kk[5] : t;
}

// ---------------- exact top-6 nearest points via bin ring search ----------------
__global__ __launch_bounds__(256) void k_dist6(const int* __restrict__ coords,
                                               const float4* __restrict__ binPC,
                                               const int* __restrict__ binStart,
                                               int* __restrict__ dIdx6) {
    int v = blockIdx.x * 256 + threadIdx.x;
    if (v >= NVc) return;
    int xi = coords[v * 4 + 1], yi = coords[v * 4 + 2];
    float x = (float)xi, y = (float)yi;
    int bx = xi >> 4; if (bx > NBX - 1) bx = NBX - 1;
    int by = yi >> 4; if (by > NBY - 1) by = NBY - 1;
    unsigned kk[6] = {~0u, ~0u, ~0u, ~0u, ~0u, ~0u};
    for (int r = 0; r < 32; ++r) {
        int x0 = bx - r, x1 = bx + r, y0 = by - r, y1 = by + r;
        for (int cy = y0; cy <= y1; ++cy) {
            if (cy < 0 || cy > NBY - 1) continue;
            int step = (cy == y0 || cy == y1) ? 1 : (x1 > x0 ? x1 - x0 : 1);
            for (int cx = x0; cx <= x1; cx += step) {
                if (cx < 0 || cx > NBX - 1) continue;
                int b = cy * NBX + cx;
                int s0 = binStart[b], s1 = binStart[b + 1];
                for (int s = s0; s < s1; ++s) {
                    float4 p = binPC[s];
                    float e1 = x - p.x, e2 = y - p.y;
                    float d2 = fmaf(e1, e1, fmaf(e2, e2, p.z));
                    unsigned key = (__float_as_uint(d2) & 0xFFFFC000u) | __float_as_uint(p.w);
                    ins_min6(kk, key);
                }
            }
        }
        // stop: points in rings > r have d^2 > 256*r^2; truncated d3 underestimates
        // the true 3rd-best by < 2^-9 relative, so the 1.004 factor is a safe cover.
        if (kk[2] != ~0u) {
            float d3 = __uint_as_float(kk[2] & 0xFFFFC000u);
            if (256.f * (float)(r * r) > d3 * 1.004f + 1e-3f) break;
        }
    }
#pragma unroll
    for (int j = 0; j < 6; ++j) dIdx6[v * 6 + j] = (int)(kk[j] & 16383u);
}

// ---------------- MFMA score candidate top-4 per 1024-point chunk ----------------
// grid (157,16), block 256 (4 waves). 64 pillars x 1024 points.
// Accumulator pre-biased +256 so scores are positive -> 2-op sortable keys.
__global__ __launch_bounds__(256) void k_score4(const u16* __restrict__ pillarH,
                                                const u16* __restrict__ pfeatH,
                                                int* __restrict__ sIdx) {
    __shared__ unsigned SH[4096];      // 16 KB: B-frag staging (u16[8192]) / merge scratch
    u16* BF = (u16*)SH;
    int t = threadIdx.x;
    int w = t >> 6, l = t & 63;
    int lm = l & 15, qd = l >> 4;
    int pb = blockIdx.x * 64;
    int cb = blockIdx.y * 1024;

    const u16* arow = pillarH + (size_t)(pb + 16 * w + lm) * 64 + qd * 8;
    s16x8 a0 = *(const s16x8*)arow;
    s16x8 a1 = *(const s16x8*)(arow + 32);

    unsigned sk[4][4];
#pragma unroll
    for (int r = 0; r < 4; ++r)
#pragma unroll
        for (int j = 0; j < 4; ++j) sk[r][j] = 0u;

    for (int s = 0; s < 8; ++s) {
        int ptb = cb + s * 128;
#pragma unroll
        for (int r = 0; r < 4; ++r) {
            int q = t + 256 * r;
            int row = q >> 3, g = q & 7;
            uint4 v = *(const uint4*)(pfeatH + (size_t)(ptb + row) * 64 + g * 8);
            *(uint4*)&BF[(((row >> 4) * 8 + g) * 16 + ((row & 15) ^ g)) * 8] = v;
        }
        __syncthreads();
#pragma unroll
        for (int pt = 0; pt < 8; ++pt) {
            s16x8 b0 = *(const s16x8*)&BF[(((pt * 8 + qd) * 16) + (lm ^ qd)) * 8];
            s16x8 b1 = *(const s16x8*)&BF[(((pt * 8 + qd + 4) * 16) + (lm ^ (qd + 4))) * 8];
            f32x4 acc = {256.f, 256.f, 256.f, 256.f};
            acc = __builtin_amdgcn_mfma_f32_16x16x32_bf16(a0, b0, acc, 0, 0, 0);
            acc = __builtin_amdgcn_mfma_f32_16x16x32_bf16(a1, b1, acc, 0, 0, 0);
            unsigned idf = (unsigned)(1023 - (s * 128 + pt * 16 + lm));
#pragma unroll
            for (int r = 0; r < 4; ++r) {
                unsigned key = (__float_as_uint(acc[r]) & 0xFFFFFC00u) | idf;
                ins_max4(sk[r][0], sk[r][1], sk[r][2], sk[r][3], key);
            }
        }
        __syncthreads();
    }
    // merge 16 lane-partials per pillar row (SH reused; BF dead after last sync)
#pragma unroll
    for (int r = 0; r < 4; ++r) {
        int row = 16 * w + qd * 4 + r;
        *(uint4*)&SH[(row * 16 + lm) * 4] = make_uint4(sk[r][0], sk[r][1], sk[r][2], sk[r][3]);
    }
    __syncthreads();
    if (t < 64) {
        int gpr = pb + t;
        unsigned m0 = 0u, m1 = 0u, m2 = 0u, m3 = 0u;
#pragma unroll 4
        for (int cc = 0; cc < 16; ++cc) {
            uint4 v = *(const uint4*)&SH[(t * 16 + cc) * 4];
            ins_max4(m0, m1, m2, m3, v.x);
            ins_max4(m0, m1, m2, m3, v.y);
            ins_max4(m0, m1, m2, m3, v.z);
            ins_max4(m0, m1, m2, m3, v.w);
        }
        if (gpr < NVc) {
            int base = (blockIdx.y * NVc + gpr) * 4;
            sIdx[base + 0] = cb + 1023 - (int)(m0 & 1023u);
            sIdx[base + 1] = cb + 1023 - (int)(m1 & 1023u);
            sIdx[base + 2] = cb + 1023 - (int)(m2 & 1023u);
            sIdx[base + 3] = cb + 1023 - (int)(m3 & 1023u);
        }
    }
}

// ---------------- fp64 re-rank: scores 64 candidates, dist 6 candidates ----------------
__global__ __launch_bounds__(256) void k_rerank(const float* __restrict__ pillar,
                                                const int* __restrict__ coords,
                                                const float* __restrict__ pfeat,
                                                const float* __restrict__ pcoord,
                                                const int* __restrict__ sIdx,
                                                const int* __restrict__ dIdx6,
                                                int* __restrict__ idx_f,
                                                int* __restrict__ idx_c) {
    int t = threadIdx.x;
    int wv = t >> 6, l = t & 63;
    int v = blockIdx.x * 4 + wv;
    int chunk = l >> 2, slot = l & 3;
    int ps = sIdx[(chunk * NVc + v) * 4 + slot];
    int pd = dIdx6[v * 6 + (l < 6 ? l : 0)];
    double s = 0.0;
#pragma unroll
    for (int i = 0; i < 16; ++i) {
        float4 a = *(const float4*)(pillar + v * 64 + 4 * i);
        float4 b = *(const float4*)(pfeat + ps * 64 + 4 * i);
        s += (double)a.x * (double)b.x + (double)a.y * (double)b.y
           + (double)a.z * (double)b.z + (double)a.w * (double)b.w;
    }
    float4 qc = *(const float4*)(pcoord + pd * 4);
    double db_ = (double)coords[v * 4 + 0] - (double)qc.x;
    double dx_ = (double)coords[v * 4 + 1] - (double)qc.y;
    double dy_ = (double)coords[v * 4 + 2] - (double)qc.z;
    double dz_ = (double)coords[v * 4 + 3] - (double)qc.w;
    double d2 = db_ * db_ + dx_ * dx_ + dy_ * dy_ + dz_ * dz_;
    double sv = s; int sx = ps;
    for (int k = 0; k < 3; ++k) {
        double bv = sv; int bi = sx;
#pragma unroll
        for (int off = 32; off >= 1; off >>= 1) {
            double ov = __shfl_xor(bv, off);
            int    oi = __shfl_xor(bi, off);
            if (ov > bv || (ov == bv && oi < bi)) { bv = ov; bi = oi; }
        }
        if (l == 0) idx_f[v * 3 + k] = bi;
        if (sx == bi) { sv = -INFINITY; sx = 0x7fffffff; }
    }
    double dv = d2; int dx2 = pd;
    for (int k = 0; k < 3; ++k) {
        double bv = dv; int bi = dx2;
#pragma unroll
        for (int off = 32; off >= 1; off >>= 1) {
            double ov = __shfl_xor(bv, off);
            int    oi = __shfl_xor(bi, off);
            if (ov < bv || (ov == bv && oi < bi)) { bv = ov; bi = oi; }
        }
        if (l == 0) idx_c[v * 3 + k] = bi;
        if (dx2 == bi) { dv = INFINITY; dx2 = 0x7fffffff; }
    }
}

// ---------------- MFMA streaming memory_lookup (unchanged from R4) ----------------
__global__ __launch_bounds__(256) void k_mem2(const u16* __restrict__ pfeatH,
                                              const u16* __restrict__ memwH,
                                              const u16* __restrict__ memwTH,
                                              float* __restrict__ Pout) {
    __shared__ u16 WH[8192];
    __shared__ u16 WT[8192];
    __shared__ u16 ST[4][2048];
    int t = threadIdx.x;
    int w = t >> 6, l = t & 63;
    int lm = l & 15, qd = l >> 4;
    int pb = blockIdx.x * 64;

    const u16* arow = pfeatH + (size_t)(pb + 16 * w + lm) * 64 + qd * 8;
    s16x8 a0 = *(const s16x8*)arow;
    s16x8 a1 = *(const s16x8*)(arow + 32);

    float mM[4] = {-INFINITY, -INFINITY, -INFINITY, -INFINITY};
    float Zs[4] = {0.f, 0.f, 0.f, 0.f};

    for (int tile = 0; tile < 8; ++tile) {
        __syncthreads();
#pragma unroll
        for (int r = 0; r < 4; ++r) {
            int q = t + 256 * r;
            int row = q >> 3, g = q & 7;
            uint4 v = *(const uint4*)(memwH + (size_t)(tile * 128 + row) * 64 + g * 8);
            *(uint4*)&WH[(((row >> 4) * 8 + g) * 16 + ((row & 15) ^ g)) * 8] = v;
        }
        __syncthreads();
        f32x4 acc[8];
#pragma unroll
        for (int st = 0; st < 8; ++st) {
            s16x8 b0 = *(const s16x8*)&WH[((st * 8 + qd) * 16 + (lm ^ qd)) * 8];
            s16x8 b1 = *(const s16x8*)&WH[((st * 8 + qd + 4) * 16 + (lm ^ (qd + 4))) * 8];
            f32x4 z = {0.f, 0.f, 0.f, 0.f};
            z = __builtin_amdgcn_mfma_f32_16x16x32_bf16(a0, b0, z, 0, 0, 0);
            z = __builtin_amdgcn_mfma_f32_16x16x32_bf16(a1, b1, z, 0, 0, 0);
            acc[st] = z;
        }
#pragma unroll
        for (int r = 0; r < 4; ++r) {
            float tmax = acc[0][r];
#pragma unroll
            for (int st = 1; st < 8; ++st) tmax = fmaxf(tmax, acc[st][r]);
            float mn = fmaxf(mM[r], tmax);
            float zacc = Zs[r] * __expf(mM[r] - mn);
#pragma unroll
            for (int st = 0; st < 8; ++st) zacc += __expf(acc[st][r] - mn);
            mM[r] = mn; Zs[r] = zacc;
        }
    }
#pragma unroll
    for (int r = 0; r < 4; ++r) {
#pragma unroll
        for (int off = 1; off < 16; off <<= 1) {
            float om = __shfl_xor(mM[r], off);
            float oz = __shfl_xor(Zs[r], off);
            float mn = fmaxf(mM[r], om);
            Zs[r] = Zs[r] * __expf(mM[r] - mn) + oz * __expf(om - mn);
            mM[r] = mn;
        }
    }
    float invZ[4], L1[4] = {0.f, 0.f, 0.f, 0.f};
#pragma unroll
    for (int r = 0; r < 4; ++r) invZ[r] = 1.f / Zs[r];

    f32x4 oacc[4];
#pragma unroll
    for (int n = 0; n < 4; ++n) oacc[n] = (f32x4){0.f, 0.f, 0.f, 0.f};

    for (int tile = 0; tile < 8; ++tile) {
        __syncthreads();
#pragma unroll
        for (int r = 0; r < 4; ++r) {
            int q = t + 256 * r;
            int row = q >> 3, g = q & 7;
            uint4 v = *(const uint4*)(memwH + (size_t)(tile * 128 + row) * 64 + g * 8);
            *(uint4*)&WH[(((row >> 4) * 8 + g) * 16 + ((row & 15) ^ g)) * 8] = v;
        }
#pragma unroll
        for (int r = 0; r < 4; ++r) {
            int q = t + 256 * r;
            int row = q >> 4, g = q & 15;
            uint4 v = *(const uint4*)(memwTH + (size_t)row * 1024 + tile * 128 + g * 8);
            *(uint4*)&WT[(g * 64 + (row ^ g)) * 8] = v;
        }
        __syncthreads();
#pragma unroll
        for (int st = 0; st < 8; ++st) {
            s16x8 b0 = *(const s16x8*)&WH[((st * 8 + qd) * 16 + (lm ^ qd)) * 8];
            s16x8 b1 = *(const s16x8*)&WH[((st * 8 + qd + 4) * 16 + (lm ^ (qd + 4))) * 8];
            f32x4 z = {0.f, 0.f, 0.f, 0.f};
            z = __builtin_amdgcn_mfma_f32_16x16x32_bf16(a0, b0, z, 0, 0, 0);
            z = __builtin_amdgcn_mfma_f32_16x16x32_bf16(a1, b1, z, 0, 0, 0);
            int g2 = st * 2 + (lm >> 3);
#pragma unroll
            for (int r = 0; r < 4; ++r) {
                float e = __expf(z[r] - mM[r]);
                float a = e * invZ[r];
                float tt = a - SHRINKc;
                float sres = fmaxf(tt, 0.f) * a / (fabsf(tt) + 1e-12f);
                L1[r] += sres;
                int rr = qd * 4 + r;
                ST[w][(g2 * 16 + (rr ^ g2)) * 8 + (lm & 7)] = f2b(sres);
            }
        }
#pragma unroll
        for (int ks = 0; ks < 4; ++ks) {
            int g = ks * 4 + qd;
            s16x8 af = *(const s16x8*)&ST[w][(g * 16 + (lm ^ g)) * 8];
#pragma unroll
            for (int n = 0; n < 4; ++n) {
                s16x8 bf = *(const s16x8*)&WT[(g * 64 + ((n * 16 + lm) ^ g)) * 8];
                oacc[n] = __builtin_amdgcn_mfma_f32_16x16x32_bf16(af, bf, oacc[n], 0, 0, 0);
            }
        }
    }
#pragma unroll
    for (int r = 0; r < 4; ++r) {
#pragma unroll
        for (int off = 1; off < 16; off <<= 1) L1[r] += __shfl_xor(L1[r], off);
        L1[r] = 1.f / fmaxf(L1[r], 1e-12f);
    }
#pragma unroll
    for (int n = 0; n < 4; ++n)
#pragma unroll
        for (int r = 0; r < 4; ++r)
            Pout[(size_t)(pb + 16 * w + qd * 4 + r) * 64 + n * 16 + lm] = oacc[n][r] * L1[r];
}

// ---------------- Q[p][k*64+j] = sum_d Pout[p][d] * adapt[j][k*64+d] ----------------
__global__ __launch_bounds__(256) void k_proj(const float* __restrict__ Pout,
                                              const float* __restrict__ adapt,
                                              float* __restrict__ Q) {
    __shared__ float Xs[32][65];
    __shared__ float As[64][197];
    int t = threadIdx.x;
    int pb = blockIdx.x * 32;
#pragma unroll
    for (int r = 0; r < 2; ++r) {
        int q = t + 256 * r;
        int p = q >> 4, d = (q & 15) << 2;
        float4 v = *(const float4*)(Pout + (pb + p) * 64 + d);
        Xs[p][d] = v.x; Xs[p][d + 1] = v.y; Xs[p][d + 2] = v.z; Xs[p][d + 3] = v.w;
    }
#pragma unroll
    for (int r = 0; r < 12; ++r) {
        int q = t + 256 * r;
        int j = q / 48, i = (q % 48) << 2;
        float4 v = *(const float4*)(adapt + j * 192 + i);
        As[j][i] = v.x; As[j][i + 1] = v.y; As[j][i + 2] = v.z; As[j][i + 3] = v.w;
    }
    __syncthreads();
    int tr = t >> 4, tc = t & 15;
    float acc[2][12];
#pragma unroll
    for (int u = 0; u < 2; ++u)
#pragma unroll
        for (int cc = 0; cc < 12; ++cc) acc[u][cc] = 0.f;
    for (int d = 0; d < 64; ++d) {
        float xv0 = Xs[tr * 2 + 0][d];
        float xv1 = Xs[tr * 2 + 1][d];
#pragma unroll
        for (int cc = 0; cc < 12; ++cc) {
            int c = tc * 12 + cc;
            float a = As[c & 63][((c >> 6) << 6) + d];
            acc[0][cc] += xv0 * a;
            acc[1][cc] += xv1 * a;
        }
    }
#pragma unroll
    for (int u = 0; u < 2; ++u)
#pragma unroll
        for (int cc = 0; cc < 12; ++cc)
            Q[(pb + tr * 2 + u) * 192 + tc * 12 + cc] = acc[u][cc];
}

// ---------------- gather-add + w logits + BN partial sums ----------------
__global__ __launch_bounds__(256) void k_gather(const float* __restrict__ Q,
                                                const int* __restrict__ idx_f,
                                                const int* __restrict__ idx_c,
                                                const float* __restrict__ pillar,
                                                const float* __restrict__ ww,
                                                float* __restrict__ f_pre,
                                                float* __restrict__ c_pre,
                                                float* __restrict__ w_pre,
                                                float* __restrict__ stats) {
    __shared__ float red[4][4][64];
    __shared__ float redw[4][4];
    int t = threadIdx.x;
    int wv = t >> 6, l = t & 63;
    int base = blockIdx.x * 40;
    int vend = base + 40;
    float fs = 0, fq = 0, cs = 0, cq = 0, ws0 = 0, wq0 = 0, ws1 = 0, wq1 = 0;
    float w0l = ww[l], w1l = ww[64 + l];
    for (int v = base + wv; v < vend; v += 4) {
        int if0 = idx_f[v * 3], if1 = idx_f[v * 3 + 1], if2 = idx_f[v * 3 + 2];
        float f = Q[if0 * 192 + l] + Q[if1 * 192 + 64 + l] + Q[if2 * 192 + 128 + l];
        f_pre[v * 64 + l] = f; fs += f; fq += f * f;
        int ic0 = idx_c[v * 3], ic1 = idx_c[v * 3 + 1], ic2 = idx_c[v * 3 + 2];
        float c = Q[ic0 * 192 + l] + Q[ic1 * 192 + 64 + l] + Q[ic2 * 192 + 128 + l];
        c_pre[v * 64 + l] = c; cs += c; cq += c * c;
        float pv = pillar[v * 64 + l];
        float a0 = pv * w0l, a1 = pv * w1l;
#pragma unroll
        for (int off = 32; off >= 1; off >>= 1) {
            a0 += __shfl_xor(a0, off);
            a1 += __shfl_xor(a1, off);
        }
        if (l == 0) { w_pre[v * 2] = a0; w_pre[v * 2 + 1] = a1; }
        ws0 += a0; wq0 += a0 * a0; ws1 += a1; wq1 += a1 * a1;
    }
    red[0][wv][l] = fs; red[1][wv][l] = fq; red[2][wv][l] = cs; red[3][wv][l] = cq;
    if (l == 0) { redw[wv][0] = ws0; redw[wv][1] = wq0; redw[wv][2] = ws1; redw[wv][3] = wq1; }
    __syncthreads();
    if (wv == 0) {
#pragma unroll
        for (int q = 0; q < 4; ++q) {
            float sum = red[q][0][l] + red[q][1][l] + red[q][2][l] + red[q][3][l];
            atomicAdd(&stats[q * 64 + l], sum);
        }
        if (l < 4) {
            float sum = redw[0][l] + redw[1][l] + redw[2][l] + redw[3][l];
            atomicAdd(&stats[256 + l], sum);
        }
    }
}

// ---------------- BN finalize + softmax weights + scatter ----------------
__global__ __launch_bounds__(256) void k_final(const float* __restrict__ f_pre,
                                               const float* __restrict__ c_pre,
                                               const float* __restrict__ w_pre,
                                               const float* __restrict__ stats,
                                               const float* __restrict__ pillar,
                                               const int* __restrict__ coords,
                                               const float* __restrict__ g1,
                                               const float* __restrict__ b1,
                                               const float* __restrict__ g2,
                                               const float* __restrict__ b2,
                                               float* __restrict__ out) {
    int t = threadIdx.x;
    int wv = t >> 6, l = t & 63;
    int v = blockIdx.x * 4 + wv;
    const float invn = 1.0f / (float)NVc;
    float mf = stats[l] * invn;
    float vf = stats[64 + l] * invn - mf * mf;
    float rf = rsqrtf(vf + 1e-3f);
    float mc = stats[128 + l] * invn;
    float vc = stats[192 + l] * invn - mc * mc;
    float rc = rsqrtf(vc + 1e-3f);
    float mw0 = stats[256] * invn, vw0 = stats[257] * invn - mw0 * mw0;
    float mw1 = stats[258] * invn, vw1 = stats[259] * invn - mw1 * mw1;
    float rw0 = rsqrtf(vw0 + 1e-3f), rw1 = rsqrtf(vw1 + 1e-3f);
    float fb = (f_pre[v * 64 + l] - mf) * rf * g1[l] + b1[l];
    float f = fmaxf(fb, 0.f);
    float cb_ = (c_pre[v * 64 + l] - mc) * rc * g1[l] + b1[l];
    float c = fmaxf(cb_, 0.f);
    float z0 = (w_pre[v * 2] - mw0) * rw0 * g2[0] + b2[0];
    float z1 = (w_pre[v * 2 + 1] - mw1) * rw1 * g2[1] + b2[1];
    float mz = fmaxf(z0, z1);
    float e0 = __expf(z0 - mz), e1 = __expf(z1 - mz);
    float wd = 1.f / (e0 + e1);
    float aug = (e0 * wd) * f + (e1 * wd) * c;
    int cxi = coords[v * 4 + 1], cyi = coords[v * 4 + 2], czi = coords[v * 4 + 3];
    int cell = cxi + cyi * NXc + czi;
    out[l * CELLS + cell] = pillar[v * 64 + l];
    out[(64 + l) * CELLS + cell] = aug;
    if (l == 0) {
        float* o1 = out + 128 * CELLS;
        o1[cell] = (float)cyi;
        o1[CELLS + cell] = (float)czi;
        o1[2 * CELLS + cell] = (float)cxi;
    }
}

extern "C" void kernel_launch(void* const* d_in, const int* in_sizes, int n_in,
                              void* d_out, int out_size, void* d_ws, size_t ws_size,
                              hipStream_t stream) {
    const float* pillar = (const float*)d_in[0];
    const int*   coords = (const int*)d_in[1];
    const float* pfeat  = (const float*)d_in[2];
    const float* pcoord = (const float*)d_in[3];
    const float* adapt  = (const float*)d_in[4];
    const float* bn1g   = (const float*)d_in[5];
    const float* bn1b   = (const float*)d_in[6];
    const float* ww     = (const float*)d_in[7];
    const float* bn2g   = (const float*)d_in[8];
    const float* bn2b   = (const float*)d_in[9];
    const float* memw   = (const float*)d_in[10];
    float* out = (float*)d_out;
    float* ws  = (float*)d_ws;
    // workspace layout (float offsets)
    float* Pout  = ws + 0;                 // 1,048,576
    float* Q     = ws + 1048576;           // 3,145,728
    int*   sIdx  = (int*)(ws + 4194304);   // 640,000
    // bin structures in the old dIdx region [4834304, 5474304)
    int*   binCnt    = (int*)(ws + 4834304);       // 840
    int*   binStart  = (int*)(ws + 4835144);       // 840
    int*   binCursor = (int*)(ws + 4835984);       // 840
    int*   dIdx6     = (int*)(ws + 4836824);       // 60,000
    float4* binPC    = (float4*)(ws + 4896824);    // 16384 float4 = 65,536 floats
    int*   idxf  = (int*)(ws + 5474304);   // 30,000
    int*   idxc  = (int*)(ws + 5504304);   // 30,000
    float* fpre  = ws + 5534304;           // 640,000
    float* cpre  = ws + 6174304;           // 640,000
    float* wpre  = ws + 6814304;           // 20,000
    float* stats = ws + 6834304;           // 260
    // bf16 feature buffers overlap fpre/cpre (dead until k_gather writes them)
    u16* pillarH = (u16*)(ws + 5534304);           // 643,072 u16
    u16* pfeatH  = pillarH + (size_t)NVPAD * 64;   // 1,048,576 u16
    // bf16 memw copies overlap the head of Q (dead until k_proj writes Q)
    u16* memwH   = (u16*)(ws + 1048576);           // 65,536 u16
    u16* memwTH  = memwH + 65536;                  // 65,536 u16

    k_zero   <<<4096, 256, 0, stream>>>(out, out_size, stats, binCnt);
    k_cast   <<<7184, 256, 0, stream>>>(pillar, pfeat, memw, pcoord,
                                        pillarH, pfeatH, memwH, memwTH, binCnt);
    k_binscan<<<1, 1024, 0, stream>>>(binCnt, binStart, binCursor);
    k_binfill<<<64, 256, 0, stream>>>(pcoord, binCursor, binPC);
    k_score4 <<<dim3(157, 16), 256, 0, stream>>>(pillarH, pfeatH, sIdx);
    k_dist6  <<<40, 256, 0, stream>>>(coords, binPC, binStart, dIdx6);
    k_rerank <<<2500, 256, 0, stream>>>(pillar, coords, pfeat, pcoord, sIdx, dIdx6, idxf, idxc);
    k_mem2   <<<256, 256, 0, stream>>>(pfeatH, memwH, memwTH, Pout);
    k_proj   <<<512, 256, 0, stream>>>(Pout, adapt, Q);
    k_gather <<<250, 256, 0, stream>>>(Q, idxf, idxc, pillar, ww, fpre, cpre, wpre, stats);
    k_final  <<<2500, 256, 0, stream>>>(fpre, cpre, wpre, stats, pillar, coords,
                                        bn1g, bn1b, bn2g, bn2b, out);
}

// Round 6
// 374.836 us; speedup vs baseline: 3.6007x; 1.0610x over previous
//
#include <hip/hip_runtime.h>
#include <math.h>

#define NXc 432
#define NYc 496
#define NVc 10000
#define NPc 16384
#define CELLS (NXc*NYc)          // 214272
#define SHRINKc 0.0025f
#define NVPAD 10048              // 157*64
#define NBX 27
#define NBY 31
#define NBIN (NBX*NBY)           // 837

typedef unsigned short u16;
typedef __attribute__((ext_vector_type(8))) short s16x8;   // 8 bf16
typedef __attribute__((ext_vector_type(4))) float f32x4;

__device__ __forceinline__ unsigned med3u(unsigned a, unsigned b, unsigned c) {
    unsigned d;
    asm("v_med3_u32 %0, %1, %2, %3" : "=v"(d) : "v"(a), "v"(b), "v"(c));
    return d;
}

// ---------------- fp32 -> bf16 (RNE) ----------------
__device__ __forceinline__ u16 f2b(float x) {
    unsigned u = __float_as_uint(x);
    unsigned r = (u + 0x7fffu + ((u >> 16) & 1u)) >> 16;
    return (u16)r;
}

// ---------------- init: zero out/stats + all bf16 casts ----------------
__global__ __launch_bounds__(256) void k_init(const float* __restrict__ pillar,
                                              const float* __restrict__ pfeat,
                                              const float* __restrict__ memw,
                                              const float* __restrict__ adapt,
                                              float* __restrict__ out, int n,
                                              float* __restrict__ stats,
                                              u16* __restrict__ pillarH,
                                              u16* __restrict__ pfeatH,
                                              u16* __restrict__ memwH,
                                              u16* __restrict__ memwTH,
                                              u16* __restrict__ badaptH) {
    int gid = blockIdx.x * 256 + threadIdx.x;      // 7168*256 = 1835008 exactly
    float4 z = make_float4(0.f, 0.f, 0.f, 0.f);
    float4* o4 = (float4*)out;
    int n4 = n >> 2;
    for (int i = gid; i < n4; i += 1835008) o4[i] = z;
    if (gid < (n & 3)) out[n4 * 4 + gid] = 0.f;
    if (gid < 260) stats[gid] = 0.f;
    const int N1 = NVPAD * 64;                     // 643072
    const int N2 = N1 + NPc * 64;                  // 1691648
    const int N3 = N2 + 65536;                     // 1757184
    const int N4 = N3 + 65536;                     // 1822720  (+12288 = 1835008)
    if (gid < N1) {
        int v = gid >> 6;
        pillarH[gid] = f2b(v < NVc ? pillar[gid] : 0.f);
    } else if (gid < N2) {
        pfeatH[gid - N1] = f2b(pfeat[gid - N1]);
    } else if (gid < N3) {
        memwH[gid - N2] = f2b(memw[gid - N2]);
    } else if (gid < N4) {
        int i = gid - N3;
        int d = i >> 10, j = i & 1023;
        memwTH[i] = f2b(memw[j * 64 + d]);         // memwT[d][j]
    } else {
        int i = gid - N4;                          // 0..12287: Badapt[c][d]
        int c = i >> 6, d = i & 63;
        badaptH[i] = f2b(adapt[(c & 63) * 192 + (c >> 6) * 64 + d]);
    }
}

// ---------------- one-block histogram + exclusive scan ----------------
__global__ __launch_bounds__(1024) void k_binscan(const float* __restrict__ pcoord,
                                                  int* __restrict__ binStart,
                                                  int* __restrict__ binCursor) {
    __shared__ int hcnt[1024];
    __shared__ int sc[1024];
    int t = threadIdx.x;
    hcnt[t] = 0;
    __syncthreads();
    for (int j = t; j < NPc; j += 1024) {
        float qx = pcoord[j * 4 + 1], qy = pcoord[j * 4 + 2];
        int bx = (int)(qx * 0.0625f); if (bx > NBX - 1) bx = NBX - 1;
        int by = (int)(qy * 0.0625f); if (by > NBY - 1) by = NBY - 1;
        atomicAdd(&hcnt[by * NBX + bx], 1);
    }
    __syncthreads();
    int vcount = (t < NBIN) ? hcnt[t] : 0;
    sc[t] = vcount;
    __syncthreads();
    for (int off = 1; off < 1024; off <<= 1) {
        int add = (t >= off) ? sc[t - off] : 0;
        __syncthreads();
        sc[t] += add;
        __syncthreads();
    }
    int excl = sc[t] - vcount;
    if (t <= NBIN) { binStart[t] = excl; binCursor[t] = excl; }
}

// ---------------- fill bins: (qx, qy, qz^2, idx-bits) per slot ----------------
__global__ __launch_bounds__(256) void k_binfill(const float* __restrict__ pcoord,
                                                 int* __restrict__ binCursor,
                                                 float4* __restrict__ binPC) {
    int j = blockIdx.x * 256 + threadIdx.x;        // 64*256 = 16384 exactly
    float qx = pcoord[j * 4 + 1], qy = pcoord[j * 4 + 2], qz = pcoord[j * 4 + 3];
    int bx = (int)(qx * 0.0625f); if (bx > NBX - 1) bx = NBX - 1;
    int by = (int)(qy * 0.0625f); if (by > NBY - 1) by = NBY - 1;
    int slot = atomicAdd(&binCursor[by * NBX + bx], 1);
    binPC[slot] = make_float4(qx, qy, qz * qz, __uint_as_float((unsigned)j));
}

// ---------------- exact top-6 nearest points via bin ring search ----------------
__global__ __launch_bounds__(256) void k_dist6(const int* __restrict__ coords,
                                               const float4* __restrict__ binPC,
                                               const int* __restrict__ binStart,
                                               int* __restrict__ dIdx6) {
    int v = blockIdx.x * 256 + threadIdx.x;
    if (v >= NVc) return;
    int xi = coords[v * 4 + 1], yi = coords[v * 4 + 2];
    float x = (float)xi, y = (float)yi;
    int bx = xi >> 4; if (bx > NBX - 1) bx = NBX - 1;
    int by = yi >> 4; if (by > NBY - 1) by = NBY - 1;
    unsigned kk[6] = {~0u, ~0u, ~0u, ~0u, ~0u, ~0u};
    for (int r = 0; r < 32; ++r) {
        int x0 = bx - r, x1 = bx + r, y0 = by - r, y1 = by + r;
        for (int cy = y0; cy <= y1; ++cy) {
            if (cy < 0 || cy > NBY - 1) continue;
            int step = (cy == y0 || cy == y1) ? 1 : (x1 > x0 ? x1 - x0 : 1);
            for (int cx = x0; cx <= x1; cx += step) {
                if (cx < 0 || cx > NBX - 1) continue;
                int b = cy * NBX + cx;
                int s0 = binStart[b], s1 = binStart[b + 1];
                for (int s = s0; s < s1; ++s) {
                    float4 p = binPC[s];
                    float e1 = x - p.x, e2 = y - p.y;
                    float d2 = fmaf(e1, e1, fmaf(e2, e2, p.z));
                    unsigned t = (__float_as_uint(d2) & 0xFFFFC000u) | __float_as_uint(p.w);
                    kk[5] = med3u(kk[4], kk[5], t);
                    kk[4] = med3u(kk[3], kk[4], t);
                    kk[3] = med3u(kk[2], kk[3], t);
                    kk[2] = med3u(kk[1], kk[2], t);
                    kk[1] = med3u(kk[0], kk[1], t);
                    kk[0] = kk[0] < t ? kk[0] : t;
                }
            }
        }
        // stop: points in rings > r have d^2 > 256*r^2; truncated d3 underestimates
        // the true 3rd-best by < 2^-9 relative, so the 1.004 factor is a safe cover.
        if (kk[2] != ~0u) {
            float d3 = __uint_as_float(kk[2] & 0xFFFFC000u);
            if (256.f * (float)(r * r) > d3 * 1.004f + 1e-3f) break;
        }
    }
#pragma unroll
    for (int j = 0; j < 6; ++j) dIdx6[v * 6 + j] = (int)(kk[j] & 16383u);
}

// ---------------- MFMA score candidate top-4, med3 inserts, dbuf staging ----------------
// grid (157,16), block 256 (4 waves). 64 pillars x 1024 points.
__global__ __launch_bounds__(256) void k_score5(const u16* __restrict__ pillarH,
                                                const u16* __restrict__ pfeatH,
                                                int* __restrict__ sIdx) {
    __shared__ u16 BF[2][8192];        // 32 KB double-buffered B fragments
    int t = threadIdx.x;
    int w = t >> 6, l = t & 63;
    int lm = l & 15, qd = l >> 4;
    int pb = blockIdx.x * 64;
    int cb = blockIdx.y * 1024;

    const u16* arow = pillarH + (size_t)(pb + 16 * w + lm) * 64 + qd * 8;
    s16x8 a0 = *(const s16x8*)arow;
    s16x8 a1 = *(const s16x8*)(arow + 32);

    int so[4], doff[4];
#pragma unroll
    for (int r = 0; r < 4; ++r) {
        int q = t + 256 * r;
        int row = q >> 3, g = q & 7;
        so[r] = row * 64 + g * 8;
        doff[r] = (((row >> 4) * 8 + g) * 16 + ((row & 15) ^ g)) * 8;
    }
    uint4 pre[4];
    const u16* src = pfeatH + (size_t)cb * 64;
#pragma unroll
    for (int r = 0; r < 4; ++r) pre[r] = *(const uint4*)(src + so[r]);
#pragma unroll
    for (int r = 0; r < 4; ++r) *(uint4*)&BF[0][doff[r]] = pre[r];

    unsigned sk[4][4];
#pragma unroll
    for (int r = 0; r < 4; ++r)
#pragma unroll
        for (int j = 0; j < 4; ++j) sk[r][j] = 0u;

    for (int s = 0; s < 8; ++s) {
        __syncthreads();                           // BF[s&1] ready; compute(s-1) done
        if (s < 7) {
            const u16* s2 = src + (size_t)(s + 1) * 128 * 64;
#pragma unroll
            for (int r = 0; r < 4; ++r) pre[r] = *(const uint4*)(s2 + so[r]);
        }
        const u16* B = &BF[s & 1][0];
#pragma unroll
        for (int pt = 0; pt < 8; ++pt) {
            s16x8 b0 = *(const s16x8*)&B[(((pt * 8 + qd) * 16) + (lm ^ qd)) * 8];
            s16x8 b1 = *(const s16x8*)&B[(((pt * 8 + qd + 4) * 16) + (lm ^ (qd + 4))) * 8];
            f32x4 acc = {256.f, 256.f, 256.f, 256.f};
            acc = __builtin_amdgcn_mfma_f32_16x16x32_bf16(a0, b0, acc, 0, 0, 0);
            acc = __builtin_amdgcn_mfma_f32_16x16x32_bf16(a1, b1, acc, 0, 0, 0);
            unsigned idf = (unsigned)(1023 - (s * 128 + pt * 16 + lm));
#pragma unroll
            for (int r = 0; r < 4; ++r) {
                unsigned key = (__float_as_uint(acc[r]) & 0xFFFFFC00u) | idf;
                sk[r][3] = med3u(sk[r][2], sk[r][3], key);
                sk[r][2] = med3u(sk[r][1], sk[r][2], key);
                sk[r][1] = med3u(sk[r][0], sk[r][1], key);
                sk[r][0] = sk[r][0] > key ? sk[r][0] : key;
            }
        }
        if (s < 7) {
#pragma unroll
            for (int r = 0; r < 4; ++r) *(uint4*)&BF[(s + 1) & 1][doff[r]] = pre[r];
        }
    }
    __syncthreads();
    unsigned* mrg = (unsigned*)&BF[0][0];          // 16 KB scratch
#pragma unroll
    for (int r = 0; r < 4; ++r) {
        int row = 16 * w + qd * 4 + r;
        *(uint4*)&mrg[(row * 16 + lm) * 4] = make_uint4(sk[r][0], sk[r][1], sk[r][2], sk[r][3]);
    }
    __syncthreads();
    if (t < 64) {
        int gpr = pb + t;
        unsigned m0 = 0u, m1 = 0u, m2 = 0u, m3 = 0u;
#pragma unroll 4
        for (int cc = 0; cc < 16; ++cc) {
            uint4 v = *(const uint4*)&mrg[(t * 16 + cc) * 4];
#pragma unroll
            for (int j = 0; j < 4; ++j) {
                unsigned x = j == 0 ? v.x : (j == 1 ? v.y : (j == 2 ? v.z : v.w));
                m3 = med3u(m2, m3, x);
                m2 = med3u(m1, m2, x);
                m1 = med3u(m0, m1, x);
                m0 = m0 > x ? m0 : x;
            }
        }
        if (gpr < NVc) {
            int base = (blockIdx.y * NVc + gpr) * 4;
            sIdx[base + 0] = cb + 1023 - (int)(m0 & 1023u);
            sIdx[base + 1] = cb + 1023 - (int)(m1 & 1023u);
            sIdx[base + 2] = cb + 1023 - (int)(m2 & 1023u);
            sIdx[base + 3] = cb + 1023 - (int)(m3 & 1023u);
        }
    }
}

// ---------------- fp64 re-rank: scores 64 candidates, dist 6 candidates ----------------
__global__ __launch_bounds__(256) void k_rerank(const float* __restrict__ pillar,
                                                const int* __restrict__ coords,
                                                const float* __restrict__ pfeat,
                                                const float* __restrict__ pcoord,
                                                const int* __restrict__ sIdx,
                                                const int* __restrict__ dIdx6,
                                                int* __restrict__ idx_f,
                                                int* __restrict__ idx_c) {
    int t = threadIdx.x;
    int wv = t >> 6, l = t & 63;
    int v = blockIdx.x * 4 + wv;
    int chunk = l >> 2, slot = l & 3;
    int ps = sIdx[(chunk * NVc + v) * 4 + slot];
    int pd = dIdx6[v * 6 + (l < 6 ? l : 0)];
    double s = 0.0;
#pragma unroll
    for (int i = 0; i < 16; ++i) {
        float4 a = *(const float4*)(pillar + v * 64 + 4 * i);
        float4 b = *(const float4*)(pfeat + ps * 64 + 4 * i);
        s += (double)a.x * (double)b.x + (double)a.y * (double)b.y
           + (double)a.z * (double)b.z + (double)a.w * (double)b.w;
    }
    float4 qc = *(const float4*)(pcoord + pd * 4);
    double db_ = (double)coords[v * 4 + 0] - (double)qc.x;
    double dx_ = (double)coords[v * 4 + 1] - (double)qc.y;
    double dy_ = (double)coords[v * 4 + 2] - (double)qc.z;
    double dz_ = (double)coords[v * 4 + 3] - (double)qc.w;
    double d2 = db_ * db_ + dx_ * dx_ + dy_ * dy_ + dz_ * dz_;
    double sv = s; int sx = ps;
    for (int k = 0; k < 3; ++k) {
        double bv = sv; int bi = sx;
#pragma unroll
        for (int off = 32; off >= 1; off >>= 1) {
            double ov = __shfl_xor(bv, off);
            int    oi = __shfl_xor(bi, off);
            if (ov > bv || (ov == bv && oi < bi)) { bv = ov; bi = oi; }
        }
        if (l == 0) idx_f[v * 3 + k] = bi;
        if (sx == bi) { sv = -INFINITY; sx = 0x7fffffff; }
    }
    double dv = d2; int dx2 = pd;
    for (int k = 0; k < 3; ++k) {
        double bv = dv; int bi = dx2;
#pragma unroll
        for (int off = 32; off >= 1; off >>= 1) {
            double ov = __shfl_xor(bv, off);
            int    oi = __shfl_xor(bi, off);
            if (ov < bv || (ov == bv && oi < bi)) { bv = ov; bi = oi; }
        }
        if (l == 0) idx_c[v * 3 + k] = bi;
        if (dx2 == bi) { dv = INFINITY; dx2 = 0x7fffffff; }
    }
}

// ---------------- MFMA streaming memory_lookup -> bf16 PoutH ----------------
__global__ __launch_bounds__(256) void k_mem2(const u16* __restrict__ pfeatH,
                                              const u16* __restrict__ memwH,
                                              const u16* __restrict__ memwTH,
                                              u16* __restrict__ PoutH) {
    __shared__ u16 WH[8192];
    __shared__ u16 WT[8192];
    __shared__ u16 ST[4][2048];
    int t = threadIdx.x;
    int w = t >> 6, l = t & 63;
    int lm = l & 15, qd = l >> 4;
    int pb = blockIdx.x * 64;

    const u16* arow = pfeatH + (size_t)(pb + 16 * w + lm) * 64 + qd * 8;
    s16x8 a0 = *(const s16x8*)arow;
    s16x8 a1 = *(const s16x8*)(arow + 32);

    float mM[4] = {-INFINITY, -INFINITY, -INFINITY, -INFINITY};
    float Zs[4] = {0.f, 0.f, 0.f, 0.f};

    for (int tile = 0; tile < 8; ++tile) {
        __syncthreads();
#pragma unroll
        for (int r = 0; r < 4; ++r) {
            int q = t + 256 * r;
            int row = q >> 3, g = q & 7;
            uint4 v = *(const uint4*)(memwH + (size_t)(tile * 128 + row) * 64 + g * 8);
            *(uint4*)&WH[(((row >> 4) * 8 + g) * 16 + ((row & 15) ^ g)) * 8] = v;
        }
        __syncthreads();
        f32x4 acc[8];
#pragma unroll
        for (int st = 0; st < 8; ++st) {
            s16x8 b0 = *(const s16x8*)&WH[((st * 8 + qd) * 16 + (lm ^ qd)) * 8];
            s16x8 b1 = *(const s16x8*)&WH[((st * 8 + qd + 4) * 16 + (lm ^ (qd + 4))) * 8];
            f32x4 z = {0.f, 0.f, 0.f, 0.f};
            z = __builtin_amdgcn_mfma_f32_16x16x32_bf16(a0, b0, z, 0, 0, 0);
            z = __builtin_amdgcn_mfma_f32_16x16x32_bf16(a1, b1, z, 0, 0, 0);
            acc[st] = z;
        }
#pragma unroll
        for (int r = 0; r < 4; ++r) {
            float tmax = acc[0][r];
#pragma unroll
            for (int st = 1; st < 8; ++st) tmax = fmaxf(tmax, acc[st][r]);
            float mn = fmaxf(mM[r], tmax);
            float zacc = Zs[r] * __expf(mM[r] - mn);
#pragma unroll
            for (int st = 0; st < 8; ++st) zacc += __expf(acc[st][r] - mn);
            mM[r] = mn; Zs[r] = zacc;
        }
    }
#pragma unroll
    for (int r = 0; r < 4; ++r) {
#pragma unroll
        for (int off = 1; off < 16; off <<= 1) {
            float om = __shfl_xor(mM[r], off);
            float oz = __shfl_xor(Zs[r], off);
            float mn = fmaxf(mM[r], om);
            Zs[r] = Zs[r] * __expf(mM[r] - mn) + oz * __expf(om - mn);
            mM[r] = mn;
        }
    }
    float invZ[4], L1[4] = {0.f, 0.f, 0.f, 0.f};
#pragma unroll
    for (int r = 0; r < 4; ++r) invZ[r] = 1.f / Zs[r];

    f32x4 oacc[4];
#pragma unroll
    for (int n = 0; n < 4; ++n) oacc[n] = (f32x4){0.f, 0.f, 0.f, 0.f};

    for (int tile = 0; tile < 8; ++tile) {
        __syncthreads();
#pragma unroll
        for (int r = 0; r < 4; ++r) {
            int q = t + 256 * r;
            int row = q >> 3, g = q & 7;
            uint4 v = *(const uint4*)(memwH + (size_t)(tile * 128 + row) * 64 + g * 8);
            *(uint4*)&WH[(((row >> 4) * 8 + g) * 16 + ((row & 15) ^ g)) * 8] = v;
        }
#pragma unroll
        for (int r = 0; r < 4; ++r) {
            int q = t + 256 * r;
            int row = q >> 4, g = q & 15;
            uint4 v = *(const uint4*)(memwTH + (size_t)row * 1024 + tile * 128 + g * 8);
            *(uint4*)&WT[(g * 64 + (row ^ g)) * 8] = v;
        }
        __syncthreads();
#pragma unroll
        for (int st = 0; st < 8; ++st) {
            s16x8 b0 = *(const s16x8*)&WH[((st * 8 + qd) * 16 + (lm ^ qd)) * 8];
            s16x8 b1 = *(const s16x8*)&WH[((st * 8 + qd + 4) * 16 + (lm ^ (qd + 4))) * 8];
            f32x4 z = {0.f, 0.f, 0.f, 0.f};
            z = __builtin_amdgcn_mfma_f32_16x16x32_bf16(a0, b0, z, 0, 0, 0);
            z = __builtin_amdgcn_mfma_f32_16x16x32_bf16(a1, b1, z, 0, 0, 0);
            int g2 = st * 2 + (lm >> 3);
#pragma unroll
            for (int r = 0; r < 4; ++r) {
                float e = __expf(z[r] - mM[r]);
                float a = e * invZ[r];
                float tt = a - SHRINKc;
                float sres = fmaxf(tt, 0.f) * a / (fabsf(tt) + 1e-12f);
                L1[r] += sres;
                int rr = qd * 4 + r;
                ST[w][(g2 * 16 + (rr ^ g2)) * 8 + (lm & 7)] = f2b(sres);
            }
        }
#pragma unroll
        for (int ks = 0; ks < 4; ++ks) {
            int g = ks * 4 + qd;
            s16x8 af = *(const s16x8*)&ST[w][(g * 16 + (lm ^ g)) * 8];
#pragma unroll
            for (int n = 0; n < 4; ++n) {
                s16x8 bf = *(const s16x8*)&WT[(g * 64 + ((n * 16 + lm) ^ g)) * 8];
                oacc[n] = __builtin_amdgcn_mfma_f32_16x16x32_bf16(af, bf, oacc[n], 0, 0, 0);
            }
        }
    }
#pragma unroll
    for (int r = 0; r < 4; ++r) {
#pragma unroll
        for (int off = 1; off < 16; off <<= 1) L1[r] += __shfl_xor(L1[r], off);
        L1[r] = 1.f / fmaxf(L1[r], 1e-12f);
    }
#pragma unroll
    for (int n = 0; n < 4; ++n)
#pragma unroll
        for (int r = 0; r < 4; ++r)
            PoutH[(size_t)(pb + 16 * w + qd * 4 + r) * 64 + n * 16 + lm] =
                f2b(oacc[n][r] * L1[r]);
}

// ---------------- MFMA projection: Q = PoutH @ Badapt^T ----------------
__global__ __launch_bounds__(256) void k_proj2(const u16* __restrict__ PoutH,
                                               const u16* __restrict__ badaptH,
                                               float* __restrict__ Q) {
    __shared__ u16 AD[12288];          // 24 KB: Badapt fragments
    int t = threadIdx.x;
    int w = t >> 6, l = t & 63;
    int lm = l & 15, qd = l >> 4;
    int pb = blockIdx.x * 64;
#pragma unroll
    for (int r = 0; r < 6; ++r) {
        int q = t + 256 * r;           // 1536 granules
        int row = q >> 3, g = q & 7;   // row in [0,192)
        uint4 v = *(const uint4*)(badaptH + (size_t)row * 64 + g * 8);
        *(uint4*)&AD[(((row >> 4) * 8 + g) * 16 + ((row & 15) ^ g)) * 8] = v;
    }
    const u16* arow = PoutH + (size_t)(pb + 16 * w + lm) * 64 + qd * 8;
    s16x8 a0 = *(const s16x8*)arow;
    s16x8 a1 = *(const s16x8*)(arow + 32);
    __syncthreads();
    f32x4 acc[12];
#pragma unroll
    for (int nt = 0; nt < 12; ++nt) {
        s16x8 b0 = *(const s16x8*)&AD[(((nt * 8 + qd) * 16) + (lm ^ qd)) * 8];
        s16x8 b1 = *(const s16x8*)&AD[(((nt * 8 + qd + 4) * 16) + (lm ^ (qd + 4))) * 8];
        f32x4 z = {0.f, 0.f, 0.f, 0.f};
        z = __builtin_amdgcn_mfma_f32_16x16x32_bf16(a0, b0, z, 0, 0, 0);
        z = __builtin_amdgcn_mfma_f32_16x16x32_bf16(a1, b1, z, 0, 0, 0);
        acc[nt] = z;
    }
#pragma unroll
    for (int nt = 0; nt < 12; ++nt)
#pragma unroll
        for (int r = 0; r < 4; ++r)
            Q[(size_t)(pb + 16 * w + qd * 4 + r) * 192 + nt * 16 + lm] = acc[nt][r];
}

// ---------------- gather-add + w logits + BN partial sums ----------------
__global__ __launch_bounds__(256) void k_gather(const float* __restrict__ Q,
                                                const int* __restrict__ idx_f,
                                                const int* __restrict__ idx_c,
                                                const float* __restrict__ pillar,
                                                const float* __restrict__ ww,
                                                float* __restrict__ f_pre,
                                                float* __restrict__ c_pre,
                                                float* __restrict__ w_pre,
                                                float* __restrict__ stats) {
    __shared__ float red[4][4][64];
    __shared__ float redw[4][4];
    int t = threadIdx.x;
    int wv = t >> 6, l = t & 63;
    int base = blockIdx.x * 40;
    int vend = base + 40;
    float fs = 0, fq = 0, cs = 0, cq = 0, ws0 = 0, wq0 = 0, ws1 = 0, wq1 = 0;
    float w0l = ww[l], w1l = ww[64 + l];
    for (int v = base + wv; v < vend; v += 4) {
        int if0 = idx_f[v * 3], if1 = idx_f[v * 3 + 1], if2 = idx_f[v * 3 + 2];
        float f = Q[if0 * 192 + l] + Q[if1 * 192 + 64 + l] + Q[if2 * 192 + 128 + l];
        f_pre[v * 64 + l] = f; fs += f; fq += f * f;
        int ic0 = idx_c[v * 3], ic1 = idx_c[v * 3 + 1], ic2 = idx_c[v * 3 + 2];
        float c = Q[ic0 * 192 + l] + Q[ic1 * 192 + 64 + l] + Q[ic2 * 192 + 128 + l];
        c_pre[v * 64 + l] = c; cs += c; cq += c * c;
        float pv = pillar[v * 64 + l];
        float a0 = pv * w0l, a1 = pv * w1l;
#pragma unroll
        for (int off = 32; off >= 1; off >>= 1) {
            a0 += __shfl_xor(a0, off);
            a1 += __shfl_xor(a1, off);
        }
        if (l == 0) { w_pre[v * 2] = a0; w_pre[v * 2 + 1] = a1; }
        ws0 += a0; wq0 += a0 * a0; ws1 += a1; wq1 += a1 * a1;
    }
    red[0][wv][l] = fs; red[1][wv][l] = fq; red[2][wv][l] = cs; red[3][wv][l] = cq;
    if (l == 0) { redw[wv][0] = ws0; redw[wv][1] = wq0; redw[wv][2] = ws1; redw[wv][3] = wq1; }
    __syncthreads();
    if (wv == 0) {
#pragma unroll
        for (int q = 0; q < 4; ++q) {
            float sum = red[q][0][l] + red[q][1][l] + red[q][2][l] + red[q][3][l];
            atomicAdd(&stats[q * 64 + l], sum);
        }
        if (l < 4) {
            float sum = redw[0][l] + redw[1][l] + redw[2][l] + redw[3][l];
            atomicAdd(&stats[256 + l], sum);
        }
    }
}

// ---------------- BN finalize + softmax weights + scatter ----------------
__global__ __launch_bounds__(256) void k_final(const float* __restrict__ f_pre,
                                               const float* __restrict__ c_pre,
                                               const float* __restrict__ w_pre,
                                               const float* __restrict__ stats,
                                               const float* __restrict__ pillar,
                                               const int* __restrict__ coords,
                                               const float* __restrict__ g1,
                                               const float* __restrict__ b1,
                                               const float* __restrict__ g2,
                                               const float* __restrict__ b2,
                                               float* __restrict__ out) {
    int t = threadIdx.x;
    int wv = t >> 6, l = t & 63;
    int v = blockIdx.x * 4 + wv;
    const float invn = 1.0f / (float)NVc;
    float mf = stats[l] * invn;
    float vf = stats[64 + l] * invn - mf * mf;
    float rf = rsqrtf(vf + 1e-3f);
    float mc = stats[128 + l] * invn;
    float vc = stats[192 + l] * invn - mc * mc;
    float rc = rsqrtf(vc + 1e-3f);
    float mw0 = stats[256] * invn, vw0 = stats[257] * invn - mw0 * mw0;
    float mw1 = stats[258] * invn, vw1 = stats[259] * invn - mw1 * mw1;
    float rw0 = rsqrtf(vw0 + 1e-3f), rw1 = rsqrtf(vw1 + 1e-3f);
    float fb = (f_pre[v * 64 + l] - mf) * rf * g1[l] + b1[l];
    float f = fmaxf(fb, 0.f);
    float cb_ = (c_pre[v * 64 + l] - mc) * rc * g1[l] + b1[l];
    float c = fmaxf(cb_, 0.f);
    float z0 = (w_pre[v * 2] - mw0) * rw0 * g2[0] + b2[0];
    float z1 = (w_pre[v * 2 + 1] - mw1) * rw1 * g2[1] + b2[1];
    float mz = fmaxf(z0, z1);
    float e0 = __expf(z0 - mz), e1 = __expf(z1 - mz);
    float wd = 1.f / (e0 + e1);
    float aug = (e0 * wd) * f + (e1 * wd) * c;
    int cxi = coords[v * 4 + 1], cyi = coords[v * 4 + 2], czi = coords[v * 4 + 3];
    int cell = cxi + cyi * NXc + czi;
    out[l * CELLS + cell] = pillar[v * 64 + l];
    out[(64 + l) * CELLS + cell] = aug;
    if (l == 0) {
        float* o1 = out + 128 * CELLS;
        o1[cell] = (float)cyi;
        o1[CELLS + cell] = (float)czi;
        o1[2 * CELLS + cell] = (float)cxi;
    }
}

extern "C" void kernel_launch(void* const* d_in, const int* in_sizes, int n_in,
                              void* d_out, int out_size, void* d_ws, size_t ws_size,
                              hipStream_t stream) {
    const float* pillar = (const float*)d_in[0];
    const int*   coords = (const int*)d_in[1];
    const float* pfeat  = (const float*)d_in[2];
    const float* pcoord = (const float*)d_in[3];
    const float* adapt  = (const float*)d_in[4];
    const float* bn1g   = (const float*)d_in[5];
    const float* bn1b   = (const float*)d_in[6];
    const float* ww     = (const float*)d_in[7];
    const float* bn2g   = (const float*)d_in[8];
    const float* bn2b   = (const float*)d_in[9];
    const float* memw   = (const float*)d_in[10];
    float* out = (float*)d_out;
    float* ws  = (float*)d_ws;
    // workspace layout (float offsets)
    u16*   PoutH = (u16*)(ws + 0);                 // 1,048,576 u16 = 524,288 fl
    float* Q     = ws + 1048576;                   // 3,145,728 fl
    int*   sIdx  = (int*)(ws + 4194304);           // 640,000
    int*   binStart  = (int*)(ws + 4834304);       // 838
    int*   binCursor = (int*)(ws + 4835200);       // 838
    int*   dIdx6     = (int*)(ws + 4836824);       // 60,000
    float4* binPC    = (float4*)(ws + 4896824);    // 65,536 fl, ends 4962360
    u16*   memwH   = (u16*)(ws + 4970000);         // 65,536 u16 -> 32,768 fl
    u16*   memwTH  = (u16*)(ws + 5002768);         // 65,536 u16
    u16*   badaptH = (u16*)(ws + 5035536);         // 12,288 u16
    int*   idxf  = (int*)(ws + 5474304);           // 30,000
    int*   idxc  = (int*)(ws + 5504304);           // 30,000
    float* fpre  = ws + 5534304;                   // 640,000
    float* cpre  = ws + 6174304;                   // 640,000
    float* wpre  = ws + 6814304;                   // 20,000
    float* stats = ws + 6834304;                   // 260
    // bf16 feature buffers overlap fpre/cpre (dead until k_gather writes them)
    u16* pillarH = (u16*)(ws + 5534304);           // 643,072 u16
    u16* pfeatH  = pillarH + (size_t)NVPAD * 64;   // 1,048,576 u16

    k_init   <<<7168, 256, 0, stream>>>(pillar, pfeat, memw, adapt, out, out_size,
                                        stats, pillarH, pfeatH, memwH, memwTH, badaptH);
    k_binscan<<<1, 1024, 0, stream>>>(pcoord, binStart, binCursor);
    k_binfill<<<64, 256, 0, stream>>>(pcoord, binCursor, binPC);
    k_score5 <<<dim3(157, 16), 256, 0, stream>>>(pillarH, pfeatH, sIdx);
    k_dist6  <<<40, 256, 0, stream>>>(coords, binPC, binStart, dIdx6);
    k_rerank <<<2500, 256, 0, stream>>>(pillar, coords, pfeat, pcoord, sIdx, dIdx6, idxf, idxc);
    k_mem2   <<<256, 256, 0, stream>>>(pfeatH, memwH, memwTH, PoutH);
    k_proj2  <<<256, 256, 0, stream>>>(PoutH, badaptH, Q);
    k_gather <<<250, 256, 0, stream>>>(Q, idxf, idxc, pillar, ww, fpre, cpre, wpre, stats);
    k_final  <<<2500, 256, 0, stream>>>(fpre, cpre, wpre, stats, pillar, coords,
                                        bn1g, bn1b, bn2g, bn2b, out);
}

// Round 7
// 359.500 us; speedup vs baseline: 3.7543x; 1.0427x over previous
//
#include <hip/hip_runtime.h>
#include <math.h>

#define NXc 432
#define NYc 496
#define NVc 10000
#define NPc 16384
#define CELLS (NXc*NYc)          // 214272
#define SHRINKc 0.0025f
#define NVPAD 10048              // 157*64
#define NBX 27
#define NBY 31
#define NBIN (NBX*NBY)           // 837

typedef unsigned short u16;
typedef __attribute__((ext_vector_type(8))) short s16x8;   // 8 bf16
typedef __attribute__((ext_vector_type(4))) float f32x4;

__device__ __forceinline__ unsigned med3u(unsigned a, unsigned b, unsigned c) {
    unsigned d;
    asm("v_med3_u32 %0, %1, %2, %3" : "=v"(d) : "v"(a), "v"(b), "v"(c));
    return d;
}

// ---------------- fp32 -> bf16 (RNE) ----------------
__device__ __forceinline__ u16 f2b(float x) {
    unsigned u = __float_as_uint(x);
    unsigned r = (u + 0x7fffu + ((u >> 16) & 1u)) >> 16;
    return (u16)r;
}

// ---------------- init: stats zero + cellMap=-1 + all bf16 casts ----------------
__global__ __launch_bounds__(256) void k_init(const float* __restrict__ pillar,
                                              const float* __restrict__ pfeat,
                                              const float* __restrict__ memw,
                                              const float* __restrict__ adapt,
                                              float* __restrict__ stats,
                                              int* __restrict__ cellMap,
                                              u16* __restrict__ pillarH,
                                              u16* __restrict__ pfeatH,
                                              u16* __restrict__ memwH,
                                              u16* __restrict__ memwTH,
                                              u16* __restrict__ badaptH) {
    int gid = blockIdx.x * 256 + threadIdx.x;      // 7168*256 = 1835008 exactly
    if (gid < CELLS) cellMap[gid] = -1;
    if (gid < 260) stats[gid] = 0.f;
    const int N1 = NVPAD * 64;                     // 643072
    const int N2 = N1 + NPc * 64;                  // 1691648
    const int N3 = N2 + 65536;                     // 1757184
    const int N4 = N3 + 65536;                     // 1822720  (+12288 = 1835008)
    if (gid < N1) {
        int v = gid >> 6;
        pillarH[gid] = f2b(v < NVc ? pillar[gid] : 0.f);
    } else if (gid < N2) {
        pfeatH[gid - N1] = f2b(pfeat[gid - N1]);
    } else if (gid < N3) {
        memwH[gid - N2] = f2b(memw[gid - N2]);
    } else if (gid < N4) {
        int i = gid - N3;
        int d = i >> 10, j = i & 1023;
        memwTH[i] = f2b(memw[j * 64 + d]);         // memwT[d][j]
    } else {
        int i = gid - N4;                          // 0..12287: Badapt[c][d]
        int c = i >> 6, d = i & 63;
        badaptH[i] = f2b(adapt[(c & 63) * 192 + (c >> 6) * 64 + d]);
    }
}

// ---------------- one-block histogram + exclusive scan ----------------
__global__ __launch_bounds__(1024) void k_binscan(const float* __restrict__ pcoord,
                                                  int* __restrict__ binStart,
                                                  int* __restrict__ binCursor) {
    __shared__ int hcnt[1024];
    __shared__ int sc[1024];
    int t = threadIdx.x;
    hcnt[t] = 0;
    __syncthreads();
    for (int j = t; j < NPc; j += 1024) {
        float qx = pcoord[j * 4 + 1], qy = pcoord[j * 4 + 2];
        int bx = (int)(qx * 0.0625f); if (bx > NBX - 1) bx = NBX - 1;
        int by = (int)(qy * 0.0625f); if (by > NBY - 1) by = NBY - 1;
        atomicAdd(&hcnt[by * NBX + bx], 1);
    }
    __syncthreads();
    int vcount = (t < NBIN) ? hcnt[t] : 0;
    sc[t] = vcount;
    __syncthreads();
    for (int off = 1; off < 1024; off <<= 1) {
        int add = (t >= off) ? sc[t - off] : 0;
        __syncthreads();
        sc[t] += add;
        __syncthreads();
    }
    int excl = sc[t] - vcount;
    if (t <= NBIN) { binStart[t] = excl; binCursor[t] = excl; }
}

// ---------------- fill bins + cellMap scatter ----------------
__global__ __launch_bounds__(256) void k_binfill(const float* __restrict__ pcoord,
                                                 const int* __restrict__ coords,
                                                 int* __restrict__ binCursor,
                                                 float4* __restrict__ binPC,
                                                 int* __restrict__ cellMap) {
    int j = blockIdx.x * 256 + threadIdx.x;        // 64*256 = 16384 exactly
    float qx = pcoord[j * 4 + 1], qy = pcoord[j * 4 + 2], qz = pcoord[j * 4 + 3];
    int bx = (int)(qx * 0.0625f); if (bx > NBX - 1) bx = NBX - 1;
    int by = (int)(qy * 0.0625f); if (by > NBY - 1) by = NBY - 1;
    int slot = atomicAdd(&binCursor[by * NBX + bx], 1);
    binPC[slot] = make_float4(qx, qy, qz * qz, __uint_as_float((unsigned)j));
    if (j < NVc) {
        int cell = coords[j * 4 + 1] + coords[j * 4 + 2] * NXc + coords[j * 4 + 3];
        cellMap[cell] = j;
    }
}

// ---------------- exact top-6 nearest points via bin ring search ----------------
__global__ __launch_bounds__(64) void k_dist6(const int* __restrict__ coords,
                                              const float4* __restrict__ binPC,
                                              const int* __restrict__ binStart,
                                              int* __restrict__ dIdx6) {
    int v = blockIdx.x * 64 + threadIdx.x;         // 157 blocks -> 157 CUs
    if (v >= NVc) return;
    int xi = coords[v * 4 + 1], yi = coords[v * 4 + 2];
    float x = (float)xi, y = (float)yi;
    int bx = xi >> 4; if (bx > NBX - 1) bx = NBX - 1;
    int by = yi >> 4; if (by > NBY - 1) by = NBY - 1;
    unsigned kk[6] = {~0u, ~0u, ~0u, ~0u, ~0u, ~0u};
    for (int r = 0; r < 32; ++r) {
        int x0 = bx - r, x1 = bx + r, y0 = by - r, y1 = by + r;
        for (int cy = y0; cy <= y1; ++cy) {
            if (cy < 0 || cy > NBY - 1) continue;
            int step = (cy == y0 || cy == y1) ? 1 : (x1 > x0 ? x1 - x0 : 1);
            for (int cx = x0; cx <= x1; cx += step) {
                if (cx < 0 || cx > NBX - 1) continue;
                int b = cy * NBX + cx;
                int s0 = binStart[b], s1 = binStart[b + 1];
                for (int s = s0; s < s1; ++s) {
                    float4 p = binPC[s];
                    float e1 = x - p.x, e2 = y - p.y;
                    float d2 = fmaf(e1, e1, fmaf(e2, e2, p.z));
                    unsigned t = (__float_as_uint(d2) & 0xFFFFC000u) | __float_as_uint(p.w);
                    kk[5] = med3u(kk[4], kk[5], t);
                    kk[4] = med3u(kk[3], kk[4], t);
                    kk[3] = med3u(kk[2], kk[3], t);
                    kk[2] = med3u(kk[1], kk[2], t);
                    kk[1] = med3u(kk[0], kk[1], t);
                    kk[0] = kk[0] < t ? kk[0] : t;
                }
            }
        }
        if (kk[2] != ~0u) {
            float d3 = __uint_as_float(kk[2] & 0xFFFFC000u);
            if (256.f * (float)(r * r) > d3 * 1.004f + 1e-3f) break;
        }
    }
#pragma unroll
    for (int j2 = 0; j2 < 6; ++j2) dIdx6[v * 6 + j2] = (int)(kk[j2] & 16383u);
}

// ---------------- MFMA score candidate top-4, med3 inserts, dbuf staging ----------------
__global__ __launch_bounds__(256) void k_score5(const u16* __restrict__ pillarH,
                                                const u16* __restrict__ pfeatH,
                                                int* __restrict__ sIdx) {
    __shared__ u16 BF[2][8192];        // 32 KB double-buffered B fragments
    int t = threadIdx.x;
    int w = t >> 6, l = t & 63;
    int lm = l & 15, qd = l >> 4;
    int pb = blockIdx.x * 64;
    int cb = blockIdx.y * 1024;

    const u16* arow = pillarH + (size_t)(pb + 16 * w + lm) * 64 + qd * 8;
    s16x8 a0 = *(const s16x8*)arow;
    s16x8 a1 = *(const s16x8*)(arow + 32);

    int so[4], doff[4];
#pragma unroll
    for (int r = 0; r < 4; ++r) {
        int q = t + 256 * r;
        int row = q >> 3, g = q & 7;
        so[r] = row * 64 + g * 8;
        doff[r] = (((row >> 4) * 8 + g) * 16 + ((row & 15) ^ g)) * 8;
    }
    uint4 pre[4];
    const u16* src = pfeatH + (size_t)cb * 64;
#pragma unroll
    for (int r = 0; r < 4; ++r) pre[r] = *(const uint4*)(src + so[r]);
#pragma unroll
    for (int r = 0; r < 4; ++r) *(uint4*)&BF[0][doff[r]] = pre[r];

    unsigned sk[4][4];
#pragma unroll
    for (int r = 0; r < 4; ++r)
#pragma unroll
        for (int j = 0; j < 4; ++j) sk[r][j] = 0u;

    for (int s = 0; s < 8; ++s) {
        __syncthreads();
        if (s < 7) {
            const u16* s2 = src + (size_t)(s + 1) * 128 * 64;
#pragma unroll
            for (int r = 0; r < 4; ++r) pre[r] = *(const uint4*)(s2 + so[r]);
        }
        const u16* B = &BF[s & 1][0];
#pragma unroll
        for (int pt = 0; pt < 8; ++pt) {
            s16x8 b0 = *(const s16x8*)&B[(((pt * 8 + qd) * 16) + (lm ^ qd)) * 8];
            s16x8 b1 = *(const s16x8*)&B[(((pt * 8 + qd + 4) * 16) + (lm ^ (qd + 4))) * 8];
            f32x4 acc = {256.f, 256.f, 256.f, 256.f};
            acc = __builtin_amdgcn_mfma_f32_16x16x32_bf16(a0, b0, acc, 0, 0, 0);
            acc = __builtin_amdgcn_mfma_f32_16x16x32_bf16(a1, b1, acc, 0, 0, 0);
            unsigned idf = (unsigned)(1023 - (s * 128 + pt * 16 + lm));
#pragma unroll
            for (int r = 0; r < 4; ++r) {
                unsigned key = (__float_as_uint(acc[r]) & 0xFFFFFC00u) | idf;
                sk[r][3] = med3u(sk[r][2], sk[r][3], key);
                sk[r][2] = med3u(sk[r][1], sk[r][2], key);
                sk[r][1] = med3u(sk[r][0], sk[r][1], key);
                sk[r][0] = sk[r][0] > key ? sk[r][0] : key;
            }
        }
        if (s < 7) {
#pragma unroll
            for (int r = 0; r < 4; ++r) *(uint4*)&BF[(s + 1) & 1][doff[r]] = pre[r];
        }
    }
    __syncthreads();
    unsigned* mrg = (unsigned*)&BF[0][0];          // 16 KB scratch
#pragma unroll
    for (int r = 0; r < 4; ++r) {
        int row = 16 * w + qd * 4 + r;
        *(uint4*)&mrg[(row * 16 + lm) * 4] = make_uint4(sk[r][0], sk[r][1], sk[r][2], sk[r][3]);
    }
    __syncthreads();
    if (t < 64) {
        int gpr = pb + t;
        unsigned m0 = 0u, m1 = 0u, m2 = 0u, m3 = 0u;
#pragma unroll 4
        for (int cc = 0; cc < 16; ++cc) {
            uint4 v = *(const uint4*)&mrg[(t * 16 + cc) * 4];
#pragma unroll
            for (int j = 0; j < 4; ++j) {
                unsigned x = j == 0 ? v.x : (j == 1 ? v.y : (j == 2 ? v.z : v.w));
                m3 = med3u(m2, m3, x);
                m2 = med3u(m1, m2, x);
                m1 = med3u(m0, m1, x);
                m0 = m0 > x ? m0 : x;
            }
        }
        if (gpr < NVc) {
            int base = (blockIdx.y * NVc + gpr) * 4;
            sIdx[base + 0] = cb + 1023 - (int)(m0 & 1023u);
            sIdx[base + 1] = cb + 1023 - (int)(m1 & 1023u);
            sIdx[base + 2] = cb + 1023 - (int)(m2 & 1023u);
            sIdx[base + 3] = cb + 1023 - (int)(m3 & 1023u);
        }
    }
}

// ---------------- fp64 re-rank: scores 64 candidates, dist 6 candidates ----------------
__global__ __launch_bounds__(256) void k_rerank(const float* __restrict__ pillar,
                                                const int* __restrict__ coords,
                                                const float* __restrict__ pfeat,
                                                const float* __restrict__ pcoord,
                                                const int* __restrict__ sIdx,
                                                const int* __restrict__ dIdx6,
                                                int* __restrict__ idx_f,
                                                int* __restrict__ idx_c) {
    int t = threadIdx.x;
    int wv = t >> 6, l = t & 63;
    int v = blockIdx.x * 4 + wv;
    int chunk = l >> 2, slot = l & 3;
    int ps = sIdx[(chunk * NVc + v) * 4 + slot];
    int pd = dIdx6[v * 6 + (l < 6 ? l : 0)];
    double s = 0.0;
#pragma unroll
    for (int i = 0; i < 16; ++i) {
        float4 a = *(const float4*)(pillar + v * 64 + 4 * i);
        float4 b = *(const float4*)(pfeat + ps * 64 + 4 * i);
        s += (double)a.x * (double)b.x + (double)a.y * (double)b.y
           + (double)a.z * (double)b.z + (double)a.w * (double)b.w;
    }
    float4 qc = *(const float4*)(pcoord + pd * 4);
    double db_ = (double)coords[v * 4 + 0] - (double)qc.x;
    double dx_ = (double)coords[v * 4 + 1] - (double)qc.y;
    double dy_ = (double)coords[v * 4 + 2] - (double)qc.z;
    double dz_ = (double)coords[v * 4 + 3] - (double)qc.w;
    double d2 = db_ * db_ + dx_ * dx_ + dy_ * dy_ + dz_ * dz_;
    double sv = s; int sx = ps;
    for (int k = 0; k < 3; ++k) {
        double bv = sv; int bi = sx;
#pragma unroll
        for (int off = 32; off >= 1; off >>= 1) {
            double ov = __shfl_xor(bv, off);
            int    oi = __shfl_xor(bi, off);
            if (ov > bv || (ov == bv && oi < bi)) { bv = ov; bi = oi; }
        }
        if (l == 0) idx_f[v * 3 + k] = bi;
        if (sx == bi) { sv = -INFINITY; sx = 0x7fffffff; }
    }
    double dv = d2; int dx2 = pd;
    for (int k = 0; k < 3; ++k) {
        double bv = dv; int bi = dx2;
#pragma unroll
        for (int off = 32; off >= 1; off >>= 1) {
            double ov = __shfl_xor(bv, off);
            int    oi = __shfl_xor(bi, off);
            if (ov < bv || (ov == bv && oi < bi)) { bv = ov; bi = oi; }
        }
        if (l == 0) idx_c[v * 3 + k] = bi;
        if (dx2 == bi) { dv = INFINITY; dx2 = 0x7fffffff; }
    }
}

// ---------------- MFMA streaming memory_lookup -> bf16 PoutH ----------------
__global__ __launch_bounds__(256) void k_mem2(const u16* __restrict__ pfeatH,
                                              const u16* __restrict__ memwH,
                                              const u16* __restrict__ memwTH,
                                              u16* __restrict__ PoutH) {
    __shared__ u16 WH[8192];
    __shared__ u16 WT[8192];
    __shared__ u16 ST[4][2048];
    int t = threadIdx.x;
    int w = t >> 6, l = t & 63;
    int lm = l & 15, qd = l >> 4;
    int pb = blockIdx.x * 64;

    const u16* arow = pfeatH + (size_t)(pb + 16 * w + lm) * 64 + qd * 8;
    s16x8 a0 = *(const s16x8*)arow;
    s16x8 a1 = *(const s16x8*)(arow + 32);

    float mM[4] = {-INFINITY, -INFINITY, -INFINITY, -INFINITY};
    float Zs[4] = {0.f, 0.f, 0.f, 0.f};

    for (int tile = 0; tile < 8; ++tile) {
        __syncthreads();
#pragma unroll
        for (int r = 0; r < 4; ++r) {
            int q = t + 256 * r;
            int row = q >> 3, g = q & 7;
            uint4 v = *(const uint4*)(memwH + (size_t)(tile * 128 + row) * 64 + g * 8);
            *(uint4*)&WH[(((row >> 4) * 8 + g) * 16 + ((row & 15) ^ g)) * 8] = v;
        }
        __syncthreads();
        f32x4 acc[8];
#pragma unroll
        for (int st = 0; st < 8; ++st) {
            s16x8 b0 = *(const s16x8*)&WH[((st * 8 + qd) * 16 + (lm ^ qd)) * 8];
            s16x8 b1 = *(const s16x8*)&WH[((st * 8 + qd + 4) * 16 + (lm ^ (qd + 4))) * 8];
            f32x4 z = {0.f, 0.f, 0.f, 0.f};
            z = __builtin_amdgcn_mfma_f32_16x16x32_bf16(a0, b0, z, 0, 0, 0);
            z = __builtin_amdgcn_mfma_f32_16x16x32_bf16(a1, b1, z, 0, 0, 0);
            acc[st] = z;
        }
#pragma unroll
        for (int r = 0; r < 4; ++r) {
            float tmax = acc[0][r];
#pragma unroll
            for (int st = 1; st < 8; ++st) tmax = fmaxf(tmax, acc[st][r]);
            float mn = fmaxf(mM[r], tmax);
            float zacc = Zs[r] * __expf(mM[r] - mn);
#pragma unroll
            for (int st = 0; st < 8; ++st) zacc += __expf(acc[st][r] - mn);
            mM[r] = mn; Zs[r] = zacc;
        }
    }
#pragma unroll
    for (int r = 0; r < 4; ++r) {
#pragma unroll
        for (int off = 1; off < 16; off <<= 1) {
            float om = __shfl_xor(mM[r], off);
            float oz = __shfl_xor(Zs[r], off);
            float mn = fmaxf(mM[r], om);
            Zs[r] = Zs[r] * __expf(mM[r] - mn) + oz * __expf(om - mn);
            mM[r] = mn;
        }
    }
    float invZ[4], L1[4] = {0.f, 0.f, 0.f, 0.f};
#pragma unroll
    for (int r = 0; r < 4; ++r) invZ[r] = 1.f / Zs[r];

    f32x4 oacc[4];
#pragma unroll
    for (int n = 0; n < 4; ++n) oacc[n] = (f32x4){0.f, 0.f, 0.f, 0.f};

    for (int tile = 0; tile < 8; ++tile) {
        __syncthreads();
#pragma unroll
        for (int r = 0; r < 4; ++r) {
            int q = t + 256 * r;
            int row = q >> 3, g = q & 7;
            uint4 v = *(const uint4*)(memwH + (size_t)(tile * 128 + row) * 64 + g * 8);
            *(uint4*)&WH[(((row >> 4) * 8 + g) * 16 + ((row & 15) ^ g)) * 8] = v;
        }
#pragma unroll
        for (int r = 0; r < 4; ++r) {
            int q = t + 256 * r;
            int row = q >> 4, g = q & 15;
            uint4 v = *(const uint4*)(memwTH + (size_t)row * 1024 + tile * 128 + g * 8);
            *(uint4*)&WT[(g * 64 + (row ^ g)) * 8] = v;
        }
        __syncthreads();
#pragma unroll
        for (int st = 0; st < 8; ++st) {
            s16x8 b0 = *(const s16x8*)&WH[((st * 8 + qd) * 16 + (lm ^ qd)) * 8];
            s16x8 b1 = *(const s16x8*)&WH[((st * 8 + qd + 4) * 16 + (lm ^ (qd + 4))) * 8];
            f32x4 z = {0.f, 0.f, 0.f, 0.f};
            z = __builtin_amdgcn_mfma_f32_16x16x32_bf16(a0, b0, z, 0, 0, 0);
            z = __builtin_amdgcn_mfma_f32_16x16x32_bf16(a1, b1, z, 0, 0, 0);
            int g2 = st * 2 + (lm >> 3);
#pragma unroll
            for (int r = 0; r < 4; ++r) {
                float e = __expf(z[r] - mM[r]);
                float a = e * invZ[r];
                float tt = a - SHRINKc;
                float sres = fmaxf(tt, 0.f) * a / (fabsf(tt) + 1e-12f);
                L1[r] += sres;
                int rr = qd * 4 + r;
                ST[w][(g2 * 16 + (rr ^ g2)) * 8 + (lm & 7)] = f2b(sres);
            }
        }
#pragma unroll
        for (int ks = 0; ks < 4; ++ks) {
            int g = ks * 4 + qd;
            s16x8 af = *(const s16x8*)&ST[w][(g * 16 + (lm ^ g)) * 8];
#pragma unroll
            for (int n = 0; n < 4; ++n) {
                s16x8 bf = *(const s16x8*)&WT[(g * 64 + ((n * 16 + lm) ^ g)) * 8];
                oacc[n] = __builtin_amdgcn_mfma_f32_16x16x32_bf16(af, bf, oacc[n], 0, 0, 0);
            }
        }
    }
#pragma unroll
    for (int r = 0; r < 4; ++r) {
#pragma unroll
        for (int off = 1; off < 16; off <<= 1) L1[r] += __shfl_xor(L1[r], off);
        L1[r] = 1.f / fmaxf(L1[r], 1e-12f);
    }
#pragma unroll
    for (int n = 0; n < 4; ++n)
#pragma unroll
        for (int r = 0; r < 4; ++r)
            PoutH[(size_t)(pb + 16 * w + qd * 4 + r) * 64 + n * 16 + lm] =
                f2b(oacc[n][r] * L1[r]);
}

// ---------------- MFMA projection: Q = PoutH @ Badapt^T ----------------
__global__ __launch_bounds__(256) void k_proj2(const u16* __restrict__ PoutH,
                                               const u16* __restrict__ badaptH,
                                               float* __restrict__ Q) {
    __shared__ u16 AD[12288];
    int t = threadIdx.x;
    int w = t >> 6, l = t & 63;
    int lm = l & 15, qd = l >> 4;
    int pb = blockIdx.x * 64;
#pragma unroll
    for (int r = 0; r < 6; ++r) {
        int q = t + 256 * r;
        int row = q >> 3, g = q & 7;
        uint4 v = *(const uint4*)(badaptH + (size_t)row * 64 + g * 8);
        *(uint4*)&AD[(((row >> 4) * 8 + g) * 16 + ((row & 15) ^ g)) * 8] = v;
    }
    const u16* arow = PoutH + (size_t)(pb + 16 * w + lm) * 64 + qd * 8;
    s16x8 a0 = *(const s16x8*)arow;
    s16x8 a1 = *(const s16x8*)(arow + 32);
    __syncthreads();
    f32x4 acc[12];
#pragma unroll
    for (int nt = 0; nt < 12; ++nt) {
        s16x8 b0 = *(const s16x8*)&AD[(((nt * 8 + qd) * 16) + (lm ^ qd)) * 8];
        s16x8 b1 = *(const s16x8*)&AD[(((nt * 8 + qd + 4) * 16) + (lm ^ (qd + 4))) * 8];
        f32x4 z = {0.f, 0.f, 0.f, 0.f};
        z = __builtin_amdgcn_mfma_f32_16x16x32_bf16(a0, b0, z, 0, 0, 0);
        z = __builtin_amdgcn_mfma_f32_16x16x32_bf16(a1, b1, z, 0, 0, 0);
        acc[nt] = z;
    }
#pragma unroll
    for (int nt = 0; nt < 12; ++nt)
#pragma unroll
        for (int r = 0; r < 4; ++r)
            Q[(size_t)(pb + 16 * w + qd * 4 + r) * 192 + nt * 16 + lm] = acc[nt][r];
}

// ---------------- gather-add + w logits + BN partial sums ----------------
__global__ __launch_bounds__(256) void k_gather(const float* __restrict__ Q,
                                                const int* __restrict__ idx_f,
                                                const int* __restrict__ idx_c,
                                                const float* __restrict__ pillar,
                                                const float* __restrict__ ww,
                                                float* __restrict__ f_pre,
                                                float* __restrict__ c_pre,
                                                float* __restrict__ w_pre,
                                                float* __restrict__ stats) {
    __shared__ float red[4][4][64];
    __shared__ float redw[4][4];
    int t = threadIdx.x;
    int wv = t >> 6, l = t & 63;
    int base = blockIdx.x * 40;
    int vend = base + 40;
    float fs = 0, fq = 0, cs = 0, cq = 0, ws0 = 0, wq0 = 0, ws1 = 0, wq1 = 0;
    float w0l = ww[l], w1l = ww[64 + l];
    for (int v = base + wv; v < vend; v += 4) {
        int if0 = idx_f[v * 3], if1 = idx_f[v * 3 + 1], if2 = idx_f[v * 3 + 2];
        float f = Q[if0 * 192 + l] + Q[if1 * 192 + 64 + l] + Q[if2 * 192 + 128 + l];
        f_pre[v * 64 + l] = f; fs += f; fq += f * f;
        int ic0 = idx_c[v * 3], ic1 = idx_c[v * 3 + 1], ic2 = idx_c[v * 3 + 2];
        float c = Q[ic0 * 192 + l] + Q[ic1 * 192 + 64 + l] + Q[ic2 * 192 + 128 + l];
        c_pre[v * 64 + l] = c; cs += c; cq += c * c;
        float pv = pillar[v * 64 + l];
        float a0 = pv * w0l, a1 = pv * w1l;
#pragma unroll
        for (int off = 32; off >= 1; off >>= 1) {
            a0 += __shfl_xor(a0, off);
            a1 += __shfl_xor(a1, off);
        }
        if (l == 0) { w_pre[v * 2] = a0; w_pre[v * 2 + 1] = a1; }
        ws0 += a0; wq0 += a0 * a0; ws1 += a1; wq1 += a1 * a1;
    }
    red[0][wv][l] = fs; red[1][wv][l] = fq; red[2][wv][l] = cs; red[3][wv][l] = cq;
    if (l == 0) { redw[wv][0] = ws0; redw[wv][1] = wq0; redw[wv][2] = ws1; redw[wv][3] = wq1; }
    __syncthreads();
    if (wv == 0) {
#pragma unroll
        for (int q = 0; q < 4; ++q) {
            float sum = red[q][0][l] + red[q][1][l] + red[q][2][l] + red[q][3][l];
            atomicAdd(&stats[q * 64 + l], sum);
        }
        if (l < 4) {
            float sum = redw[0][l] + redw[1][l] + redw[2][l] + redw[3][l];
            atomicAdd(&stats[256 + l], sum);
        }
    }
}

// ---------------- BN finalize + softmax weights -> compact aug ----------------
__global__ __launch_bounds__(256) void k_aug(const float* __restrict__ f_pre,
                                             const float* __restrict__ c_pre,
                                             const float* __restrict__ w_pre,
                                             const float* __restrict__ stats,
                                             const float* __restrict__ g1,
                                             const float* __restrict__ b1,
                                             const float* __restrict__ g2,
                                             const float* __restrict__ b2,
                                             float* __restrict__ aug) {
    int t = threadIdx.x;
    int wv = t >> 6, l = t & 63;
    int v = blockIdx.x * 4 + wv;
    const float invn = 1.0f / (float)NVc;
    float mf = stats[l] * invn;
    float vf = stats[64 + l] * invn - mf * mf;
    float rf = rsqrtf(vf + 1e-3f);
    float mc = stats[128 + l] * invn;
    float vc = stats[192 + l] * invn - mc * mc;
    float rc = rsqrtf(vc + 1e-3f);
    float mw0 = stats[256] * invn, vw0 = stats[257] * invn - mw0 * mw0;
    float mw1 = stats[258] * invn, vw1 = stats[259] * invn - mw1 * mw1;
    float rw0 = rsqrtf(vw0 + 1e-3f), rw1 = rsqrtf(vw1 + 1e-3f);
    float fb = (f_pre[v * 64 + l] - mf) * rf * g1[l] + b1[l];
    float f = fmaxf(fb, 0.f);
    float cb_ = (c_pre[v * 64 + l] - mc) * rc * g1[l] + b1[l];
    float c = fmaxf(cb_, 0.f);
    float z0 = (w_pre[v * 2] - mw0) * rw0 * g2[0] + b2[0];
    float z1 = (w_pre[v * 2 + 1] - mw1) * rw1 * g2[1] + b2[1];
    float mz = fmaxf(z0, z1);
    float e0 = __expf(z0 - mz), e1 = __expf(z1 - mz);
    float wd = 1.f / (e0 + e1);
    aug[v * 64 + l] = (e0 * wd) * f + (e1 * wd) * c;
}

// ---------------- full-canvas write: select(zero, gathered) per cell ----------------
// grid (210, 4): block covers 1024 cells x 33 feature rows. float4 stores.
__global__ __launch_bounds__(256) void k_out(const int* __restrict__ cellMap,
                                             const float* __restrict__ pillar,
                                             const float* __restrict__ aug,
                                             float* __restrict__ out) {
    int c4 = (blockIdx.x * 256 + threadIdx.x) * 4;
    if (c4 >= CELLS) return;                       // CELLS%4==0 -> full float4 valid
    int4 cm = *(const int4*)(cellMap + c4);
    int f0 = blockIdx.y * 33;
    int f1 = f0 + 33; if (f1 > 131) f1 = 131;
    for (int f = f0; f < f1; ++f) {
        float4 val;
        if (f < 64) {
            val.x = cm.x >= 0 ? pillar[cm.x * 64 + f] : 0.f;
            val.y = cm.y >= 0 ? pillar[cm.y * 64 + f] : 0.f;
            val.z = cm.z >= 0 ? pillar[cm.z * 64 + f] : 0.f;
            val.w = cm.w >= 0 ? pillar[cm.w * 64 + f] : 0.f;
        } else if (f < 128) {
            int fa = f - 64;
            val.x = cm.x >= 0 ? aug[cm.x * 64 + fa] : 0.f;
            val.y = cm.y >= 0 ? aug[cm.y * 64 + fa] : 0.f;
            val.z = cm.z >= 0 ? aug[cm.z * 64 + fa] : 0.f;
            val.w = cm.w >= 0 ? aug[cm.w * 64 + fa] : 0.f;
        } else if (f == 128) {                     // pind[0] = y
            val.x = cm.x >= 0 ? (float)((c4 + 0) / NXc) : 0.f;
            val.y = cm.y >= 0 ? (float)((c4 + 1) / NXc) : 0.f;
            val.z = cm.z >= 0 ? (float)((c4 + 2) / NXc) : 0.f;
            val.w = cm.w >= 0 ? (float)((c4 + 3) / NXc) : 0.f;
        } else if (f == 129) {                     // pind[1] = z = 0
            val = make_float4(0.f, 0.f, 0.f, 0.f);
        } else {                                   // pind[2] = x
            val.x = cm.x >= 0 ? (float)((c4 + 0) % NXc) : 0.f;
            val.y = cm.y >= 0 ? (float)((c4 + 1) % NXc) : 0.f;
            val.z = cm.z >= 0 ? (float)((c4 + 2) % NXc) : 0.f;
            val.w = cm.w >= 0 ? (float)((c4 + 3) % NXc) : 0.f;
        }
        *(float4*)(out + (size_t)f * CELLS + c4) = val;
    }
}

extern "C" void kernel_launch(void* const* d_in, const int* in_sizes, int n_in,
                              void* d_out, int out_size, void* d_ws, size_t ws_size,
                              hipStream_t stream) {
    const float* pillar = (const float*)d_in[0];
    const int*   coords = (const int*)d_in[1];
    const float* pfeat  = (const float*)d_in[2];
    const float* pcoord = (const float*)d_in[3];
    const float* adapt  = (const float*)d_in[4];
    const float* bn1g   = (const float*)d_in[5];
    const float* bn1b   = (const float*)d_in[6];
    const float* ww     = (const float*)d_in[7];
    const float* bn2g   = (const float*)d_in[8];
    const float* bn2b   = (const float*)d_in[9];
    const float* memw   = (const float*)d_in[10];
    float* out = (float*)d_out;
    float* ws  = (float*)d_ws;
    // workspace layout (float offsets)
    u16*   PoutH = (u16*)(ws + 0);                 // 1,048,576 u16
    float* Q     = ws + 1048576;                   // 3,145,728 fl
    int*   sIdx  = (int*)(ws + 4194304);           // 640,000
    int*   binStart  = (int*)(ws + 4834304);       // 838
    int*   binCursor = (int*)(ws + 4835200);       // 838
    int*   dIdx6     = (int*)(ws + 4836824);       // 60,000
    float4* binPC    = (float4*)(ws + 4896824);    // 65,536 fl
    u16*   memwH   = (u16*)(ws + 4970000);         // 65,536 u16
    u16*   memwTH  = (u16*)(ws + 5002768);         // 65,536 u16
    u16*   badaptH = (u16*)(ws + 5035536);         // 12,288 u16
    int*   idxf  = (int*)(ws + 5474304);           // 30,000
    int*   idxc  = (int*)(ws + 5504304);           // 30,000
    float* fpre  = ws + 5534304;                   // 640,000
    float* cpre  = ws + 6174304;                   // 640,000
    float* wpre  = ws + 6814304;                   // 20,000
    float* stats = ws + 6834304;                   // 260
    int*   cellMap = (int*)(ws + 6840000);         // 214,272 ints
    float* aug   = ws + 7060000;                   // 640,000
    // bf16 feature buffers overlap fpre/cpre (dead until k_gather writes them)
    u16* pillarH = (u16*)(ws + 5534304);           // 643,072 u16
    u16* pfeatH  = pillarH + (size_t)NVPAD * 64;   // 1,048,576 u16

    k_init   <<<7168, 256, 0, stream>>>(pillar, pfeat, memw, adapt, stats, cellMap,
                                        pillarH, pfeatH, memwH, memwTH, badaptH);
    k_binscan<<<1, 1024, 0, stream>>>(pcoord, binStart, binCursor);
    k_binfill<<<64, 256, 0, stream>>>(pcoord, coords, binCursor, binPC, cellMap);
    k_score5 <<<dim3(157, 16), 256, 0, stream>>>(pillarH, pfeatH, sIdx);
    k_dist6  <<<157, 64, 0, stream>>>(coords, binPC, binStart, dIdx6);
    k_rerank <<<2500, 256, 0, stream>>>(pillar, coords, pfeat, pcoord, sIdx, dIdx6, idxf, idxc);
    k_mem2   <<<256, 256, 0, stream>>>(pfeatH, memwH, memwTH, PoutH);
    k_proj2  <<<256, 256, 0, stream>>>(PoutH, badaptH, Q);
    k_gather <<<250, 256, 0, stream>>>(Q, idxf, idxc, pillar, ww, fpre, cpre, wpre, stats);
    k_aug    <<<2500, 256, 0, stream>>>(fpre, cpre, wpre, stats, bn1g, bn1b, bn2g, bn2b, aug);
    k_out    <<<dim3(210, 4), 256, 0, stream>>>(cellMap, pillar, aug, out);
}

// Round 8
// 338.415 us; speedup vs baseline: 3.9882x; 1.0623x over previous
//
#include <hip/hip_runtime.h>
#include <math.h>

#define NXc 432
#define NYc 496
#define NVc 10000
#define NPc 16384
#define CELLS (NXc*NYc)          // 214272
#define SHRINKc 0.0025f
#define NVPAD 10048              // 157*64
#define NBX 27
#define NBY 31
#define NBIN (NBX*NBY)           // 837

typedef unsigned short u16;
typedef __attribute__((ext_vector_type(8))) short s16x8;   // 8 bf16
typedef __attribute__((ext_vector_type(4))) float f32x4;

__device__ __forceinline__ unsigned med3u(unsigned a, unsigned b, unsigned c) {
    unsigned d;
    asm("v_med3_u32 %0, %1, %2, %3" : "=v"(d) : "v"(a), "v"(b), "v"(c));
    return d;
}

// ---------------- fp32 -> bf16 (RNE) ----------------
__device__ __forceinline__ u16 f2b(float x) {
    unsigned u = __float_as_uint(x);
    unsigned r = (u + 0x7fffu + ((u >> 16) & 1u)) >> 16;
    return (u16)r;
}

// ---------------- init: stats zero + cellMap=-1 + all bf16 casts ----------------
__global__ __launch_bounds__(256) void k_init(const float* __restrict__ pillar,
                                              const float* __restrict__ pfeat,
                                              const float* __restrict__ memw,
                                              const float* __restrict__ adapt,
                                              float* __restrict__ stats,
                                              int* __restrict__ cellMap,
                                              u16* __restrict__ pillarH,
                                              u16* __restrict__ pfeatH,
                                              u16* __restrict__ memwH,
                                              u16* __restrict__ memwTH,
                                              u16* __restrict__ badaptH) {
    int gid = blockIdx.x * 256 + threadIdx.x;      // 7168*256 = 1835008 exactly
    if (gid < CELLS) cellMap[gid] = -1;
    if (gid < 260) stats[gid] = 0.f;
    const int N1 = NVPAD * 64;                     // 643072
    const int N2 = N1 + NPc * 64;                  // 1691648
    const int N3 = N2 + 65536;                     // 1757184
    const int N4 = N3 + 65536;                     // 1822720  (+12288 = 1835008)
    if (gid < N1) {
        int v = gid >> 6;
        pillarH[gid] = f2b(v < NVc ? pillar[gid] : 0.f);
    } else if (gid < N2) {
        pfeatH[gid - N1] = f2b(pfeat[gid - N1]);
    } else if (gid < N3) {
        memwH[gid - N2] = f2b(memw[gid - N2]);
    } else if (gid < N4) {
        int i = gid - N3;
        int d = i >> 10, j = i & 1023;
        memwTH[i] = f2b(memw[j * 64 + d]);         // memwT[d][j]
    } else {
        int i = gid - N4;                          // 0..12287: Badapt[c][d]
        int c = i >> 6, d = i & 63;
        badaptH[i] = f2b(adapt[(c & 63) * 192 + (c >> 6) * 64 + d]);
    }
}

// ---------------- single-block: histogram + scan + bin fill + cellMap scatter ----------------
__global__ __launch_bounds__(1024) void k_pre(const float* __restrict__ pcoord,
                                              const int* __restrict__ coords,
                                              int* __restrict__ binStart,
                                              float4* __restrict__ binPC,
                                              int* __restrict__ cellMap) {
    __shared__ int hcnt[1024];
    __shared__ int sc[1024];
    __shared__ int cur[1024];
    int t = threadIdx.x;
    hcnt[t] = 0;
    __syncthreads();
    for (int j = t; j < NPc; j += 1024) {
        float qx = pcoord[j * 4 + 1], qy = pcoord[j * 4 + 2];
        int bx = (int)(qx * 0.0625f); if (bx > NBX - 1) bx = NBX - 1;
        int by = (int)(qy * 0.0625f); if (by > NBY - 1) by = NBY - 1;
        atomicAdd(&hcnt[by * NBX + bx], 1);
    }
    __syncthreads();
    int vcount = (t < NBIN) ? hcnt[t] : 0;
    sc[t] = vcount;
    __syncthreads();
    for (int off = 1; off < 1024; off <<= 1) {
        int add = (t >= off) ? sc[t - off] : 0;
        __syncthreads();
        sc[t] += add;
        __syncthreads();
    }
    int excl = sc[t] - vcount;
    cur[t] = excl;
    if (t <= NBIN) binStart[t] = excl;
    __syncthreads();
    for (int j = t; j < NPc; j += 1024) {
        float qx = pcoord[j * 4 + 1], qy = pcoord[j * 4 + 2], qz = pcoord[j * 4 + 3];
        int bx = (int)(qx * 0.0625f); if (bx > NBX - 1) bx = NBX - 1;
        int by = (int)(qy * 0.0625f); if (by > NBY - 1) by = NBY - 1;
        int slot = atomicAdd(&cur[by * NBX + bx], 1);
        binPC[slot] = make_float4(qx, qy, qz * qz, __uint_as_float((unsigned)j));
    }
    for (int j = t; j < NVc; j += 1024) {
        int cell = coords[j * 4 + 1] + coords[j * 4 + 2] * NXc + coords[j * 4 + 3];
        cellMap[cell] = j;
    }
}

// ---------------- FUSED: mem2 (bid<256) | dist6 (256..295) | score5 (296..2807) ----------------
__global__ __launch_bounds__(256) void k_fused(const u16* __restrict__ pillarH,
                                               const u16* __restrict__ pfeatH,
                                               const u16* __restrict__ memwH,
                                               const u16* __restrict__ memwTH,
                                               const int* __restrict__ coords,
                                               const float4* __restrict__ binPC,
                                               const int* __restrict__ binStart,
                                               u16* __restrict__ PoutH,
                                               int* __restrict__ dIdx6,
                                               int* __restrict__ sIdx) {
    __shared__ union {
        u16 bf[2][8192];                           // score role: 32 KB dbuf
        struct { u16 wh[4096]; u16 wt[4096]; u16 st[4][1024]; } m;   // mem role: 24 KB
    } smem;
    int bid = blockIdx.x;
    int t = threadIdx.x;
    int w = t >> 6, l = t & 63;
    int lm = l & 15, qd = l >> 4;

    if (bid < 256) {
        // ================= mem2 role: streaming memory_lookup, 64-row tiles =================
        int pb = bid * 64;
        u16* WH = smem.m.wh;
        u16* WT = smem.m.wt;
        u16* ST = &smem.m.st[w][0];
        const u16* arow = pfeatH + (size_t)(pb + 16 * w + lm) * 64 + qd * 8;
        s16x8 a0 = *(const s16x8*)arow;
        s16x8 a1 = *(const s16x8*)(arow + 32);
        float mM[4] = {-INFINITY, -INFINITY, -INFINITY, -INFINITY};
        float Zs[4] = {0.f, 0.f, 0.f, 0.f};
        // pass 1: online (max, sumexp)
        for (int tile = 0; tile < 16; ++tile) {
            __syncthreads();
#pragma unroll
            for (int r = 0; r < 2; ++r) {
                int q = t + 256 * r;               // 512 granules
                int row = q >> 3, g = q & 7;
                uint4 v = *(const uint4*)(memwH + (size_t)(tile * 64 + row) * 64 + g * 8);
                *(uint4*)&WH[(((row >> 4) * 8 + g) * 16 + ((row & 15) ^ g)) * 8] = v;
            }
            __syncthreads();
            f32x4 acc[4];
#pragma unroll
            for (int st = 0; st < 4; ++st) {
                s16x8 b0 = *(const s16x8*)&WH[((st * 8 + qd) * 16 + (lm ^ qd)) * 8];
                s16x8 b1 = *(const s16x8*)&WH[((st * 8 + qd + 4) * 16 + (lm ^ (qd + 4))) * 8];
                f32x4 z = {0.f, 0.f, 0.f, 0.f};
                z = __builtin_amdgcn_mfma_f32_16x16x32_bf16(a0, b0, z, 0, 0, 0);
                z = __builtin_amdgcn_mfma_f32_16x16x32_bf16(a1, b1, z, 0, 0, 0);
                acc[st] = z;
            }
#pragma unroll
            for (int r = 0; r < 4; ++r) {
                float tmax = acc[0][r];
#pragma unroll
                for (int st = 1; st < 4; ++st) tmax = fmaxf(tmax, acc[st][r]);
                float mn = fmaxf(mM[r], tmax);
                float zacc = Zs[r] * __expf(mM[r] - mn);
#pragma unroll
                for (int st = 0; st < 4; ++st) zacc += __expf(acc[st][r] - mn);
                mM[r] = mn; Zs[r] = zacc;
            }
        }
#pragma unroll
        for (int r = 0; r < 4; ++r) {
#pragma unroll
            for (int off = 1; off < 16; off <<= 1) {
                float om = __shfl_xor(mM[r], off);
                float oz = __shfl_xor(Zs[r], off);
                float mn = fmaxf(mM[r], om);
                Zs[r] = Zs[r] * __expf(mM[r] - mn) + oz * __expf(om - mn);
                mM[r] = mn;
            }
        }
        float invZ[4], L1[4] = {0.f, 0.f, 0.f, 0.f};
#pragma unroll
        for (int r = 0; r < 4; ++r) invZ[r] = 1.f / Zs[r];
        f32x4 oacc[4];
#pragma unroll
        for (int n = 0; n < 4; ++n) oacc[n] = (f32x4){0.f, 0.f, 0.f, 0.f};
        // pass 2: recompute, shrink, transpose via wave-private ST, out-MFMA
        for (int tile = 0; tile < 16; ++tile) {
            __syncthreads();
#pragma unroll
            for (int r = 0; r < 2; ++r) {
                int q = t + 256 * r;
                int row = q >> 3, g = q & 7;
                uint4 v = *(const uint4*)(memwH + (size_t)(tile * 64 + row) * 64 + g * 8);
                *(uint4*)&WH[(((row >> 4) * 8 + g) * 16 + ((row & 15) ^ g)) * 8] = v;
            }
#pragma unroll
            for (int r = 0; r < 2; ++r) {
                int q = t + 256 * r;
                int row = q >> 3, g = q & 7;   // row = n in [0,64)
                uint4 v = *(const uint4*)(memwTH + (size_t)row * 1024 + tile * 64 + g * 8);
                *(uint4*)&WT[(g * 64 + (row ^ g)) * 8] = v;
            }
            __syncthreads();
#pragma unroll
            for (int st = 0; st < 4; ++st) {
                s16x8 b0 = *(const s16x8*)&WH[((st * 8 + qd) * 16 + (lm ^ qd)) * 8];
                s16x8 b1 = *(const s16x8*)&WH[((st * 8 + qd + 4) * 16 + (lm ^ (qd + 4))) * 8];
                f32x4 z = {0.f, 0.f, 0.f, 0.f};
                z = __builtin_amdgcn_mfma_f32_16x16x32_bf16(a0, b0, z, 0, 0, 0);
                z = __builtin_amdgcn_mfma_f32_16x16x32_bf16(a1, b1, z, 0, 0, 0);
                int g2 = st * 2 + (lm >> 3);       // [0,8)
#pragma unroll
                for (int r = 0; r < 4; ++r) {
                    float e = __expf(z[r] - mM[r]);
                    float a = e * invZ[r];
                    float tt = a - SHRINKc;
                    float sres = fmaxf(tt, 0.f) * a / (fabsf(tt) + 1e-12f);
                    L1[r] += sres;
                    int rr = qd * 4 + r;
                    ST[(g2 * 16 + (rr ^ g2)) * 8 + (lm & 7)] = f2b(sres);
                }
            }
#pragma unroll
            for (int ks = 0; ks < 2; ++ks) {
                int g = ks * 4 + qd;               // [0,8)
                s16x8 af = *(const s16x8*)&ST[(g * 16 + (lm ^ g)) * 8];
#pragma unroll
                for (int n = 0; n < 4; ++n) {
                    s16x8 bf = *(const s16x8*)&WT[(g * 64 + ((n * 16 + lm) ^ g)) * 8];
                    oacc[n] = __builtin_amdgcn_mfma_f32_16x16x32_bf16(af, bf, oacc[n], 0, 0, 0);
                }
            }
        }
#pragma unroll
        for (int r = 0; r < 4; ++r) {
#pragma unroll
            for (int off = 1; off < 16; off <<= 1) L1[r] += __shfl_xor(L1[r], off);
            L1[r] = 1.f / fmaxf(L1[r], 1e-12f);
        }
#pragma unroll
        for (int n = 0; n < 4; ++n)
#pragma unroll
            for (int r = 0; r < 4; ++r)
                PoutH[(size_t)(pb + 16 * w + qd * 4 + r) * 64 + n * 16 + lm] =
                    f2b(oacc[n][r] * L1[r]);
    } else if (bid < 296) {
        // ================= dist6 role: bin ring search =================
        int v = (bid - 256) * 256 + t;             // 40*256 = 10240
        if (v >= NVc) return;
        int xi = coords[v * 4 + 1], yi = coords[v * 4 + 2];
        float x = (float)xi, y = (float)yi;
        int bx = xi >> 4; if (bx > NBX - 1) bx = NBX - 1;
        int by = yi >> 4; if (by > NBY - 1) by = NBY - 1;
        unsigned kk[6] = {~0u, ~0u, ~0u, ~0u, ~0u, ~0u};
        for (int r = 0; r < 32; ++r) {
            int x0 = bx - r, x1 = bx + r, y0 = by - r, y1 = by + r;
            for (int cy = y0; cy <= y1; ++cy) {
                if (cy < 0 || cy > NBY - 1) continue;
                int step = (cy == y0 || cy == y1) ? 1 : (x1 > x0 ? x1 - x0 : 1);
                for (int cx = x0; cx <= x1; cx += step) {
                    if (cx < 0 || cx > NBX - 1) continue;
                    int b = cy * NBX + cx;
                    int s0 = binStart[b], s1 = binStart[b + 1];
                    for (int s = s0; s < s1; ++s) {
                        float4 p = binPC[s];
                        float e1 = x - p.x, e2 = y - p.y;
                        float d2 = fmaf(e1, e1, fmaf(e2, e2, p.z));
                        unsigned tk = (__float_as_uint(d2) & 0xFFFFC000u) | __float_as_uint(p.w);
                        kk[5] = med3u(kk[4], kk[5], tk);
                        kk[4] = med3u(kk[3], kk[4], tk);
                        kk[3] = med3u(kk[2], kk[3], tk);
                        kk[2] = med3u(kk[1], kk[2], tk);
                        kk[1] = med3u(kk[0], kk[1], tk);
                        kk[0] = kk[0] < tk ? kk[0] : tk;
                    }
                }
            }
            if (kk[2] != ~0u) {
                float d3 = __uint_as_float(kk[2] & 0xFFFFC000u);
                if (256.f * (float)(r * r) > d3 * 1.004f + 1e-3f) break;
            }
        }
#pragma unroll
        for (int j2 = 0; j2 < 6; ++j2) dIdx6[v * 6 + j2] = (int)(kk[j2] & 16383u);
    } else {
        // ================= score5 role: MFMA top-4 per 1024-chunk =================
        int sb = bid - 296;                        // 0..2511
        int pb = (sb >> 4) * 64;                   // 157 pillar tiles
        int cb = (sb & 15) * 1024;                 // 16 chunks
        const u16* arow = pillarH + (size_t)(pb + 16 * w + lm) * 64 + qd * 8;
        s16x8 a0 = *(const s16x8*)arow;
        s16x8 a1 = *(const s16x8*)(arow + 32);
        int so[4], doff[4];
#pragma unroll
        for (int r = 0; r < 4; ++r) {
            int q = t + 256 * r;
            int row = q >> 3, g = q & 7;
            so[r] = row * 64 + g * 8;
            doff[r] = (((row >> 4) * 8 + g) * 16 + ((row & 15) ^ g)) * 8;
        }
        uint4 pre[4];
        const u16* src = pfeatH + (size_t)cb * 64;
#pragma unroll
        for (int r = 0; r < 4; ++r) pre[r] = *(const uint4*)(src + so[r]);
#pragma unroll
        for (int r = 0; r < 4; ++r) *(uint4*)&smem.bf[0][doff[r]] = pre[r];
        unsigned sk[4][4];
#pragma unroll
        for (int r = 0; r < 4; ++r)
#pragma unroll
            for (int j = 0; j < 4; ++j) sk[r][j] = 0u;
        for (int s = 0; s < 8; ++s) {
            __syncthreads();
            if (s < 7) {
                const u16* s2 = src + (size_t)(s + 1) * 128 * 64;
#pragma unroll
                for (int r = 0; r < 4; ++r) pre[r] = *(const uint4*)(s2 + so[r]);
            }
            const u16* B = &smem.bf[s & 1][0];
#pragma unroll
            for (int pt = 0; pt < 8; ++pt) {
                s16x8 b0 = *(const s16x8*)&B[(((pt * 8 + qd) * 16) + (lm ^ qd)) * 8];
                s16x8 b1 = *(const s16x8*)&B[(((pt * 8 + qd + 4) * 16) + (lm ^ (qd + 4))) * 8];
                f32x4 acc = {256.f, 256.f, 256.f, 256.f};
                acc = __builtin_amdgcn_mfma_f32_16x16x32_bf16(a0, b0, acc, 0, 0, 0);
                acc = __builtin_amdgcn_mfma_f32_16x16x32_bf16(a1, b1, acc, 0, 0, 0);
                unsigned idf = (unsigned)(1023 - (s * 128 + pt * 16 + lm));
#pragma unroll
                for (int r = 0; r < 4; ++r) {
                    unsigned key = (__float_as_uint(acc[r]) & 0xFFFFFC00u) | idf;
                    sk[r][3] = med3u(sk[r][2], sk[r][3], key);
                    sk[r][2] = med3u(sk[r][1], sk[r][2], key);
                    sk[r][1] = med3u(sk[r][0], sk[r][1], key);
                    sk[r][0] = sk[r][0] > key ? sk[r][0] : key;
                }
            }
            if (s < 7) {
#pragma unroll
                for (int r = 0; r < 4; ++r) *(uint4*)&smem.bf[(s + 1) & 1][doff[r]] = pre[r];
            }
        }
        __syncthreads();
        unsigned* mrg = (unsigned*)&smem.bf[0][0];
#pragma unroll
        for (int r = 0; r < 4; ++r) {
            int row = 16 * w + qd * 4 + r;
            *(uint4*)&mrg[(row * 16 + lm) * 4] =
                make_uint4(sk[r][0], sk[r][1], sk[r][2], sk[r][3]);
        }
        __syncthreads();
        if (t < 64) {
            int gpr = pb + t;
            unsigned m0 = 0u, m1 = 0u, m2 = 0u, m3 = 0u;
#pragma unroll 4
            for (int cc = 0; cc < 16; ++cc) {
                uint4 v = *(const uint4*)&mrg[(t * 16 + cc) * 4];
#pragma unroll
                for (int j = 0; j < 4; ++j) {
                    unsigned x = j == 0 ? v.x : (j == 1 ? v.y : (j == 2 ? v.z : v.w));
                    m3 = med3u(m2, m3, x);
                    m2 = med3u(m1, m2, x);
                    m1 = med3u(m0, m1, x);
                    m0 = m0 > x ? m0 : x;
                }
            }
            if (gpr < NVc) {
                int base = ((sb & 15) * NVc + gpr) * 4;
                sIdx[base + 0] = cb + 1023 - (int)(m0 & 1023u);
                sIdx[base + 1] = cb + 1023 - (int)(m1 & 1023u);
                sIdx[base + 2] = cb + 1023 - (int)(m2 & 1023u);
                sIdx[base + 3] = cb + 1023 - (int)(m3 & 1023u);
            }
        }
    }
}

// ---------------- fp64 re-rank: scores 64 candidates, dist 6 candidates ----------------
__global__ __launch_bounds__(256) void k_rerank(const float* __restrict__ pillar,
                                                const int* __restrict__ coords,
                                                const float* __restrict__ pfeat,
                                                const float* __restrict__ pcoord,
                                                const int* __restrict__ sIdx,
                                                const int* __restrict__ dIdx6,
                                                int* __restrict__ idx_f,
                                                int* __restrict__ idx_c) {
    int t = threadIdx.x;
    int wv = t >> 6, l = t & 63;
    int v = blockIdx.x * 4 + wv;
    int chunk = l >> 2, slot = l & 3;
    int ps = sIdx[(chunk * NVc + v) * 4 + slot];
    int pd = dIdx6[v * 6 + (l < 6 ? l : 0)];
    double s = 0.0;
#pragma unroll
    for (int i = 0; i < 16; ++i) {
        float4 a = *(const float4*)(pillar + v * 64 + 4 * i);
        float4 b = *(const float4*)(pfeat + ps * 64 + 4 * i);
        s += (double)a.x * (double)b.x + (double)a.y * (double)b.y
           + (double)a.z * (double)b.z + (double)a.w * (double)b.w;
    }
    float4 qc = *(const float4*)(pcoord + pd * 4);
    double db_ = (double)coords[v * 4 + 0] - (double)qc.x;
    double dx_ = (double)coords[v * 4 + 1] - (double)qc.y;
    double dy_ = (double)coords[v * 4 + 2] - (double)qc.z;
    double dz_ = (double)coords[v * 4 + 3] - (double)qc.w;
    double d2 = db_ * db_ + dx_ * dx_ + dy_ * dy_ + dz_ * dz_;
    double sv = s; int sx = ps;
    for (int k = 0; k < 3; ++k) {
        double bv = sv; int bi = sx;
#pragma unroll
        for (int off = 32; off >= 1; off >>= 1) {
            double ov = __shfl_xor(bv, off);
            int    oi = __shfl_xor(bi, off);
            if (ov > bv || (ov == bv && oi < bi)) { bv = ov; bi = oi; }
        }
        if (l == 0) idx_f[v * 3 + k] = bi;
        if (sx == bi) { sv = -INFINITY; sx = 0x7fffffff; }
    }
    double dv = d2; int dx2 = pd;
    for (int k = 0; k < 3; ++k) {
        double bv = dv; int bi = dx2;
#pragma unroll
        for (int off = 32; off >= 1; off >>= 1) {
            double ov = __shfl_xor(bv, off);
            int    oi = __shfl_xor(bi, off);
            if (ov < bv || (ov == bv && oi < bi)) { bv = ov; bi = oi; }
        }
        if (l == 0) idx_c[v * 3 + k] = bi;
        if (dx2 == bi) { dv = INFINITY; dx2 = 0x7fffffff; }
    }
}

// ---------------- MFMA projection: Q = PoutH @ Badapt^T ----------------
__global__ __launch_bounds__(256) void k_proj2(const u16* __restrict__ PoutH,
                                               const u16* __restrict__ badaptH,
                                               float* __restrict__ Q) {
    __shared__ u16 AD[12288];
    int t = threadIdx.x;
    int w = t >> 6, l = t & 63;
    int lm = l & 15, qd = l >> 4;
    int pb = blockIdx.x * 64;
#pragma unroll
    for (int r = 0; r < 6; ++r) {
        int q = t + 256 * r;
        int row = q >> 3, g = q & 7;
        uint4 v = *(const uint4*)(badaptH + (size_t)row * 64 + g * 8);
        *(uint4*)&AD[(((row >> 4) * 8 + g) * 16 + ((row & 15) ^ g)) * 8] = v;
    }
    const u16* arow = PoutH + (size_t)(pb + 16 * w + lm) * 64 + qd * 8;
    s16x8 a0 = *(const s16x8*)arow;
    s16x8 a1 = *(const s16x8*)(arow + 32);
    __syncthreads();
    f32x4 acc[12];
#pragma unroll
    for (int nt = 0; nt < 12; ++nt) {
        s16x8 b0 = *(const s16x8*)&AD[(((nt * 8 + qd) * 16) + (lm ^ qd)) * 8];
        s16x8 b1 = *(const s16x8*)&AD[(((nt * 8 + qd + 4) * 16) + (lm ^ (qd + 4))) * 8];
        f32x4 z = {0.f, 0.f, 0.f, 0.f};
        z = __builtin_amdgcn_mfma_f32_16x16x32_bf16(a0, b0, z, 0, 0, 0);
        z = __builtin_amdgcn_mfma_f32_16x16x32_bf16(a1, b1, z, 0, 0, 0);
        acc[nt] = z;
    }
#pragma unroll
    for (int nt = 0; nt < 12; ++nt)
#pragma unroll
        for (int r = 0; r < 4; ++r)
            Q[(size_t)(pb + 16 * w + qd * 4 + r) * 192 + nt * 16 + lm] = acc[nt][r];
}

// ---------------- gather-add + w logits + BN partial sums ----------------
__global__ __launch_bounds__(256) void k_gather(const float* __restrict__ Q,
                                                const int* __restrict__ idx_f,
                                                const int* __restrict__ idx_c,
                                                const float* __restrict__ pillar,
                                                const float* __restrict__ ww,
                                                float* __restrict__ f_pre,
                                                float* __restrict__ c_pre,
                                                float* __restrict__ w_pre,
                                                float* __restrict__ stats) {
    __shared__ float red[4][4][64];
    __shared__ float redw[4][4];
    int t = threadIdx.x;
    int wv = t >> 6, l = t & 63;
    int base = blockIdx.x * 40;
    int vend = base + 40;
    float fs = 0, fq = 0, cs = 0, cq = 0, ws0 = 0, wq0 = 0, ws1 = 0, wq1 = 0;
    float w0l = ww[l], w1l = ww[64 + l];
    for (int v = base + wv; v < vend; v += 4) {
        int if0 = idx_f[v * 3], if1 = idx_f[v * 3 + 1], if2 = idx_f[v * 3 + 2];
        float f = Q[if0 * 192 + l] + Q[if1 * 192 + 64 + l] + Q[if2 * 192 + 128 + l];
        f_pre[v * 64 + l] = f; fs += f; fq += f * f;
        int ic0 = idx_c[v * 3], ic1 = idx_c[v * 3 + 1], ic2 = idx_c[v * 3 + 2];
        float c = Q[ic0 * 192 + l] + Q[ic1 * 192 + 64 + l] + Q[ic2 * 192 + 128 + l];
        c_pre[v * 64 + l] = c; cs += c; cq += c * c;
        float pv = pillar[v * 64 + l];
        float a0 = pv * w0l, a1 = pv * w1l;
#pragma unroll
        for (int off = 32; off >= 1; off >>= 1) {
            a0 += __shfl_xor(a0, off);
            a1 += __shfl_xor(a1, off);
        }
        if (l == 0) { w_pre[v * 2] = a0; w_pre[v * 2 + 1] = a1; }
        ws0 += a0; wq0 += a0 * a0; ws1 += a1; wq1 += a1 * a1;
    }
    red[0][wv][l] = fs; red[1][wv][l] = fq; red[2][wv][l] = cs; red[3][wv][l] = cq;
    if (l == 0) { redw[wv][0] = ws0; redw[wv][1] = wq0; redw[wv][2] = ws1; redw[wv][3] = wq1; }
    __syncthreads();
    if (wv == 0) {
#pragma unroll
        for (int q = 0; q < 4; ++q) {
            float sum = red[q][0][l] + red[q][1][l] + red[q][2][l] + red[q][3][l];
            atomicAdd(&stats[q * 64 + l], sum);
        }
        if (l < 4) {
            float sum = redw[0][l] + redw[1][l] + redw[2][l] + redw[3][l];
            atomicAdd(&stats[256 + l], sum);
        }
    }
}

// ---------------- full-canvas write with inline BN/softmax aug ----------------
__global__ __launch_bounds__(256) void k_out2(const int* __restrict__ cellMap,
                                              const float* __restrict__ pillar,
                                              const float* __restrict__ f_pre,
                                              const float* __restrict__ c_pre,
                                              const float* __restrict__ w_pre,
                                              const float* __restrict__ stats,
                                              const float* __restrict__ g1,
                                              const float* __restrict__ b1,
                                              const float* __restrict__ g2,
                                              const float* __restrict__ b2,
                                              float* __restrict__ out) {
    int c4 = (blockIdx.x * 256 + threadIdx.x) * 4;
    if (c4 >= CELLS) return;
    int4 cm = *(const int4*)(cellMap + c4);
    const float invn = 1.0f / (float)NVc;
    // per-pillar softmax weights (computed once per thread; used by aug rows)
    float mw0 = stats[256] * invn, vw0 = stats[257] * invn - mw0 * mw0;
    float mw1 = stats[258] * invn, vw1 = stats[259] * invn - mw1 * mw1;
    float rw0 = rsqrtf(vw0 + 1e-3f), rw1 = rsqrtf(vw1 + 1e-3f);
    float g20 = g2[0], b20 = b2[0], g21 = g2[1], b21 = b2[1];
    float w0c[4], w1c[4];
    int cms[4] = {cm.x, cm.y, cm.z, cm.w};
#pragma unroll
    for (int k = 0; k < 4; ++k) {
        int c = cms[k];
        if (c >= 0) {
            float z0 = (w_pre[c * 2] - mw0) * rw0 * g20 + b20;
            float z1 = (w_pre[c * 2 + 1] - mw1) * rw1 * g21 + b21;
            float mz = fmaxf(z0, z1);
            float e0 = __expf(z0 - mz), e1 = __expf(z1 - mz);
            float wd = 1.f / (e0 + e1);
            w0c[k] = e0 * wd; w1c[k] = e1 * wd;
        } else { w0c[k] = 0.f; w1c[k] = 0.f; }
    }
    int f0 = blockIdx.y * 33;
    int f1 = f0 + 33; if (f1 > 131) f1 = 131;
    for (int f = f0; f < f1; ++f) {
        float4 val;
        if (f < 64) {
            val.x = cm.x >= 0 ? pillar[cm.x * 64 + f] : 0.f;
            val.y = cm.y >= 0 ? pillar[cm.y * 64 + f] : 0.f;
            val.z = cm.z >= 0 ? pillar[cm.z * 64 + f] : 0.f;
            val.w = cm.w >= 0 ? pillar[cm.w * 64 + f] : 0.f;
        } else if (f < 128) {
            int fa = f - 64;
            float mf = stats[fa] * invn;
            float rf = rsqrtf(stats[64 + fa] * invn - mf * mf + 1e-3f);
            float mc = stats[128 + fa] * invn;
            float rc = rsqrtf(stats[192 + fa] * invn - mc * mc + 1e-3f);
            float gg = g1[fa], bb = b1[fa];
            float* vv = (float*)&val;
#pragma unroll
            for (int k = 0; k < 4; ++k) {
                int c = cms[k];
                if (c >= 0) {
                    float fv = fmaxf((f_pre[c * 64 + fa] - mf) * rf * gg + bb, 0.f);
                    float cv = fmaxf((c_pre[c * 64 + fa] - mc) * rc * gg + bb, 0.f);
                    vv[k] = w0c[k] * fv + w1c[k] * cv;
                } else vv[k] = 0.f;
            }
        } else if (f == 128) {
            val.x = cm.x >= 0 ? (float)((c4 + 0) / NXc) : 0.f;
            val.y = cm.y >= 0 ? (float)((c4 + 1) / NXc) : 0.f;
            val.z = cm.z >= 0 ? (float)((c4 + 2) / NXc) : 0.f;
            val.w = cm.w >= 0 ? (float)((c4 + 3) / NXc) : 0.f;
        } else if (f == 129) {
            val = make_float4(0.f, 0.f, 0.f, 0.f);
        } else {
            val.x = cm.x >= 0 ? (float)((c4 + 0) % NXc) : 0.f;
            val.y = cm.y >= 0 ? (float)((c4 + 1) % NXc) : 0.f;
            val.z = cm.z >= 0 ? (float)((c4 + 2) % NXc) : 0.f;
            val.w = cm.w >= 0 ? (float)((c4 + 3) % NXc) : 0.f;
        }
        *(float4*)(out + (size_t)f * CELLS + c4) = val;
    }
}

extern "C" void kernel_launch(void* const* d_in, const int* in_sizes, int n_in,
                              void* d_out, int out_size, void* d_ws, size_t ws_size,
                              hipStream_t stream) {
    const float* pillar = (const float*)d_in[0];
    const int*   coords = (const int*)d_in[1];
    const float* pfeat  = (const float*)d_in[2];
    const float* pcoord = (const float*)d_in[3];
    const float* adapt  = (const float*)d_in[4];
    const float* bn1g   = (const float*)d_in[5];
    const float* bn1b   = (const float*)d_in[6];
    const float* ww     = (const float*)d_in[7];
    const float* bn2g   = (const float*)d_in[8];
    const float* bn2b   = (const float*)d_in[9];
    const float* memw   = (const float*)d_in[10];
    float* out = (float*)d_out;
    float* ws  = (float*)d_ws;
    // workspace layout (float offsets)
    u16*   PoutH = (u16*)(ws + 0);                 // 1,048,576 u16
    float* Q     = ws + 1048576;                   // 3,145,728 fl
    int*   sIdx  = (int*)(ws + 4194304);           // 640,000
    int*   binStart  = (int*)(ws + 4834304);       // 838
    int*   dIdx6     = (int*)(ws + 4836824);       // 60,000
    float4* binPC    = (float4*)(ws + 4896824);    // 65,536 fl
    u16*   memwH   = (u16*)(ws + 4970000);         // 65,536 u16
    u16*   memwTH  = (u16*)(ws + 5002768);         // 65,536 u16
    u16*   badaptH = (u16*)(ws + 5035536);         // 12,288 u16
    int*   idxf  = (int*)(ws + 5474304);           // 30,000
    int*   idxc  = (int*)(ws + 5504304);           // 30,000
    float* fpre  = ws + 5534304;                   // 640,000
    float* cpre  = ws + 6174304;                   // 640,000
    float* wpre  = ws + 6814304;                   // 20,000
    float* stats = ws + 6834304;                   // 260
    int*   cellMap = (int*)(ws + 6840000);         // 214,272 ints
    // bf16 feature buffers overlap fpre/cpre (dead until k_gather writes them)
    u16* pillarH = (u16*)(ws + 5534304);           // 643,072 u16
    u16* pfeatH  = pillarH + (size_t)NVPAD * 64;   // 1,048,576 u16

    k_init  <<<7168, 256, 0, stream>>>(pillar, pfeat, memw, adapt, stats, cellMap,
                                       pillarH, pfeatH, memwH, memwTH, badaptH);
    k_pre   <<<1, 1024, 0, stream>>>(pcoord, coords, binStart, binPC, cellMap);
    k_fused <<<2808, 256, 0, stream>>>(pillarH, pfeatH, memwH, memwTH, coords,
                                       binPC, binStart, PoutH, dIdx6, sIdx);
    k_rerank<<<2500, 256, 0, stream>>>(pillar, coords, pfeat, pcoord, sIdx, dIdx6, idxf, idxc);
    k_proj2 <<<256, 256, 0, stream>>>(PoutH, badaptH, Q);
    k_gather<<<250, 256, 0, stream>>>(Q, idxf, idxc, pillar, ww, fpre, cpre, wpre, stats);
    k_out2  <<<dim3(210, 4), 256, 0, stream>>>(cellMap, pillar, fpre, cpre, wpre, stats,
                                               bn1g, bn1b, bn2g, bn2b, out);
}

// Round 9
// 323.416 us; speedup vs baseline: 4.1732x; 1.0464x over previous
//
#include <hip/hip_runtime.h>
#include <math.h>

#define NXc 432
#define NYc 496
#define NVc 10000
#define NPc 16384
#define CELLS (NXc*NYc)          // 214272
#define SHRINKc 0.0025f
#define NVPAD 10048              // 157*64
#define NBX 27
#define NBY 31
#define NBIN (NBX*NBY)           // 837

typedef unsigned short u16;
typedef __attribute__((ext_vector_type(8))) short s16x8;   // 8 bf16
typedef __attribute__((ext_vector_type(4))) float f32x4;

__device__ __forceinline__ unsigned med3u(unsigned a, unsigned b, unsigned c) {
    unsigned d;
    asm("v_med3_u32 %0, %1, %2, %3" : "=v"(d) : "v"(a), "v"(b), "v"(c));
    return d;
}

// ---------------- fp32 -> bf16 (RNE) ----------------
__device__ __forceinline__ u16 f2b(float x) {
    unsigned u = __float_as_uint(x);
    unsigned r = (u + 0x7fffu + ((u >> 16) & 1u)) >> 16;
    return (u16)r;
}

// ---------------- init: stats zero + cellMap=-1 + all bf16 casts ----------------
__global__ __launch_bounds__(256) void k_init(const float* __restrict__ pillar,
                                              const float* __restrict__ pfeat,
                                              const float* __restrict__ memw,
                                              const float* __restrict__ adapt,
                                              float* __restrict__ stats,
                                              int* __restrict__ cellMap,
                                              u16* __restrict__ pillarH,
                                              u16* __restrict__ pfeatH,
                                              u16* __restrict__ memwH,
                                              u16* __restrict__ memwTH,
                                              u16* __restrict__ badaptH) {
    int gid = blockIdx.x * 256 + threadIdx.x;      // 7168*256 = 1835008 exactly
    if (gid < CELLS) cellMap[gid] = -1;
    if (gid < 260) stats[gid] = 0.f;
    const int N1 = NVPAD * 64;                     // 643072
    const int N2 = N1 + NPc * 64;                  // 1691648
    const int N3 = N2 + 65536;                     // 1757184
    const int N4 = N3 + 65536;                     // 1822720  (+12288 = 1835008)
    if (gid < N1) {
        int v = gid >> 6;
        pillarH[gid] = f2b(v < NVc ? pillar[gid] : 0.f);
    } else if (gid < N2) {
        pfeatH[gid - N1] = f2b(pfeat[gid - N1]);
    } else if (gid < N3) {
        memwH[gid - N2] = f2b(memw[gid - N2]);
    } else if (gid < N4) {
        int i = gid - N3;
        int d = i >> 10, j = i & 1023;
        memwTH[i] = f2b(memw[j * 64 + d]);         // memwT[d][j]
    } else {
        int i = gid - N4;                          // 0..12287: Badapt[c][d]
        int c = i >> 6, d = i & 63;
        badaptH[i] = f2b(adapt[(c & 63) * 192 + (c >> 6) * 64 + d]);
    }
}

// ---------------- single-block: histogram + scan + bin fill ----------------
__global__ __launch_bounds__(1024) void k_pre(const float* __restrict__ pcoord,
                                              int* __restrict__ binStart,
                                              float4* __restrict__ binPC) {
    __shared__ int hcnt[1024];
    __shared__ int sc[1024];
    __shared__ int cur[1024];
    int t = threadIdx.x;
    hcnt[t] = 0;
    __syncthreads();
    for (int j = t; j < NPc; j += 1024) {
        float qx = pcoord[j * 4 + 1], qy = pcoord[j * 4 + 2];
        int bx = (int)(qx * 0.0625f); if (bx > NBX - 1) bx = NBX - 1;
        int by = (int)(qy * 0.0625f); if (by > NBY - 1) by = NBY - 1;
        atomicAdd(&hcnt[by * NBX + bx], 1);
    }
    __syncthreads();
    int vcount = (t < NBIN) ? hcnt[t] : 0;
    sc[t] = vcount;
    __syncthreads();
    for (int off = 1; off < 1024; off <<= 1) {
        int add = (t >= off) ? sc[t - off] : 0;
        __syncthreads();
        sc[t] += add;
        __syncthreads();
    }
    int excl = sc[t] - vcount;
    cur[t] = excl;
    if (t <= NBIN) binStart[t] = excl;
    __syncthreads();
    for (int j = t; j < NPc; j += 1024) {
        float qx = pcoord[j * 4 + 1], qy = pcoord[j * 4 + 2], qz = pcoord[j * 4 + 3];
        int bx = (int)(qx * 0.0625f); if (bx > NBX - 1) bx = NBX - 1;
        int by = (int)(qy * 0.0625f); if (by > NBY - 1) by = NBY - 1;
        int slot = atomicAdd(&cur[by * NBX + bx], 1);
        binPC[slot] = make_float4(qx, qy, qz * qz, __uint_as_float((unsigned)j));
    }
}

// ---------------- FUSED: mem2 (bid<256) | dist6 (256..295) | score (296..2807) ----------------
// union = 24 KB -> 6 blocks/CU (LDS-bound); score role single-buffered.
__global__ __launch_bounds__(256) void k_fused(const u16* __restrict__ pillarH,
                                               const u16* __restrict__ pfeatH,
                                               const u16* __restrict__ memwH,
                                               const u16* __restrict__ memwTH,
                                               const int* __restrict__ coords,
                                               const float4* __restrict__ binPC,
                                               const int* __restrict__ binStart,
                                               u16* __restrict__ PoutH,
                                               int* __restrict__ dIdx6,
                                               int* __restrict__ sIdx) {
    __shared__ union {
        u16 bf[8192];                              // score role: 16 KB single buffer
        struct { u16 wh[4096]; u16 wt[4096]; u16 st[4][1024]; } m;   // mem role: 24 KB
    } smem;
    int bid = blockIdx.x;
    int t = threadIdx.x;
    int w = t >> 6, l = t & 63;
    int lm = l & 15, qd = l >> 4;

    if (bid < 256) {
        // ================= mem2 role: streaming memory_lookup, 64-row tiles =================
        int pb = bid * 64;
        u16* WH = smem.m.wh;
        u16* WT = smem.m.wt;
        u16* ST = &smem.m.st[w][0];
        const u16* arow = pfeatH + (size_t)(pb + 16 * w + lm) * 64 + qd * 8;
        s16x8 a0 = *(const s16x8*)arow;
        s16x8 a1 = *(const s16x8*)(arow + 32);
        float mM[4] = {-INFINITY, -INFINITY, -INFINITY, -INFINITY};
        float Zs[4] = {0.f, 0.f, 0.f, 0.f};
        for (int tile = 0; tile < 16; ++tile) {
            __syncthreads();
#pragma unroll
            for (int r = 0; r < 2; ++r) {
                int q = t + 256 * r;               // 512 granules
                int row = q >> 3, g = q & 7;
                uint4 v = *(const uint4*)(memwH + (size_t)(tile * 64 + row) * 64 + g * 8);
                *(uint4*)&WH[(((row >> 4) * 8 + g) * 16 + ((row & 15) ^ g)) * 8] = v;
            }
            __syncthreads();
            f32x4 acc[4];
#pragma unroll
            for (int st = 0; st < 4; ++st) {
                s16x8 b0 = *(const s16x8*)&WH[((st * 8 + qd) * 16 + (lm ^ qd)) * 8];
                s16x8 b1 = *(const s16x8*)&WH[((st * 8 + qd + 4) * 16 + (lm ^ (qd + 4))) * 8];
                f32x4 z = {0.f, 0.f, 0.f, 0.f};
                z = __builtin_amdgcn_mfma_f32_16x16x32_bf16(a0, b0, z, 0, 0, 0);
                z = __builtin_amdgcn_mfma_f32_16x16x32_bf16(a1, b1, z, 0, 0, 0);
                acc[st] = z;
            }
#pragma unroll
            for (int r = 0; r < 4; ++r) {
                float tmax = acc[0][r];
#pragma unroll
                for (int st = 1; st < 4; ++st) tmax = fmaxf(tmax, acc[st][r]);
                float mn = fmaxf(mM[r], tmax);
                float zacc = Zs[r] * __expf(mM[r] - mn);
#pragma unroll
                for (int st = 0; st < 4; ++st) zacc += __expf(acc[st][r] - mn);
                mM[r] = mn; Zs[r] = zacc;
            }
        }
#pragma unroll
        for (int r = 0; r < 4; ++r) {
#pragma unroll
            for (int off = 1; off < 16; off <<= 1) {
                float om = __shfl_xor(mM[r], off);
                float oz = __shfl_xor(Zs[r], off);
                float mn = fmaxf(mM[r], om);
                Zs[r] = Zs[r] * __expf(mM[r] - mn) + oz * __expf(om - mn);
                mM[r] = mn;
            }
        }
        float invZ[4], L1[4] = {0.f, 0.f, 0.f, 0.f};
#pragma unroll
        for (int r = 0; r < 4; ++r) invZ[r] = 1.f / Zs[r];
        f32x4 oacc[4];
#pragma unroll
        for (int n = 0; n < 4; ++n) oacc[n] = (f32x4){0.f, 0.f, 0.f, 0.f};
        for (int tile = 0; tile < 16; ++tile) {
            __syncthreads();
#pragma unroll
            for (int r = 0; r < 2; ++r) {
                int q = t + 256 * r;
                int row = q >> 3, g = q & 7;
                uint4 v = *(const uint4*)(memwH + (size_t)(tile * 64 + row) * 64 + g * 8);
                *(uint4*)&WH[(((row >> 4) * 8 + g) * 16 + ((row & 15) ^ g)) * 8] = v;
            }
#pragma unroll
            for (int r = 0; r < 2; ++r) {
                int q = t + 256 * r;
                int row = q >> 3, g = q & 7;   // row = n in [0,64)
                uint4 v = *(const uint4*)(memwTH + (size_t)row * 1024 + tile * 64 + g * 8);
                *(uint4*)&WT[(g * 64 + (row ^ g)) * 8] = v;
            }
            __syncthreads();
#pragma unroll
            for (int st = 0; st < 4; ++st) {
                s16x8 b0 = *(const s16x8*)&WH[((st * 8 + qd) * 16 + (lm ^ qd)) * 8];
                s16x8 b1 = *(const s16x8*)&WH[((st * 8 + qd + 4) * 16 + (lm ^ (qd + 4))) * 8];
                f32x4 z = {0.f, 0.f, 0.f, 0.f};
                z = __builtin_amdgcn_mfma_f32_16x16x32_bf16(a0, b0, z, 0, 0, 0);
                z = __builtin_amdgcn_mfma_f32_16x16x32_bf16(a1, b1, z, 0, 0, 0);
                int g2 = st * 2 + (lm >> 3);       // [0,8)
#pragma unroll
                for (int r = 0; r < 4; ++r) {
                    float e = __expf(z[r] - mM[r]);
                    float a = e * invZ[r];
                    float tt = a - SHRINKc;
                    float sres = fmaxf(tt, 0.f) * a / (fabsf(tt) + 1e-12f);
                    L1[r] += sres;
                    int rr = qd * 4 + r;
                    ST[(g2 * 16 + (rr ^ g2)) * 8 + (lm & 7)] = f2b(sres);
                }
            }
#pragma unroll
            for (int ks = 0; ks < 2; ++ks) {
                int g = ks * 4 + qd;               // [0,8)
                s16x8 af = *(const s16x8*)&ST[(g * 16 + (lm ^ g)) * 8];
#pragma unroll
                for (int n = 0; n < 4; ++n) {
                    s16x8 bf = *(const s16x8*)&WT[(g * 64 + ((n * 16 + lm) ^ g)) * 8];
                    oacc[n] = __builtin_amdgcn_mfma_f32_16x16x32_bf16(af, bf, oacc[n], 0, 0, 0);
                }
            }
        }
#pragma unroll
        for (int r = 0; r < 4; ++r) {
#pragma unroll
            for (int off = 1; off < 16; off <<= 1) L1[r] += __shfl_xor(L1[r], off);
            L1[r] = 1.f / fmaxf(L1[r], 1e-12f);
        }
#pragma unroll
        for (int n = 0; n < 4; ++n)
#pragma unroll
            for (int r = 0; r < 4; ++r)
                PoutH[(size_t)(pb + 16 * w + qd * 4 + r) * 64 + n * 16 + lm] =
                    f2b(oacc[n][r] * L1[r]);
    } else if (bid < 296) {
        // ================= dist6 role: bin ring search =================
        int v = (bid - 256) * 256 + t;             // 40*256 = 10240
        if (v >= NVc) return;
        int xi = coords[v * 4 + 1], yi = coords[v * 4 + 2];
        float x = (float)xi, y = (float)yi;
        int bx = xi >> 4; if (bx > NBX - 1) bx = NBX - 1;
        int by = yi >> 4; if (by > NBY - 1) by = NBY - 1;
        unsigned kk[6] = {~0u, ~0u, ~0u, ~0u, ~0u, ~0u};
        for (int r = 0; r < 32; ++r) {
            int x0 = bx - r, x1 = bx + r, y0 = by - r, y1 = by + r;
            for (int cy = y0; cy <= y1; ++cy) {
                if (cy < 0 || cy > NBY - 1) continue;
                int step = (cy == y0 || cy == y1) ? 1 : (x1 > x0 ? x1 - x0 : 1);
                for (int cx = x0; cx <= x1; cx += step) {
                    if (cx < 0 || cx > NBX - 1) continue;
                    int b = cy * NBX + cx;
                    int s0 = binStart[b], s1 = binStart[b + 1];
                    for (int s = s0; s < s1; ++s) {
                        float4 p = binPC[s];
                        float e1 = x - p.x, e2 = y - p.y;
                        float d2 = fmaf(e1, e1, fmaf(e2, e2, p.z));
                        unsigned tk = (__float_as_uint(d2) & 0xFFFFC000u) | __float_as_uint(p.w);
                        kk[5] = med3u(kk[4], kk[5], tk);
                        kk[4] = med3u(kk[3], kk[4], tk);
                        kk[3] = med3u(kk[2], kk[3], tk);
                        kk[2] = med3u(kk[1], kk[2], tk);
                        kk[1] = med3u(kk[0], kk[1], tk);
                        kk[0] = kk[0] < tk ? kk[0] : tk;
                    }
                }
            }
            if (kk[2] != ~0u) {
                float d3 = __uint_as_float(kk[2] & 0xFFFFC000u);
                if (256.f * (float)(r * r) > d3 * 1.004f + 1e-3f) break;
            }
        }
#pragma unroll
        for (int j2 = 0; j2 < 6; ++j2) dIdx6[v * 6 + j2] = (int)(kk[j2] & 16383u);
    } else {
        // ================= score role: MFMA top-4 per 1024-chunk, single buffer =================
        int sb = bid - 296;                        // 0..2511
        int pb = (sb >> 4) * 64;                   // 157 pillar tiles
        int cb = (sb & 15) * 1024;                 // 16 chunks
        const u16* arow = pillarH + (size_t)(pb + 16 * w + lm) * 64 + qd * 8;
        s16x8 a0 = *(const s16x8*)arow;
        s16x8 a1 = *(const s16x8*)(arow + 32);
        int so[4], doff[4];
#pragma unroll
        for (int r = 0; r < 4; ++r) {
            int q = t + 256 * r;
            int row = q >> 3, g = q & 7;
            so[r] = row * 64 + g * 8;
            doff[r] = (((row >> 4) * 8 + g) * 16 + ((row & 15) ^ g)) * 8;
        }
        const u16* src = pfeatH + (size_t)cb * 64;
        unsigned sk[4][4];
#pragma unroll
        for (int r = 0; r < 4; ++r)
#pragma unroll
            for (int j = 0; j < 4; ++j) sk[r][j] = 0u;
        for (int s = 0; s < 8; ++s) {
            const u16* s2 = src + (size_t)s * 128 * 64;
#pragma unroll
            for (int r = 0; r < 4; ++r)
                *(uint4*)&smem.bf[doff[r]] = *(const uint4*)(s2 + so[r]);
            __syncthreads();
#pragma unroll
            for (int pt = 0; pt < 8; ++pt) {
                s16x8 b0 = *(const s16x8*)&smem.bf[(((pt * 8 + qd) * 16) + (lm ^ qd)) * 8];
                s16x8 b1 = *(const s16x8*)&smem.bf[(((pt * 8 + qd + 4) * 16) + (lm ^ (qd + 4))) * 8];
                f32x4 acc = {256.f, 256.f, 256.f, 256.f};
                acc = __builtin_amdgcn_mfma_f32_16x16x32_bf16(a0, b0, acc, 0, 0, 0);
                acc = __builtin_amdgcn_mfma_f32_16x16x32_bf16(a1, b1, acc, 0, 0, 0);
                unsigned idf = (unsigned)(1023 - (s * 128 + pt * 16 + lm));
#pragma unroll
                for (int r = 0; r < 4; ++r) {
                    unsigned key = (__float_as_uint(acc[r]) & 0xFFFFFC00u) | idf;
                    sk[r][3] = med3u(sk[r][2], sk[r][3], key);
                    sk[r][2] = med3u(sk[r][1], sk[r][2], key);
                    sk[r][1] = med3u(sk[r][0], sk[r][1], key);
                    sk[r][0] = sk[r][0] > key ? sk[r][0] : key;
                }
            }
            __syncthreads();
        }
        unsigned* mrg = (unsigned*)&smem.bf[0];
#pragma unroll
        for (int r = 0; r < 4; ++r) {
            int row = 16 * w + qd * 4 + r;
            *(uint4*)&mrg[(row * 16 + lm) * 4] =
                make_uint4(sk[r][0], sk[r][1], sk[r][2], sk[r][3]);
        }
        __syncthreads();
        if (t < 64) {
            int gpr = pb + t;
            unsigned m0 = 0u, m1 = 0u, m2 = 0u, m3 = 0u;
#pragma unroll 4
            for (int cc = 0; cc < 16; ++cc) {
                uint4 v = *(const uint4*)&mrg[(t * 16 + cc) * 4];
#pragma unroll
                for (int j = 0; j < 4; ++j) {
                    unsigned x = j == 0 ? v.x : (j == 1 ? v.y : (j == 2 ? v.z : v.w));
                    m3 = med3u(m2, m3, x);
                    m2 = med3u(m1, m2, x);
                    m1 = med3u(m0, m1, x);
                    m0 = m0 > x ? m0 : x;
                }
            }
            if (gpr < NVc) {
                int base = ((sb & 15) * NVc + gpr) * 4;
                sIdx[base + 0] = cb + 1023 - (int)(m0 & 1023u);
                sIdx[base + 1] = cb + 1023 - (int)(m1 & 1023u);
                sIdx[base + 2] = cb + 1023 - (int)(m2 & 1023u);
                sIdx[base + 3] = cb + 1023 - (int)(m3 & 1023u);
            }
        }
    }
}

// ---------------- FUSED-2: proj2 (bid<256) | fp64 rerank (256..2755) ----------------
__global__ __launch_bounds__(256) void k_fused2(const u16* __restrict__ PoutH,
                                                const u16* __restrict__ badaptH,
                                                const float* __restrict__ pillar,
                                                const int* __restrict__ coords,
                                                const float* __restrict__ pfeat,
                                                const float* __restrict__ pcoord,
                                                const int* __restrict__ sIdx,
                                                const int* __restrict__ dIdx6,
                                                float* __restrict__ Q,
                                                int* __restrict__ idx_f,
                                                int* __restrict__ idx_c) {
    __shared__ u16 AD[12288];
    int bid = blockIdx.x;
    int t = threadIdx.x;
    if (bid < 256) {
        // ================= proj2 role: Q = PoutH @ Badapt^T =================
        int w = t >> 6, l = t & 63;
        int lm = l & 15, qd = l >> 4;
        int pb = bid * 64;
#pragma unroll
        for (int r = 0; r < 6; ++r) {
            int q = t + 256 * r;
            int row = q >> 3, g = q & 7;
            uint4 v = *(const uint4*)(badaptH + (size_t)row * 64 + g * 8);
            *(uint4*)&AD[(((row >> 4) * 8 + g) * 16 + ((row & 15) ^ g)) * 8] = v;
        }
        const u16* arow = PoutH + (size_t)(pb + 16 * w + lm) * 64 + qd * 8;
        s16x8 a0 = *(const s16x8*)arow;
        s16x8 a1 = *(const s16x8*)(arow + 32);
        __syncthreads();
        f32x4 acc[12];
#pragma unroll
        for (int nt = 0; nt < 12; ++nt) {
            s16x8 b0 = *(const s16x8*)&AD[(((nt * 8 + qd) * 16) + (lm ^ qd)) * 8];
            s16x8 b1 = *(const s16x8*)&AD[(((nt * 8 + qd + 4) * 16) + (lm ^ (qd + 4))) * 8];
            f32x4 z = {0.f, 0.f, 0.f, 0.f};
            z = __builtin_amdgcn_mfma_f32_16x16x32_bf16(a0, b0, z, 0, 0, 0);
            z = __builtin_amdgcn_mfma_f32_16x16x32_bf16(a1, b1, z, 0, 0, 0);
            acc[nt] = z;
        }
#pragma unroll
        for (int nt = 0; nt < 12; ++nt)
#pragma unroll
            for (int r = 0; r < 4; ++r)
                Q[(size_t)(pb + 16 * w + qd * 4 + r) * 192 + nt * 16 + lm] = acc[nt][r];
    } else {
        // ================= rerank role: fp64 exact top-3 =================
        int wv = t >> 6, l = t & 63;
        int v = (bid - 256) * 4 + wv;
        int chunk = l >> 2, slot = l & 3;
        int ps = sIdx[(chunk * NVc + v) * 4 + slot];
        int pd = dIdx6[v * 6 + (l < 6 ? l : 0)];
        double s = 0.0;
#pragma unroll
        for (int i = 0; i < 16; ++i) {
            float4 a = *(const float4*)(pillar + v * 64 + 4 * i);
            float4 b = *(const float4*)(pfeat + ps * 64 + 4 * i);
            s += (double)a.x * (double)b.x + (double)a.y * (double)b.y
               + (double)a.z * (double)b.z + (double)a.w * (double)b.w;
        }
        float4 qc = *(const float4*)(pcoord + pd * 4);
        double db_ = (double)coords[v * 4 + 0] - (double)qc.x;
        double dx_ = (double)coords[v * 4 + 1] - (double)qc.y;
        double dy_ = (double)coords[v * 4 + 2] - (double)qc.z;
        double dz_ = (double)coords[v * 4 + 3] - (double)qc.w;
        double d2 = db_ * db_ + dx_ * dx_ + dy_ * dy_ + dz_ * dz_;
        double sv = s; int sx = ps;
        for (int k = 0; k < 3; ++k) {
            double bv = sv; int bi = sx;
#pragma unroll
            for (int off = 32; off >= 1; off >>= 1) {
                double ov = __shfl_xor(bv, off);
                int    oi = __shfl_xor(bi, off);
                if (ov > bv || (ov == bv && oi < bi)) { bv = ov; bi = oi; }
            }
            if (l == 0) idx_f[v * 3 + k] = bi;
            if (sx == bi) { sv = -INFINITY; sx = 0x7fffffff; }
        }
        double dv = d2; int dx2 = pd;
        for (int k = 0; k < 3; ++k) {
            double bv = dv; int bi = dx2;
#pragma unroll
            for (int off = 32; off >= 1; off >>= 1) {
                double ov = __shfl_xor(bv, off);
                int    oi = __shfl_xor(bi, off);
                if (ov < bv || (ov == bv && oi < bi)) { bv = ov; bi = oi; }
            }
            if (l == 0) idx_c[v * 3 + k] = bi;
            if (dx2 == bi) { dv = INFINITY; dx2 = 0x7fffffff; }
        }
    }
}

// ---------------- gather-add + w logits + BN partial sums + cellMap scatter ----------------
__global__ __launch_bounds__(256) void k_gather(const float* __restrict__ Q,
                                                const int* __restrict__ idx_f,
                                                const int* __restrict__ idx_c,
                                                const float* __restrict__ pillar,
                                                const int* __restrict__ coords,
                                                const float* __restrict__ ww,
                                                float* __restrict__ f_pre,
                                                float* __restrict__ c_pre,
                                                float* __restrict__ w_pre,
                                                float* __restrict__ stats,
                                                int* __restrict__ cellMap) {
    __shared__ float red[4][4][64];
    __shared__ float redw[4][4];
    int t = threadIdx.x;
    int wv = t >> 6, l = t & 63;
    int base = blockIdx.x * 40;
    int vend = base + 40;
    if (t < 40) {
        int v = base + t;
        int cell = coords[v * 4 + 1] + coords[v * 4 + 2] * NXc + coords[v * 4 + 3];
        cellMap[cell] = v;
    }
    float fs = 0, fq = 0, cs = 0, cq = 0, ws0 = 0, wq0 = 0, ws1 = 0, wq1 = 0;
    float w0l = ww[l], w1l = ww[64 + l];
    for (int v = base + wv; v < vend; v += 4) {
        int if0 = idx_f[v * 3], if1 = idx_f[v * 3 + 1], if2 = idx_f[v * 3 + 2];
        float f = Q[if0 * 192 + l] + Q[if1 * 192 + 64 + l] + Q[if2 * 192 + 128 + l];
        f_pre[v * 64 + l] = f; fs += f; fq += f * f;
        int ic0 = idx_c[v * 3], ic1 = idx_c[v * 3 + 1], ic2 = idx_c[v * 3 + 2];
        float c = Q[ic0 * 192 + l] + Q[ic1 * 192 + 64 + l] + Q[ic2 * 192 + 128 + l];
        c_pre[v * 64 + l] = c; cs += c; cq += c * c;
        float pv = pillar[v * 64 + l];
        float a0 = pv * w0l, a1 = pv * w1l;
#pragma unroll
        for (int off = 32; off >= 1; off >>= 1) {
            a0 += __shfl_xor(a0, off);
            a1 += __shfl_xor(a1, off);
        }
        if (l == 0) { w_pre[v * 2] = a0; w_pre[v * 2 + 1] = a1; }
        ws0 += a0; wq0 += a0 * a0; ws1 += a1; wq1 += a1 * a1;
    }
    red[0][wv][l] = fs; red[1][wv][l] = fq; red[2][wv][l] = cs; red[3][wv][l] = cq;
    if (l == 0) { redw[wv][0] = ws0; redw[wv][1] = wq0; redw[wv][2] = ws1; redw[wv][3] = wq1; }
    __syncthreads();
    if (wv == 0) {
#pragma unroll
        for (int q = 0; q < 4; ++q) {
            float sum = red[q][0][l] + red[q][1][l] + red[q][2][l] + red[q][3][l];
            atomicAdd(&stats[q * 64 + l], sum);
        }
        if (l < 4) {
            float sum = redw[0][l] + redw[1][l] + redw[2][l] + redw[3][l];
            atomicAdd(&stats[256 + l], sum);
        }
    }
}

// ---------------- full-canvas write with inline BN/softmax aug ----------------
__global__ __launch_bounds__(256) void k_out2(const int* __restrict__ cellMap,
                                              const float* __restrict__ pillar,
                                              const float* __restrict__ f_pre,
                                              const float* __restrict__ c_pre,
                                              const float* __restrict__ w_pre,
                                              const float* __restrict__ stats,
                                              const float* __restrict__ g1,
                                              const float* __restrict__ b1,
                                              const float* __restrict__ g2,
                                              const float* __restrict__ b2,
                                              float* __restrict__ out) {
    int c4 = (blockIdx.x * 256 + threadIdx.x) * 4;
    if (c4 >= CELLS) return;
    int4 cm = *(const int4*)(cellMap + c4);
    const float invn = 1.0f / (float)NVc;
    float mw0 = stats[256] * invn, vw0 = stats[257] * invn - mw0 * mw0;
    float mw1 = stats[258] * invn, vw1 = stats[259] * invn - mw1 * mw1;
    float rw0 = rsqrtf(vw0 + 1e-3f), rw1 = rsqrtf(vw1 + 1e-3f);
    float g20 = g2[0], b20 = b2[0], g21 = g2[1], b21 = b2[1];
    float w0c[4], w1c[4];
    int cms[4] = {cm.x, cm.y, cm.z, cm.w};
#pragma unroll
    for (int k = 0; k < 4; ++k) {
        int c = cms[k];
        if (c >= 0) {
            float z0 = (w_pre[c * 2] - mw0) * rw0 * g20 + b20;
            float z1 = (w_pre[c * 2 + 1] - mw1) * rw1 * g21 + b21;
            float mz = fmaxf(z0, z1);
            float e0 = __expf(z0 - mz), e1 = __expf(z1 - mz);
            float wd = 1.f / (e0 + e1);
            w0c[k] = e0 * wd; w1c[k] = e1 * wd;
        } else { w0c[k] = 0.f; w1c[k] = 0.f; }
    }
    int f0 = blockIdx.y * 33;
    int f1 = f0 + 33; if (f1 > 131) f1 = 131;
    for (int f = f0; f < f1; ++f) {
        float4 val;
        if (f < 64) {
            val.x = cm.x >= 0 ? pillar[cm.x * 64 + f] : 0.f;
            val.y = cm.y >= 0 ? pillar[cm.y * 64 + f] : 0.f;
            val.z = cm.z >= 0 ? pillar[cm.z * 64 + f] : 0.f;
            val.w = cm.w >= 0 ? pillar[cm.w * 64 + f] : 0.f;
        } else if (f < 128) {
            int fa = f - 64;
            float mf = stats[fa] * invn;
            float rf = rsqrtf(stats[64 + fa] * invn - mf * mf + 1e-3f);
            float mc = stats[128 + fa] * invn;
            float rc = rsqrtf(stats[192 + fa] * invn - mc * mc + 1e-3f);
            float gg = g1[fa], bb = b1[fa];
            float* vv = (float*)&val;
#pragma unroll
            for (int k = 0; k < 4; ++k) {
                int c = cms[k];
                if (c >= 0) {
                    float fv = fmaxf((f_pre[c * 64 + fa] - mf) * rf * gg + bb, 0.f);
                    float cv = fmaxf((c_pre[c * 64 + fa] - mc) * rc * gg + bb, 0.f);
                    vv[k] = w0c[k] * fv + w1c[k] * cv;
                } else vv[k] = 0.f;
            }
        } else if (f == 128) {
            val.x = cm.x >= 0 ? (float)((c4 + 0) / NXc) : 0.f;
            val.y = cm.y >= 0 ? (float)((c4 + 1) / NXc) : 0.f;
            val.z = cm.z >= 0 ? (float)((c4 + 2) / NXc) : 0.f;
            val.w = cm.w >= 0 ? (float)((c4 + 3) / NXc) : 0.f;
        } else if (f == 129) {
            val = make_float4(0.f, 0.f, 0.f, 0.f);
        } else {
            val.x = cm.x >= 0 ? (float)((c4 + 0) % NXc) : 0.f;
            val.y = cm.y >= 0 ? (float)((c4 + 1) % NXc) : 0.f;
            val.z = cm.z >= 0 ? (float)((c4 + 2) % NXc) : 0.f;
            val.w = cm.w >= 0 ? (float)((c4 + 3) % NXc) : 0.f;
        }
        *(float4*)(out + (size_t)f * CELLS + c4) = val;
    }
}

extern "C" void kernel_launch(void* const* d_in, const int* in_sizes, int n_in,
                              void* d_out, int out_size, void* d_ws, size_t ws_size,
                              hipStream_t stream) {
    const float* pillar = (const float*)d_in[0];
    const int*   coords = (const int*)d_in[1];
    const float* pfeat  = (const float*)d_in[2];
    const float* pcoord = (const float*)d_in[3];
    const float* adapt  = (const float*)d_in[4];
    const float* bn1g   = (const float*)d_in[5];
    const float* bn1b   = (const float*)d_in[6];
    const float* ww     = (const float*)d_in[7];
    const float* bn2g   = (const float*)d_in[8];
    const float* bn2b   = (const float*)d_in[9];
    const float* memw   = (const float*)d_in[10];
    float* out = (float*)d_out;
    float* ws  = (float*)d_ws;
    // workspace layout (float offsets)
    u16*   PoutH = (u16*)(ws + 0);                 // 1,048,576 u16
    float* Q     = ws + 1048576;                   // 3,145,728 fl
    int*   sIdx  = (int*)(ws + 4194304);           // 640,000
    int*   binStart  = (int*)(ws + 4834304);       // 838
    int*   dIdx6     = (int*)(ws + 4836824);       // 60,000
    float4* binPC    = (float4*)(ws + 4896824);    // 65,536 fl
    u16*   memwH   = (u16*)(ws + 4970000);         // 65,536 u16
    u16*   memwTH  = (u16*)(ws + 5002768);         // 65,536 u16
    u16*   badaptH = (u16*)(ws + 5035536);         // 12,288 u16
    int*   idxf  = (int*)(ws + 5474304);           // 30,000
    int*   idxc  = (int*)(ws + 5504304);           // 30,000
    float* fpre  = ws + 5534304;                   // 640,000
    float* cpre  = ws + 6174304;                   // 640,000
    float* wpre  = ws + 6814304;                   // 20,000
    float* stats = ws + 6834304;                   // 260
    int*   cellMap = (int*)(ws + 6840000);         // 214,272 ints
    // bf16 feature buffers overlap fpre/cpre (dead until k_gather writes them)
    u16* pillarH = (u16*)(ws + 5534304);           // 643,072 u16
    u16* pfeatH  = pillarH + (size_t)NVPAD * 64;   // 1,048,576 u16

    k_init  <<<7168, 256, 0, stream>>>(pillar, pfeat, memw, adapt, stats, cellMap,
                                       pillarH, pfeatH, memwH, memwTH, badaptH);
    k_pre   <<<1, 1024, 0, stream>>>(pcoord, binStart, binPC);
    k_fused <<<2808, 256, 0, stream>>>(pillarH, pfeatH, memwH, memwTH, coords,
                                       binPC, binStart, PoutH, dIdx6, sIdx);
    k_fused2<<<2756, 256, 0, stream>>>(PoutH, badaptH, pillar, coords, pfeat, pcoord,
                                       sIdx, dIdx6, Q, idxf, idxc);
    k_gather<<<250, 256, 0, stream>>>(Q, idxf, idxc, pillar, coords, ww,
                                      fpre, cpre, wpre, stats, cellMap);
    k_out2  <<<dim3(210, 4), 256, 0, stream>>>(cellMap, pillar, fpre, cpre, wpre, stats,
                                               bn1g, bn1b, bn2g, bn2b, out);
}